// Round 1
// baseline (1976.795 us; speedup 1.0000x reference)
//
#include <hip/hip_runtime.h>
#include <math.h>

#define NB 4
#define NN 4096
#define NC 256
#define NQ 14

// ---------------------------------------------------------------- helpers
__device__ __forceinline__ bool aligned_pt(int ss, int sq) {
    // (2s+3)(2q+3) perfect square <=> equal square-free parts
    return (ss == sq) || ((ss == 0) && (sq == 12)) || ((ss == 12) && (sq == 0)) ||
           ((ss == 3) && (sq == 11)) || ((ss == 11) && (sq == 3));
}

__device__ __forceinline__ float blockReduceSum256(float v, float* sred) {
    #pragma unroll
    for (int off = 32; off; off >>= 1) v += __shfl_xor(v, off, 64);
    const int lane = threadIdx.x & 63, wid = threadIdx.x >> 6;
    if (lane == 0) sred[wid] = v;
    __syncthreads();
    float s = sred[0] + sred[1] + sred[2] + sred[3];
    __syncthreads();
    return s;
}

// ---------------------------------------------------------------- generic GEMM
// out[M,256] = (A (+A2)) @ W[256,256], M = 16384. grid(2,256), block 256.
// 64x128 block tile, 4x8 per thread, K-chunks of 32.
__global__ __launch_bounds__(256) void gemm_aw(const float* __restrict__ A,
                                               const float* __restrict__ A2,
                                               const float* __restrict__ W,
                                               float* __restrict__ out) {
    const int t = threadIdx.x;
    const int row0 = blockIdx.y * 64;
    const int cb = blockIdx.x * 128;
    __shared__ __align__(16) float Ast[32][68];   // transposed A tile [k][r]
    __shared__ __align__(16) float Wt[32][132];   // W tile [k][c]
    const int r0 = (t & 15) * 4;
    const int c0 = (t >> 4) * 8;
    const int ar = t >> 2;          // 0..63
    const int ak = (t & 3) * 8;     // 0,8,16,24
    const int wr = t >> 3;          // 0..31
    const int wc = (t & 7) * 16;    // 0..112
    float acc[4][8];
    #pragma unroll
    for (int i = 0; i < 4; i++)
        #pragma unroll
        for (int j = 0; j < 8; j++) acc[i][j] = 0.f;

    for (int k0 = 0; k0 < 256; k0 += 32) {
        const float* asrc = A + (size_t)(row0 + ar) * 256 + k0 + ak;
        float4 a0 = *(const float4*)asrc;
        float4 a1 = *(const float4*)(asrc + 4);
        if (A2) {
            const float* a2s = A2 + (size_t)(row0 + ar) * 256 + k0 + ak;
            float4 b0 = *(const float4*)a2s;
            float4 b1 = *(const float4*)(a2s + 4);
            a0.x += b0.x; a0.y += b0.y; a0.z += b0.z; a0.w += b0.w;
            a1.x += b1.x; a1.y += b1.y; a1.z += b1.z; a1.w += b1.w;
        }
        const float* wsrc = W + (size_t)(k0 + wr) * 256 + cb + wc;
        float4 w0 = *(const float4*)wsrc;
        float4 w1 = *(const float4*)(wsrc + 4);
        float4 w2 = *(const float4*)(wsrc + 8);
        float4 w3 = *(const float4*)(wsrc + 12);
        __syncthreads();
        Ast[ak + 0][ar] = a0.x; Ast[ak + 1][ar] = a0.y;
        Ast[ak + 2][ar] = a0.z; Ast[ak + 3][ar] = a0.w;
        Ast[ak + 4][ar] = a1.x; Ast[ak + 5][ar] = a1.y;
        Ast[ak + 6][ar] = a1.z; Ast[ak + 7][ar] = a1.w;
        *(float4*)&Wt[wr][wc + 0] = w0;
        *(float4*)&Wt[wr][wc + 4] = w1;
        *(float4*)&Wt[wr][wc + 8] = w2;
        *(float4*)&Wt[wr][wc + 12] = w3;
        __syncthreads();
        #pragma unroll
        for (int kk = 0; kk < 32; kk++) {
            const float4 a4 = *(const float4*)&Ast[kk][r0];
            const float4 wa = *(const float4*)&Wt[kk][c0];
            const float4 wb = *(const float4*)&Wt[kk][c0 + 4];
            const float av[4] = {a4.x, a4.y, a4.z, a4.w};
            const float wv[8] = {wa.x, wa.y, wa.z, wa.w, wb.x, wb.y, wb.z, wb.w};
            #pragma unroll
            for (int i = 0; i < 4; i++)
                #pragma unroll
                for (int j = 0; j < 8; j++) acc[i][j] += av[i] * wv[j];
        }
    }
    #pragma unroll
    for (int i = 0; i < 4; i++) {
        float* dst = out + (size_t)(row0 + r0 + i) * 256 + cb + c0;
        float4 o0 = make_float4(acc[i][0], acc[i][1], acc[i][2], acc[i][3]);
        float4 o1 = make_float4(acc[i][4], acc[i][5], acc[i][6], acc[i][7]);
        *(float4*)dst = o0;
        *(float4*)(dst + 4) = o1;
    }
}

// ---------------------------------------------------------------- prep kernels
// Wqk2[c1][c2] = (sum_d Wqs[c1][d]*Wks[c2][d]) / sqrt(512)
__global__ __launch_bounds__(256) void prep_wqk(const float* __restrict__ Wqs,
                                                const float* __restrict__ Wks,
                                                float* __restrict__ Wqk2) {
    __shared__ __align__(16) float srow[512];
    const int c1 = blockIdx.x, c2 = threadIdx.x;
    srow[c2] = Wqs[c1 * 512 + c2];
    srow[c2 + 256] = Wqs[c1 * 512 + 256 + c2];
    __syncthreads();
    const float* wk = Wks + (size_t)c2 * 512;
    float acc = 0.f;
    for (int d = 0; d < 512; d += 4) {
        float4 a = *(const float4*)&srow[d];
        float4 b = *(const float4*)(wk + d);
        acc += a.x * b.x + a.y * b.y + a.z * b.z + a.w * b.w;
    }
    Wqk2[c1 * 256 + c2] = acc * 0.044194173824159216f;  // 1/sqrt(512)
}

// Wcomb[c1][c2] = sum_d Wvs[c1][d]*Wfc[d][c2]
__global__ __launch_bounds__(256) void prep_wcomb(const float* __restrict__ Wvs,
                                                  const float* __restrict__ Wfc,
                                                  float* __restrict__ Wcomb) {
    __shared__ float srow[512];
    const int c1 = blockIdx.x, c2 = threadIdx.x;
    srow[c2] = Wvs[c1 * 512 + c2];
    srow[c2 + 256] = Wvs[c1 * 512 + 256 + c2];
    __syncthreads();
    float acc = 0.f;
    for (int d = 0; d < 512; d++) acc += srow[d] * Wfc[d * 256 + c2];
    Wcomb[c1 * 256 + c2] = acc;
}

// seed[b,q,c] = sum_c' sv[b,c',q]*Ws[c',c];  qhk[b,q,c] = sum_c' seed[b,q,c']*Wqk2[c',c]
__global__ __launch_bounds__(256) void k_seed(const float* __restrict__ sv,
                                              const float* __restrict__ Ws,
                                              const float* __restrict__ Wqk2,
                                              float* __restrict__ seed,
                                              float* __restrict__ qhk) {
    const int q = blockIdx.x, b = blockIdx.y, c = threadIdx.x;
    __shared__ float ssv[256];
    __shared__ float sseed[256];
    ssv[c] = sv[((size_t)b * 256 + c) * 14 + q];
    __syncthreads();
    float acc = 0.f;
    for (int d = 0; d < 256; d++) acc += ssv[d] * Ws[d * 256 + c];
    seed[((size_t)b * 14 + q) * 256 + c] = acc;
    sseed[c] = acc;
    __syncthreads();
    float a2 = 0.f;
    for (int d = 0; d < 256; d++) a2 += sseed[d] * Wqk2[d * 256 + c];
    qhk[((size_t)b * 14 + q) * 256 + c] = a2;
}

// ---------------------------------------------------------------- stage-2 attention
// logits[b,q,n] = supp_mask? kk[b,n,:]·qhk[b,q,:] : -1e9   (scale folded into qhk)
__global__ __launch_bounds__(256) void k_logits1(const float* __restrict__ kk,
                                                 const float* __restrict__ qhk,
                                                 const int* __restrict__ supp,
                                                 float* __restrict__ logits) {
    const int b = blockIdx.y;
    const int n = blockIdx.x * 256 + threadIdx.x;
    __shared__ __align__(16) float sq[14][256];
    for (int i = threadIdx.x; i < 14 * 256; i += 256) sq[i >> 8][i & 255] = qhk[b * 14 * 256 + i];
    __syncthreads();
    float acc[14];
    #pragma unroll
    for (int q = 0; q < 14; q++) acc[q] = 0.f;
    const float* krow = kk + ((size_t)b * 4096 + n) * 256;
    for (int c = 0; c < 256; c += 4) {
        const float4 k4 = *(const float4*)(krow + c);
        #pragma unroll
        for (int q = 0; q < 14; q++) {
            const float4 a4 = *(const float4*)&sq[q][c];
            acc[q] += k4.x * a4.x + k4.y * a4.y + k4.z * a4.z + k4.w * a4.w;
        }
    }
    const bool msk = (supp[b * 4096 + n] == 0);
    #pragma unroll
    for (int q = 0; q < 14; q++)
        logits[((size_t)b * 14 + q) * 4096 + n] = msk ? -1e9f : acc[q];
}

// row softmax over n (4096), in place. grid(14,4), block 256.
__global__ __launch_bounds__(256) void k_softmax1(float* __restrict__ logits) {
    const int b = blockIdx.y, qq = blockIdx.x, t = threadIdx.x;
    __shared__ __align__(16) float sl[4096];
    __shared__ float sred[8];
    float* row = logits + ((size_t)b * 14 + qq) * 4096;
    float mx = -3e38f;
    for (int i = t; i < 4096; i += 256) { float v = row[i]; sl[i] = v; mx = fmaxf(mx, v); }
    #pragma unroll
    for (int off = 32; off; off >>= 1) mx = fmaxf(mx, __shfl_xor(mx, off, 64));
    if ((t & 63) == 0) sred[t >> 6] = mx;
    __syncthreads();
    mx = fmaxf(fmaxf(sred[0], sred[1]), fmaxf(sred[2], sred[3]));
    __syncthreads();
    float s = 0.f;
    for (int i = t; i < 4096; i += 256) { float e = expf(sl[i] - mx); sl[i] = e; s += e; }
    #pragma unroll
    for (int off = 32; off; off >>= 1) s += __shfl_xor(s, off, 64);
    if ((t & 63) == 0) sred[t >> 6] = s;
    __syncthreads();
    s = sred[0] + sred[1] + sred[2] + sred[3];
    const float inv = 1.f / s;
    for (int i = t; i < 4096; i += 256) row[i] = sl[i] * inv;
}

// partial ctxv: part[b,ch,q,c] = sum_{n in chunk} A[b,q,n]*vv[b,n,c]. grid(16,4), block 256.
__global__ __launch_bounds__(256) void k_ctxv(const float* __restrict__ A,
                                              const float* __restrict__ vv,
                                              float* __restrict__ part) {
    const int b = blockIdx.y, ch = blockIdx.x, c = threadIdx.x;
    const int n0 = ch * 256;
    __shared__ __align__(16) float sA[14][256];
    for (int i = c; i < 14 * 256; i += 256) {
        int qq = i >> 8, j = i & 255;
        sA[qq][j] = A[((size_t)b * 14 + qq) * 4096 + n0 + j];
    }
    __syncthreads();
    float acc[14];
    #pragma unroll
    for (int q = 0; q < 14; q++) acc[q] = 0.f;
    for (int n = 0; n < 256; n += 4) {
        const float v0 = vv[((size_t)b * 4096 + n0 + n + 0) * 256 + c];
        const float v1 = vv[((size_t)b * 4096 + n0 + n + 1) * 256 + c];
        const float v2 = vv[((size_t)b * 4096 + n0 + n + 2) * 256 + c];
        const float v3 = vv[((size_t)b * 4096 + n0 + n + 3) * 256 + c];
        #pragma unroll
        for (int q = 0; q < 14; q++) {
            const float4 a4 = *(const float4*)&sA[q][n];
            acc[q] += a4.x * v0 + a4.y * v1 + a4.z * v2 + a4.w * v3;
        }
    }
    #pragma unroll
    for (int q = 0; q < 14; q++) part[(((size_t)b * 16 + ch) * 14 + q) * 256 + c] = acc[q];
}

// prototypes + pk/pq + l2norm. grid(14,4), block 256 (one thread per channel c).
__global__ __launch_bounds__(256) void k_proto(const float* __restrict__ part,
                                               const float* __restrict__ Wcomb,
                                               const float* __restrict__ bfc,
                                               const float* __restrict__ seed,
                                               const float* __restrict__ lng,
                                               const float* __restrict__ lnb,
                                               const float* __restrict__ Wsk,
                                               const float* __restrict__ Wsq,
                                               float* __restrict__ pkn,
                                               float* __restrict__ pqn) {
    const int q = blockIdx.x, b = blockIdx.y, c = threadIdx.x;
    __shared__ float sctx[256];
    __shared__ float sproto[256];
    __shared__ float sred[8];
    float cv = 0.f;
    for (int ch = 0; ch < 16; ch++) cv += part[(((size_t)b * 16 + ch) * 14 + q) * 256 + c];
    sctx[c] = cv;
    __syncthreads();
    float pre = 0.f;
    for (int d = 0; d < 256; d++) pre += sctx[d] * Wcomb[d * 256 + c];
    pre += bfc[c] + seed[((size_t)b * 14 + q) * 256 + c];
    const float mu = blockReduceSum256(pre, sred) * (1.f / 256.f);
    const float dv = pre - mu;
    const float var = blockReduceSum256(dv * dv, sred) * (1.f / 256.f);
    const float proto = dv * (1.f / sqrtf(var + 1e-5f)) * lng[c] + lnb[c];
    sproto[c] = proto;
    __syncthreads();
    float pk = 0.f, pq = 0.f;
    for (int d = 0; d < 256; d++) {
        const float sp = sproto[d];
        pk += sp * Wsk[d * 256 + c];
        pq += sp * Wsq[d * 256 + c];
    }
    const float nk = blockReduceSum256(pk * pk, sred);
    const float nq = blockReduceSum256(pq * pq, sred);
    pkn[((size_t)b * 14 + q) * 256 + c] = pk / fmaxf(sqrtf(nk), 1e-12f);
    pqn[((size_t)b * 14 + q) * 256 + c] = pq / fmaxf(sqrtf(nq), 1e-12f);
}

// cosine sims: att_q2p = l2n(qs)·pkn, att = l2n(kk)·pqn, and sid_q. grid(16,4), block 256.
__global__ __launch_bounds__(256) void k_q2p(const float* __restrict__ qs,
                                             const float* __restrict__ kk,
                                             const float* __restrict__ pkn,
                                             const float* __restrict__ pqn,
                                             float* __restrict__ aq2p,
                                             float* __restrict__ attc,
                                             int* __restrict__ sidq) {
    const int b = blockIdx.y;
    const int n = blockIdx.x * 256 + threadIdx.x;
    __shared__ __align__(16) float spk[14][256];
    __shared__ __align__(16) float spq[14][256];
    for (int i = threadIdx.x; i < 14 * 256; i += 256) {
        spk[i >> 8][i & 255] = pkn[b * 14 * 256 + i];
        spq[i >> 8][i & 255] = pqn[b * 14 * 256 + i];
    }
    __syncthreads();
    float aq[14], ak[14];
    #pragma unroll
    for (int q = 0; q < 14; q++) { aq[q] = 0.f; ak[q] = 0.f; }
    float nq = 0.f, nk = 0.f;
    const float* qrow = qs + ((size_t)b * 4096 + n) * 256;
    const float* krow = kk + ((size_t)b * 4096 + n) * 256;
    for (int c = 0; c < 256; c += 4) {
        const float4 q4 = *(const float4*)(qrow + c);
        const float4 k4 = *(const float4*)(krow + c);
        nq += q4.x * q4.x + q4.y * q4.y + q4.z * q4.z + q4.w * q4.w;
        nk += k4.x * k4.x + k4.y * k4.y + k4.z * k4.z + k4.w * k4.w;
        #pragma unroll
        for (int q = 0; q < 14; q++) {
            const float4 p4 = *(const float4*)&spk[q][c];
            const float4 p4b = *(const float4*)&spq[q][c];
            aq[q] += q4.x * p4.x + q4.y * p4.y + q4.z * p4.z + q4.w * p4.w;
            ak[q] += k4.x * p4b.x + k4.y * p4b.y + k4.z * p4b.z + k4.w * p4b.w;
        }
    }
    const float sq_ = 1.f / fmaxf(sqrtf(nq), 1e-12f);
    const float sk_ = 1.f / fmaxf(sqrtf(nk), 1e-12f);
    float* aqrow = aq2p + ((size_t)b * 4096 + n) * 14;
    float* akrow = attc + ((size_t)b * 4096 + n) * 14;
    int best = 0;
    float bv = -3e38f;
    #pragma unroll
    for (int q = 0; q < 14; q++) {
        const float v = aq[q] * sq_;
        aqrow[q] = v;
        if (v > bv) { bv = v; best = q; }
        akrow[q] = ak[q] * sk_;
    }
    sidq[b * 4096 + n] = best;
}

// ---------------------------------------------------------------- Sinkhorn
// one block per batch, 1024 threads, K kept in registers (4 rows x 15 per thread).
__global__ __launch_bounds__(1024) void k_sinkhorn(const float* __restrict__ attc,
                                                   const int* __restrict__ supp,
                                                   float* __restrict__ as2p,
                                                   int* __restrict__ sids) {
    const int b = blockIdx.x;
    const int t = threadIdx.x;
    const int lane = t & 63, wid = t >> 6;
    __shared__ float wred[16][16];
    __shared__ float vsh[16];
    __shared__ float sbg[16];
    float K[4][15], u[4];
    float bgcnt = 0.f;
    #pragma unroll
    for (int j = 0; j < 4; j++) {
        const int n = t + j * 1024;
        const int sm = supp[b * 4096 + n];
        bgcnt += (sm == 0) ? 1.f : 0.f;
        const float* arow = attc + ((size_t)b * 4096 + n) * 14;
        #pragma unroll
        for (int m = 0; m < 14; m++) K[j][m] = expf(-20.f * (1.f - arow[m]));
        K[j][14] = (sm > 0) ? expf(-40.f) : 1.f;
        u[j] = 1.f / 4096.f;
    }
    #pragma unroll
    for (int off = 32; off; off >>= 1) bgcnt += __shfl_xor(bgcnt, off, 64);
    if (lane == 0) sbg[wid] = bgcnt;
    __syncthreads();
    float num_bg = 0.f;
    #pragma unroll
    for (int w = 0; w < 16; w++) num_bg += sbg[w];
    const float num_fg = 4096.f - num_bg;
    const float bm_fg = num_fg / (14.f * 4096.f);
    const float bm_tr = num_bg / 4096.f;
    const float a_n = 1.f / 4096.f;

    for (int it = 0; it < 100; it++) {
        #pragma unroll
        for (int m = 0; m < 15; m++) {
            float p = K[0][m] * u[0] + K[1][m] * u[1] + K[2][m] * u[2] + K[3][m] * u[3];
            #pragma unroll
            for (int off = 32; off; off >>= 1) p += __shfl_xor(p, off, 64);
            if (lane == 0) wred[wid][m] = p;
        }
        __syncthreads();
        if (t < 15) {
            float s = 0.f;
            #pragma unroll
            for (int w = 0; w < 16; w++) s += wred[w][t];
            const float bm = (t < 14) ? bm_fg : bm_tr;
            vsh[t] = bm / (s + 1e-16f);
        }
        __syncthreads();
        #pragma unroll
        for (int j = 0; j < 4; j++) {
            float s = 0.f;
            #pragma unroll
            for (int m = 0; m < 15; m++) s += K[j][m] * vsh[m];
            u[j] = a_n / (s + 1e-16f);
        }
    }
    #pragma unroll
    for (int j = 0; j < 4; j++) {
        const int n = t + j * 1024;
        float* orow = as2p + ((size_t)b * 4096 + n) * 14;
        float bv = -3e38f;
        int bi = 0;
        #pragma unroll
        for (int m = 0; m < 14; m++) {
            float tv = fmaxf(4096.f * u[j] * K[j][m] * vsh[m], 0.f);
            orow[m] = tv;
            if (tv > bv) { bv = tv; bi = m; }
        }
        sids[b * 4096 + n] = bi;
    }
}

// ---------------------------------------------------------------- big attention
// phase 1: per-row level-bucketed exp sums. grid(16,4,4) = (nchunk, msplit, b), block 256.
__global__ __launch_bounds__(256) void k_phase1(const float* __restrict__ aq2p,
                                                const float* __restrict__ as2p,
                                                const int* __restrict__ sidq,
                                                const int* __restrict__ sids,
                                                const int* __restrict__ valid,
                                                float* __restrict__ spart) {
    const int b = blockIdx.z, ms = blockIdx.y;
    const int n = blockIdx.x * 256 + threadIdx.x;
    __shared__ float s2p[128 * 14];
    __shared__ int ssid[128], sval[128];
    float qv[14];
    const float* qrow = aq2p + ((size_t)b * 4096 + n) * 14;
    #pragma unroll
    for (int k2 = 0; k2 < 14; k2++) qv[k2] = qrow[k2];
    const int sq = sidq[b * 4096 + n];
    float s0 = 0.f, s1 = 0.f, s2 = 0.f;
    for (int m0 = ms * 1024; m0 < (ms + 1) * 1024; m0 += 128) {
        __syncthreads();
        for (int i = threadIdx.x; i < 128 * 14; i += 256)
            s2p[i] = as2p[((size_t)b * 4096 + m0) * 14 + i];
        if (threadIdx.x < 128) {
            ssid[threadIdx.x] = sids[b * 4096 + m0 + threadIdx.x];
            sval[threadIdx.x] = valid[b * 4096 + m0 + threadIdx.x];
        }
        __syncthreads();
        for (int mm = 0; mm < 128; mm++) {
            const float* sp = &s2p[mm * 14];
            float l = 0.f;
            #pragma unroll
            for (int k2 = 0; k2 < 14; k2++) l += qv[k2] * sp[k2];
            const int lvl = sval[mm] + (aligned_pt(ssid[mm], sq) ? 0 : 1);
            const float e = expf(l);
            s0 += (lvl == 0) ? e : 0.f;
            s1 += (lvl == 1) ? e : 0.f;
            s2 += (lvl == 2) ? e : 0.f;
        }
    }
    const int idx = ms * 16384 + b * 4096 + n;
    spart[idx * 3 + 0] = s0;
    spart[idx * 3 + 1] = s1;
    spart[idx * 3 + 2] = s2;
}

// phase1 merge: pick top level present, 1/sum. grid 64, block 256.
__global__ __launch_bounds__(256) void k_ph1merge(const float* __restrict__ spart,
                                                  int* __restrict__ lam,
                                                  float* __restrict__ rinv) {
    const int i = blockIdx.x * 256 + threadIdx.x;  // b*4096+n
    float s0 = 0.f, s1 = 0.f, s2 = 0.f;
    for (int ms = 0; ms < 4; ms++) {
        const float* p = spart + ((size_t)ms * 16384 + i) * 3;
        s0 += p[0]; s1 += p[1]; s2 += p[2];
    }
    const int l = (s0 > 0.f) ? 0 : ((s1 > 0.f) ? 1 : 2);
    const float sv = (l == 0) ? s0 : ((l == 1) ? s1 : s2);
    lam[i] = l;
    rinv[i] = 1.f / sv;
}

// phase2: y[n,c] += p(n,m)*vv[m,c]. grid(64,2,4) = (ntile, msplit, b), block 256.
__global__ __launch_bounds__(256) void k_phase2(const float* __restrict__ aq2p,
                                                const float* __restrict__ as2p,
                                                const int* __restrict__ sidq,
                                                const int* __restrict__ sids,
                                                const int* __restrict__ valid,
                                                const int* __restrict__ lam,
                                                const float* __restrict__ rinv,
                                                const float* __restrict__ vv,
                                                float* __restrict__ ypart) {
    const int b = blockIdx.z, ms = blockIdx.y, nt = blockIdx.x;
    const int t = threadIdx.x;
    const int n0 = nt * 64;
    __shared__ __align__(16) float pT[64][64];     // [mm][r]
    __shared__ float s2p_s[64 * 14];
    __shared__ int ssid[64], sval[64];
    const int pr = t & 63;
    const int pchunk = t >> 6;  // 0..3 -> 16 mm each
    float qv[14];
    const float* qrow = aq2p + ((size_t)b * 4096 + n0 + pr) * 14;
    #pragma unroll
    for (int k2 = 0; k2 < 14; k2++) qv[k2] = qrow[k2];
    const int sq = sidq[b * 4096 + n0 + pr];
    const int mylam = lam[b * 4096 + n0 + pr];
    const float myrinv = rinv[b * 4096 + n0 + pr];

    const int c0 = (t & 31) * 8;
    const int r0 = (t >> 5) * 8;
    float acc[8][8];
    #pragma unroll
    for (int i = 0; i < 8; i++)
        #pragma unroll
        for (int j = 0; j < 8; j++) acc[i][j] = 0.f;
    const float* vvb = vv + (size_t)b * 4096 * 256;

    for (int mt = 0; mt < 32; mt++) {
        const int m0 = ms * 2048 + mt * 64;
        __syncthreads();
        for (int i = t; i < 64 * 14; i += 256)
            s2p_s[i] = as2p[((size_t)b * 4096 + m0) * 14 + i];
        if (t < 64) {
            ssid[t] = sids[b * 4096 + m0 + t];
            sval[t] = valid[b * 4096 + m0 + t];
        }
        __syncthreads();
        #pragma unroll
        for (int i = 0; i < 16; i++) {
            const int mm = pchunk * 16 + i;
            const float* sp = &s2p_s[mm * 14];
            float l = 0.f;
            #pragma unroll
            for (int k2 = 0; k2 < 14; k2++) l += qv[k2] * sp[k2];
            const int lvl = sval[mm] + (aligned_pt(ssid[mm], sq) ? 0 : 1);
            pT[mm][pr] = (lvl == mylam) ? expf(l) * myrinv : 0.f;
        }
        __syncthreads();
        #pragma unroll 4
        for (int mm = 0; mm < 64; mm++) {
            const float4 p0 = *(const float4*)&pT[mm][r0];
            const float4 p1 = *(const float4*)&pT[mm][r0 + 4];
            const float* vr = vvb + (size_t)(m0 + mm) * 256 + c0;
            const float4 v0 = *(const float4*)vr;
            const float4 v1 = *(const float4*)(vr + 4);
            const float pv[8] = {p0.x, p0.y, p0.z, p0.w, p1.x, p1.y, p1.z, p1.w};
            const float vw[8] = {v0.x, v0.y, v0.z, v0.w, v1.x, v1.y, v1.z, v1.w};
            #pragma unroll
            for (int i = 0; i < 8; i++)
                #pragma unroll
                for (int j = 0; j < 8; j++) acc[i][j] += pv[i] * vw[j];
        }
    }
    float* yp = ypart + ((size_t)ms * 4 + b) * 4096 * 256;
    #pragma unroll
    for (int i = 0; i < 8; i++) {
        float* dst = yp + (size_t)(n0 + r0 + i) * 256 + c0;
        float4 o0 = make_float4(acc[i][0], acc[i][1], acc[i][2], acc[i][3]);
        float4 o1 = make_float4(acc[i][4], acc[i][5], acc[i][6], acc[i][7]);
        *(float4*)dst = o0;
        *(float4*)(dst + 4) = o1;
    }
}

// ---------------------------------------------------------------- launch
extern "C" void kernel_launch(void* const* d_in, const int* in_sizes, int n_in,
                              void* d_out, int out_size, void* d_ws, size_t ws_size,
                              hipStream_t stream) {
    (void)in_sizes; (void)n_in; (void)out_size; (void)ws_size;
    const float* q    = (const float*)d_in[0];
    const float* k    = (const float*)d_in[1];
    const float* v    = (const float*)d_in[2];
    const float* sv   = (const float*)d_in[3];
    const int*  valid = (const int*)d_in[4];
    const int*  supp  = (const int*)d_in[5];
    const float* Wq   = (const float*)d_in[6];
    const float* Wk   = (const float*)d_in[7];
    const float* Wv   = (const float*)d_in[8];
    const float* Ws   = (const float*)d_in[9];
    const float* Wsq  = (const float*)d_in[10];
    const float* Wsk  = (const float*)d_in[11];
    const float* Wproj= (const float*)d_in[12];
    const float* Wqs  = (const float*)d_in[13];
    const float* Wks  = (const float*)d_in[14];
    const float* Wvs  = (const float*)d_in[15];
    const float* Wfc  = (const float*)d_in[16];
    const float* bfc  = (const float*)d_in[17];
    const float* lng  = (const float*)d_in[18];
    const float* lnb  = (const float*)d_in[19];

    float* ws = (float*)d_ws;
    float* qs   = ws + 0;         float* y0 = qs;   // qs dead before phase2 writes y0
    float* kk   = ws + 4194304;   float* y1 = kk;   // kk dead before phase2 writes y1
    float* vv   = ws + 8388608;
    float* wqk2 = ws + 12582912;
    float* wcomb= ws + 12648448;
    float* seed = ws + 12713984;
    float* qhk  = ws + 12728320;
    float* logA = ws + 12742656;
    float* cpart= ws + 12972032;
    float* pkn  = ws + 13201408;
    float* pqn  = ws + 13215744;
    float* aq2p = ws + 13230080;
    float* attc = ws + 13459456;
    float* as2p = ws + 13688832;
    float* spart= ws + 13918208;
    float* rinvb= ws + 14114816;
    int* lam  = (int*)(ws + 14131200);
    int* sidq = (int*)(ws + 14147584);
    int* sids = (int*)(ws + 14163968);

    gemm_aw<<<dim3(2, 256), 256, 0, stream>>>(q, nullptr, Wq, qs);
    gemm_aw<<<dim3(2, 256), 256, 0, stream>>>(k, nullptr, Wk, kk);
    gemm_aw<<<dim3(2, 256), 256, 0, stream>>>(v, nullptr, Wv, vv);
    prep_wqk<<<256, 256, 0, stream>>>(Wqs, Wks, wqk2);
    prep_wcomb<<<256, 256, 0, stream>>>(Wvs, Wfc, wcomb);
    k_seed<<<dim3(14, 4), 256, 0, stream>>>(sv, Ws, wqk2, seed, qhk);
    k_logits1<<<dim3(16, 4), 256, 0, stream>>>(kk, qhk, supp, logA);
    k_softmax1<<<dim3(14, 4), 256, 0, stream>>>(logA);
    k_ctxv<<<dim3(16, 4), 256, 0, stream>>>(logA, vv, cpart);
    k_proto<<<dim3(14, 4), 256, 0, stream>>>(cpart, wcomb, bfc, seed, lng, lnb, Wsk, Wsq, pkn, pqn);
    k_q2p<<<dim3(16, 4), 256, 0, stream>>>(qs, kk, pkn, pqn, aq2p, attc, sidq);
    k_sinkhorn<<<4, 1024, 0, stream>>>(attc, supp, as2p, sids);
    k_phase1<<<dim3(16, 4, 4), 256, 0, stream>>>(aq2p, as2p, sidq, sids, valid, spart);
    k_ph1merge<<<64, 256, 0, stream>>>(spart, lam, rinvb);
    k_phase2<<<dim3(64, 2, 4), 256, 0, stream>>>(aq2p, as2p, sidq, sids, valid, lam, rinvb, vv, y0);
    gemm_aw<<<dim3(2, 256), 256, 0, stream>>>(y0, y1, Wproj, (float*)d_out);
}

// Round 2
// 1795.258 us; speedup vs baseline: 1.1011x; 1.1011x over previous
//
#include <hip/hip_runtime.h>
#include <math.h>

#define NB 4
#define NN 4096
#define NC 256
#define NQ 14

typedef __attribute__((ext_vector_type(8))) short short8;
typedef __attribute__((ext_vector_type(4))) float f32x4;
union U16x8 { uint4 u4; short8 s8; unsigned short us[8]; };

// ---------------------------------------------------------------- helpers
__device__ __forceinline__ bool aligned_pt(int ss, int sq) {
    // (2s+3)(2q+3) perfect square <=> equal square-free parts
    return (ss == sq) || ((ss == 0) && (sq == 12)) || ((ss == 12) && (sq == 0)) ||
           ((ss == 3) && (sq == 11)) || ((ss == 11) && (sq == 3));
}

__device__ __forceinline__ unsigned short f2bf(float x) {
    unsigned u = __float_as_uint(x);
    u += 0x7fff + ((u >> 16) & 1);   // RNE
    return (unsigned short)(u >> 16);
}
__device__ __forceinline__ float bf2f(unsigned short h) {
    return __uint_as_float(((unsigned)h) << 16);
}

__device__ __forceinline__ float blockReduceSum256(float v, float* sred) {
    #pragma unroll
    for (int off = 32; off; off >>= 1) v += __shfl_xor(v, off, 64);
    const int lane = threadIdx.x & 63, wid = threadIdx.x >> 6;
    if (lane == 0) sred[wid] = v;
    __syncthreads();
    float s = sred[0] + sred[1] + sred[2] + sred[3];
    __syncthreads();
    return s;
}

// ---------------------------------------------------------------- generic GEMM
// out[M,256] = (A (+A2)) @ W[256,256], M = 16384. grid(2,256), block 256.
__global__ __launch_bounds__(256) void gemm_aw(const float* __restrict__ A,
                                               const float* __restrict__ A2,
                                               const float* __restrict__ W,
                                               float* __restrict__ out) {
    const int t = threadIdx.x;
    const int row0 = blockIdx.y * 64;
    const int cb = blockIdx.x * 128;
    __shared__ __align__(16) float Ast[32][68];   // transposed A tile [k][r]
    __shared__ __align__(16) float Wt[32][132];   // W tile [k][c]
    const int r0 = (t & 15) * 4;
    const int c0 = (t >> 4) * 8;
    const int ar = t >> 2;          // 0..63
    const int ak = (t & 3) * 8;     // 0,8,16,24
    const int wr = t >> 3;          // 0..31
    const int wc = (t & 7) * 16;    // 0..112
    float acc[4][8];
    #pragma unroll
    for (int i = 0; i < 4; i++)
        #pragma unroll
        for (int j = 0; j < 8; j++) acc[i][j] = 0.f;

    for (int k0 = 0; k0 < 256; k0 += 32) {
        const float* asrc = A + (size_t)(row0 + ar) * 256 + k0 + ak;
        float4 a0 = *(const float4*)asrc;
        float4 a1 = *(const float4*)(asrc + 4);
        if (A2) {
            const float* a2s = A2 + (size_t)(row0 + ar) * 256 + k0 + ak;
            float4 b0 = *(const float4*)a2s;
            float4 b1 = *(const float4*)(a2s + 4);
            a0.x += b0.x; a0.y += b0.y; a0.z += b0.z; a0.w += b0.w;
            a1.x += b1.x; a1.y += b1.y; a1.z += b1.z; a1.w += b1.w;
        }
        const float* wsrc = W + (size_t)(k0 + wr) * 256 + cb + wc;
        float4 w0 = *(const float4*)wsrc;
        float4 w1 = *(const float4*)(wsrc + 4);
        float4 w2 = *(const float4*)(wsrc + 8);
        float4 w3 = *(const float4*)(wsrc + 12);
        __syncthreads();
        Ast[ak + 0][ar] = a0.x; Ast[ak + 1][ar] = a0.y;
        Ast[ak + 2][ar] = a0.z; Ast[ak + 3][ar] = a0.w;
        Ast[ak + 4][ar] = a1.x; Ast[ak + 5][ar] = a1.y;
        Ast[ak + 6][ar] = a1.z; Ast[ak + 7][ar] = a1.w;
        *(float4*)&Wt[wr][wc + 0] = w0;
        *(float4*)&Wt[wr][wc + 4] = w1;
        *(float4*)&Wt[wr][wc + 8] = w2;
        *(float4*)&Wt[wr][wc + 12] = w3;
        __syncthreads();
        #pragma unroll
        for (int kk = 0; kk < 32; kk++) {
            const float4 a4 = *(const float4*)&Ast[kk][r0];
            const float4 wa = *(const float4*)&Wt[kk][c0];
            const float4 wb = *(const float4*)&Wt[kk][c0 + 4];
            const float av[4] = {a4.x, a4.y, a4.z, a4.w};
            const float wv[8] = {wa.x, wa.y, wa.z, wa.w, wb.x, wb.y, wb.z, wb.w};
            #pragma unroll
            for (int i = 0; i < 4; i++)
                #pragma unroll
                for (int j = 0; j < 8; j++) acc[i][j] += av[i] * wv[j];
        }
    }
    #pragma unroll
    for (int i = 0; i < 4; i++) {
        float* dst = out + (size_t)(row0 + r0 + i) * 256 + cb + c0;
        float4 o0 = make_float4(acc[i][0], acc[i][1], acc[i][2], acc[i][3]);
        float4 o1 = make_float4(acc[i][4], acc[i][5], acc[i][6], acc[i][7]);
        *(float4*)dst = o0;
        *(float4*)(dst + 4) = o1;
    }
}

// ---------------------------------------------------------------- prep kernels
__global__ __launch_bounds__(256) void prep_wqk(const float* __restrict__ Wqs,
                                                const float* __restrict__ Wks,
                                                float* __restrict__ Wqk2) {
    __shared__ __align__(16) float srow[512];
    const int c1 = blockIdx.x, c2 = threadIdx.x;
    srow[c2] = Wqs[c1 * 512 + c2];
    srow[c2 + 256] = Wqs[c1 * 512 + 256 + c2];
    __syncthreads();
    const float* wk = Wks + (size_t)c2 * 512;
    float acc = 0.f;
    for (int d = 0; d < 512; d += 4) {
        float4 a = *(const float4*)&srow[d];
        float4 b = *(const float4*)(wk + d);
        acc += a.x * b.x + a.y * b.y + a.z * b.z + a.w * b.w;
    }
    Wqk2[c1 * 256 + c2] = acc * 0.044194173824159216f;  // 1/sqrt(512)
}

__global__ __launch_bounds__(256) void prep_wcomb(const float* __restrict__ Wvs,
                                                  const float* __restrict__ Wfc,
                                                  float* __restrict__ Wcomb) {
    __shared__ float srow[512];
    const int c1 = blockIdx.x, c2 = threadIdx.x;
    srow[c2] = Wvs[c1 * 512 + c2];
    srow[c2 + 256] = Wvs[c1 * 512 + 256 + c2];
    __syncthreads();
    float acc = 0.f;
    for (int d = 0; d < 512; d++) acc += srow[d] * Wfc[d * 256 + c2];
    Wcomb[c1 * 256 + c2] = acc;
}

__global__ __launch_bounds__(256) void k_seed(const float* __restrict__ sv,
                                              const float* __restrict__ Ws,
                                              const float* __restrict__ Wqk2,
                                              float* __restrict__ seed,
                                              float* __restrict__ qhk) {
    const int q = blockIdx.x, b = blockIdx.y, c = threadIdx.x;
    __shared__ float ssv[256];
    __shared__ float sseed[256];
    ssv[c] = sv[((size_t)b * 256 + c) * 14 + q];
    __syncthreads();
    float acc = 0.f;
    for (int d = 0; d < 256; d++) acc += ssv[d] * Ws[d * 256 + c];
    seed[((size_t)b * 14 + q) * 256 + c] = acc;
    sseed[c] = acc;
    __syncthreads();
    float a2 = 0.f;
    for (int d = 0; d < 256; d++) a2 += sseed[d] * Wqk2[d * 256 + c];
    qhk[((size_t)b * 14 + q) * 256 + c] = a2;
}

// vv [b][m][c] fp32 -> vvT_hi/lo [b][c][m] bf16 split. grid(64,4,4), block 256.
__global__ __launch_bounds__(256) void k_vvsplit(const float* __restrict__ vv,
                                                 unsigned short* __restrict__ vvT_hi,
                                                 unsigned short* __restrict__ vvT_lo) {
    __shared__ float tile[64][65];   // [c][m]
    const int b = blockIdx.z, c0 = blockIdx.y * 64, m0 = blockIdx.x * 64;
    const int t = threadIdx.x;
    #pragma unroll
    for (int i = 0; i < 4; i++) {
        const int m = (t >> 4) + i * 16;
        const float4 v4 = *(const float4*)(vv + ((size_t)b * 4096 + m0 + m) * 256 + c0 + (t & 15) * 4);
        tile[(t & 15) * 4 + 0][m] = v4.x;
        tile[(t & 15) * 4 + 1][m] = v4.y;
        tile[(t & 15) * 4 + 2][m] = v4.z;
        tile[(t & 15) * 4 + 3][m] = v4.w;
    }
    __syncthreads();
    const int c = t >> 2, mo = (t & 3) * 16;
    U16x8 h0, h1, l0, l1;
    #pragma unroll
    for (int j = 0; j < 8; j++) {
        float x = tile[c][mo + j];
        unsigned short h = f2bf(x);
        h0.us[j] = h; l0.us[j] = f2bf(x - bf2f(h));
        float y = tile[c][mo + 8 + j];
        unsigned short h2 = f2bf(y);
        h1.us[j] = h2; l1.us[j] = f2bf(y - bf2f(h2));
    }
    const size_t off = ((size_t)b * 256 + c0 + c) * 4096 + m0 + mo;
    *(uint4*)(vvT_hi + off) = h0.u4;
    *(uint4*)(vvT_hi + off + 8) = h1.u4;
    *(uint4*)(vvT_lo + off) = l0.u4;
    *(uint4*)(vvT_lo + off + 8) = l1.u4;
}

// ---------------------------------------------------------------- stage-2 attention
__global__ __launch_bounds__(256) void k_logits1(const float* __restrict__ kk,
                                                 const float* __restrict__ qhk,
                                                 const int* __restrict__ supp,
                                                 float* __restrict__ logits) {
    const int b = blockIdx.y;
    const int n = blockIdx.x * 256 + threadIdx.x;
    __shared__ __align__(16) float sq[14][256];
    for (int i = threadIdx.x; i < 14 * 256; i += 256) sq[i >> 8][i & 255] = qhk[b * 14 * 256 + i];
    __syncthreads();
    float acc[14];
    #pragma unroll
    for (int q = 0; q < 14; q++) acc[q] = 0.f;
    const float* krow = kk + ((size_t)b * 4096 + n) * 256;
    for (int c = 0; c < 256; c += 4) {
        const float4 k4 = *(const float4*)(krow + c);
        #pragma unroll
        for (int q = 0; q < 14; q++) {
            const float4 a4 = *(const float4*)&sq[q][c];
            acc[q] += k4.x * a4.x + k4.y * a4.y + k4.z * a4.z + k4.w * a4.w;
        }
    }
    const bool msk = (supp[b * 4096 + n] == 0);
    #pragma unroll
    for (int q = 0; q < 14; q++)
        logits[((size_t)b * 14 + q) * 4096 + n] = msk ? -1e9f : acc[q];
}

__global__ __launch_bounds__(256) void k_softmax1(float* __restrict__ logits) {
    const int b = blockIdx.y, qq = blockIdx.x, t = threadIdx.x;
    __shared__ __align__(16) float sl[4096];
    __shared__ float sred[8];
    float* row = logits + ((size_t)b * 14 + qq) * 4096;
    float mx = -3e38f;
    for (int i = t; i < 4096; i += 256) { float v = row[i]; sl[i] = v; mx = fmaxf(mx, v); }
    #pragma unroll
    for (int off = 32; off; off >>= 1) mx = fmaxf(mx, __shfl_xor(mx, off, 64));
    if ((t & 63) == 0) sred[t >> 6] = mx;
    __syncthreads();
    mx = fmaxf(fmaxf(sred[0], sred[1]), fmaxf(sred[2], sred[3]));
    __syncthreads();
    float s = 0.f;
    for (int i = t; i < 4096; i += 256) { float e = expf(sl[i] - mx); sl[i] = e; s += e; }
    #pragma unroll
    for (int off = 32; off; off >>= 1) s += __shfl_xor(s, off, 64);
    if ((t & 63) == 0) sred[t >> 6] = s;
    __syncthreads();
    s = sred[0] + sred[1] + sred[2] + sred[3];
    const float inv = 1.f / s;
    for (int i = t; i < 4096; i += 256) row[i] = sl[i] * inv;
}

__global__ __launch_bounds__(256) void k_ctxv(const float* __restrict__ A,
                                              const float* __restrict__ vv,
                                              float* __restrict__ part) {
    const int b = blockIdx.y, ch = blockIdx.x, c = threadIdx.x;
    const int n0 = ch * 256;
    __shared__ __align__(16) float sA[14][256];
    for (int i = c; i < 14 * 256; i += 256) {
        int qq = i >> 8, j = i & 255;
        sA[qq][j] = A[((size_t)b * 14 + qq) * 4096 + n0 + j];
    }
    __syncthreads();
    float acc[14];
    #pragma unroll
    for (int q = 0; q < 14; q++) acc[q] = 0.f;
    for (int n = 0; n < 256; n += 4) {
        const float v0 = vv[((size_t)b * 4096 + n0 + n + 0) * 256 + c];
        const float v1 = vv[((size_t)b * 4096 + n0 + n + 1) * 256 + c];
        const float v2 = vv[((size_t)b * 4096 + n0 + n + 2) * 256 + c];
        const float v3 = vv[((size_t)b * 4096 + n0 + n + 3) * 256 + c];
        #pragma unroll
        for (int q = 0; q < 14; q++) {
            const float4 a4 = *(const float4*)&sA[q][n];
            acc[q] += a4.x * v0 + a4.y * v1 + a4.z * v2 + a4.w * v3;
        }
    }
    #pragma unroll
    for (int q = 0; q < 14; q++) part[(((size_t)b * 16 + ch) * 14 + q) * 256 + c] = acc[q];
}

__global__ __launch_bounds__(256) void k_proto(const float* __restrict__ part,
                                               const float* __restrict__ Wcomb,
                                               const float* __restrict__ bfc,
                                               const float* __restrict__ seed,
                                               const float* __restrict__ lng,
                                               const float* __restrict__ lnb,
                                               const float* __restrict__ Wsk,
                                               const float* __restrict__ Wsq,
                                               float* __restrict__ pkn,
                                               float* __restrict__ pqn) {
    const int q = blockIdx.x, b = blockIdx.y, c = threadIdx.x;
    __shared__ float sctx[256];
    __shared__ float sproto[256];
    __shared__ float sred[8];
    float cv = 0.f;
    for (int ch = 0; ch < 16; ch++) cv += part[(((size_t)b * 16 + ch) * 14 + q) * 256 + c];
    sctx[c] = cv;
    __syncthreads();
    float pre = 0.f;
    for (int d = 0; d < 256; d++) pre += sctx[d] * Wcomb[d * 256 + c];
    pre += bfc[c] + seed[((size_t)b * 14 + q) * 256 + c];
    const float mu = blockReduceSum256(pre, sred) * (1.f / 256.f);
    const float dv = pre - mu;
    const float var = blockReduceSum256(dv * dv, sred) * (1.f / 256.f);
    const float proto = dv * (1.f / sqrtf(var + 1e-5f)) * lng[c] + lnb[c];
    sproto[c] = proto;
    __syncthreads();
    float pk = 0.f, pq = 0.f;
    for (int d = 0; d < 256; d++) {
        const float sp = sproto[d];
        pk += sp * Wsk[d * 256 + c];
        pq += sp * Wsq[d * 256 + c];
    }
    const float nk = blockReduceSum256(pk * pk, sred);
    const float nq = blockReduceSum256(pq * pq, sred);
    pkn[((size_t)b * 14 + q) * 256 + c] = pk / fmaxf(sqrtf(nk), 1e-12f);
    pqn[((size_t)b * 14 + q) * 256 + c] = pq / fmaxf(sqrtf(nq), 1e-12f);
}

__global__ __launch_bounds__(256) void k_q2p(const float* __restrict__ qs,
                                             const float* __restrict__ kk,
                                             const float* __restrict__ pkn,
                                             const float* __restrict__ pqn,
                                             float* __restrict__ aq2p,
                                             float* __restrict__ attc,
                                             int* __restrict__ sidq) {
    const int b = blockIdx.y;
    const int n = blockIdx.x * 256 + threadIdx.x;
    __shared__ __align__(16) float spk[14][256];
    __shared__ __align__(16) float spq[14][256];
    for (int i = threadIdx.x; i < 14 * 256; i += 256) {
        spk[i >> 8][i & 255] = pkn[b * 14 * 256 + i];
        spq[i >> 8][i & 255] = pqn[b * 14 * 256 + i];
    }
    __syncthreads();
    float aq[14], ak[14];
    #pragma unroll
    for (int q = 0; q < 14; q++) { aq[q] = 0.f; ak[q] = 0.f; }
    float nq = 0.f, nk = 0.f;
    const float* qrow = qs + ((size_t)b * 4096 + n) * 256;
    const float* krow = kk + ((size_t)b * 4096 + n) * 256;
    for (int c = 0; c < 256; c += 4) {
        const float4 q4 = *(const float4*)(qrow + c);
        const float4 k4 = *(const float4*)(krow + c);
        nq += q4.x * q4.x + q4.y * q4.y + q4.z * q4.z + q4.w * q4.w;
        nk += k4.x * k4.x + k4.y * k4.y + k4.z * k4.z + k4.w * k4.w;
        #pragma unroll
        for (int q = 0; q < 14; q++) {
            const float4 p4 = *(const float4*)&spk[q][c];
            const float4 p4b = *(const float4*)&spq[q][c];
            aq[q] += q4.x * p4.x + q4.y * p4.y + q4.z * p4.z + q4.w * p4.w;
            ak[q] += k4.x * p4b.x + k4.y * p4b.y + k4.z * p4b.z + k4.w * p4b.w;
        }
    }
    const float sq_ = 1.f / fmaxf(sqrtf(nq), 1e-12f);
    const float sk_ = 1.f / fmaxf(sqrtf(nk), 1e-12f);
    float* aqrow = aq2p + ((size_t)b * 4096 + n) * 14;
    float* akrow = attc + ((size_t)b * 4096 + n) * 14;
    int best = 0;
    float bv = -3e38f;
    #pragma unroll
    for (int q = 0; q < 14; q++) {
        const float v = aq[q] * sq_;
        aqrow[q] = v;
        if (v > bv) { bv = v; best = q; }
        akrow[q] = ak[q] * sk_;
    }
    sidq[b * 4096 + n] = best;
}

// ---------------------------------------------------------------- Sinkhorn
__global__ __launch_bounds__(1024) void k_sinkhorn(const float* __restrict__ attc,
                                                   const int* __restrict__ supp,
                                                   float* __restrict__ as2p,
                                                   int* __restrict__ sids) {
    const int b = blockIdx.x;
    const int t = threadIdx.x;
    const int lane = t & 63, wid = t >> 6;
    __shared__ float wred[16][16];
    __shared__ float vsh[16];
    __shared__ float sbg[16];
    float K[4][15], u[4];
    float bgcnt = 0.f;
    #pragma unroll
    for (int j = 0; j < 4; j++) {
        const int n = t + j * 1024;
        const int sm = supp[b * 4096 + n];
        bgcnt += (sm == 0) ? 1.f : 0.f;
        const float* arow = attc + ((size_t)b * 4096 + n) * 14;
        #pragma unroll
        for (int m = 0; m < 14; m++) K[j][m] = expf(-20.f * (1.f - arow[m]));
        K[j][14] = (sm > 0) ? expf(-40.f) : 1.f;
        u[j] = 1.f / 4096.f;
    }
    #pragma unroll
    for (int off = 32; off; off >>= 1) bgcnt += __shfl_xor(bgcnt, off, 64);
    if (lane == 0) sbg[wid] = bgcnt;
    __syncthreads();
    float num_bg = 0.f;
    #pragma unroll
    for (int w = 0; w < 16; w++) num_bg += sbg[w];
    const float num_fg = 4096.f - num_bg;
    const float bm_fg = num_fg / (14.f * 4096.f);
    const float bm_tr = num_bg / 4096.f;
    const float a_n = 1.f / 4096.f;

    for (int it = 0; it < 100; it++) {
        #pragma unroll
        for (int m = 0; m < 15; m++) {
            float p = K[0][m] * u[0] + K[1][m] * u[1] + K[2][m] * u[2] + K[3][m] * u[3];
            #pragma unroll
            for (int off = 32; off; off >>= 1) p += __shfl_xor(p, off, 64);
            if (lane == 0) wred[wid][m] = p;
        }
        __syncthreads();
        if (t < 15) {
            float s = 0.f;
            #pragma unroll
            for (int w = 0; w < 16; w++) s += wred[w][t];
            const float bm = (t < 14) ? bm_fg : bm_tr;
            vsh[t] = bm / (s + 1e-16f);
        }
        __syncthreads();
        #pragma unroll
        for (int j = 0; j < 4; j++) {
            float s = 0.f;
            #pragma unroll
            for (int m = 0; m < 15; m++) s += K[j][m] * vsh[m];
            u[j] = a_n / (s + 1e-16f);
        }
    }
    #pragma unroll
    for (int j = 0; j < 4; j++) {
        const int n = t + j * 1024;
        float* orow = as2p + ((size_t)b * 4096 + n) * 14;
        float bv = -3e38f;
        int bi = 0;
        #pragma unroll
        for (int m = 0; m < 14; m++) {
            float tv = fmaxf(4096.f * u[j] * K[j][m] * vsh[m], 0.f);
            orow[m] = tv;
            if (tv > bv) { bv = tv; bi = m; }
        }
        sids[b * 4096 + n] = bi;
    }
}

// ---------------------------------------------------------------- big attention
__global__ __launch_bounds__(256) void k_phase1(const float* __restrict__ aq2p,
                                                const float* __restrict__ as2p,
                                                const int* __restrict__ sidq,
                                                const int* __restrict__ sids,
                                                const int* __restrict__ valid,
                                                float* __restrict__ spart) {
    const int b = blockIdx.z, ms = blockIdx.y;
    const int n = blockIdx.x * 256 + threadIdx.x;
    __shared__ float s2p[128 * 14];
    __shared__ int ssid[128], sval[128];
    float qv[14];
    const float* qrow = aq2p + ((size_t)b * 4096 + n) * 14;
    #pragma unroll
    for (int k2 = 0; k2 < 14; k2++) qv[k2] = qrow[k2];
    const int sq = sidq[b * 4096 + n];
    float s0 = 0.f, s1 = 0.f, s2 = 0.f;
    for (int m0 = ms * 1024; m0 < (ms + 1) * 1024; m0 += 128) {
        __syncthreads();
        for (int i = threadIdx.x; i < 128 * 14; i += 256)
            s2p[i] = as2p[((size_t)b * 4096 + m0) * 14 + i];
        if (threadIdx.x < 128) {
            ssid[threadIdx.x] = sids[b * 4096 + m0 + threadIdx.x];
            sval[threadIdx.x] = valid[b * 4096 + m0 + threadIdx.x];
        }
        __syncthreads();
        for (int mm = 0; mm < 128; mm++) {
            const float* sp = &s2p[mm * 14];
            float l = 0.f;
            #pragma unroll
            for (int k2 = 0; k2 < 14; k2++) l += qv[k2] * sp[k2];
            const int lvl = sval[mm] + (aligned_pt(ssid[mm], sq) ? 0 : 1);
            const float e = expf(l);
            s0 += (lvl == 0) ? e : 0.f;
            s1 += (lvl == 1) ? e : 0.f;
            s2 += (lvl == 2) ? e : 0.f;
        }
    }
    const int idx = ms * 16384 + b * 4096 + n;
    spart[idx * 3 + 0] = s0;
    spart[idx * 3 + 1] = s1;
    spart[idx * 3 + 2] = s2;
}

__global__ __launch_bounds__(256) void k_ph1merge(const float* __restrict__ spart,
                                                  int* __restrict__ lam,
                                                  float* __restrict__ rinv) {
    const int i = blockIdx.x * 256 + threadIdx.x;  // b*4096+n
    float s0 = 0.f, s1 = 0.f, s2 = 0.f;
    for (int ms = 0; ms < 4; ms++) {
        const float* p = spart + ((size_t)ms * 16384 + i) * 3;
        s0 += p[0]; s1 += p[1]; s2 += p[2];
    }
    const int l = (s0 > 0.f) ? 0 : ((s1 > 0.f) ? 1 : 2);
    const float sv = (l == 0) ? s0 : ((l == 1) ? s1 : s2);
    lam[i] = l;
    rinv[i] = 1.f / sv;
}

// phase2 MFMA: y[n,c] += p(n,m)*vv[m,c] via split-bf16, 3-product.
// grid(64,2,4) = (ntile64, msplit, b), block 256 (4 waves).
// wave w: MFMA rows n0+w*16..+15, all 256 c (16 D-tiles, 64 acc VGPR).
// p-compute: thread t handles n = n0+(t&63), m-slab = (t>>6)*8 per 32-chunk.
__global__ __launch_bounds__(256) void k_phase2_mfma(
    const float* __restrict__ aq2p, const float* __restrict__ as2p,
    const int* __restrict__ sidq, const int* __restrict__ sids,
    const int* __restrict__ valid, const int* __restrict__ lam,
    const float* __restrict__ rinv, const unsigned short* __restrict__ vvT_hi,
    const unsigned short* __restrict__ vvT_lo, float* __restrict__ ypart) {
    const int b = blockIdx.z, ms = blockIdx.y, nt = blockIdx.x;
    const int t = threadIdx.x;
    const int n0 = nt * 64;
    const int l = t & 63, wv = t >> 6;
    const int quad = l >> 4, lr = l & 15;

    // stride 40 bf16 (80 B): 16-B aligned frag reads, <=2-way bank aliasing (free)
    __shared__ unsigned short pAh[2][64 * 40];
    __shared__ unsigned short pAl[2][64 * 40];

    const int nloc = l;
    float qv[14];
    const float* qrow = aq2p + ((size_t)b * 4096 + n0 + nloc) * 14;
    #pragma unroll
    for (int k2 = 0; k2 < 14; k2++) qv[k2] = qrow[k2];
    const int sq = sidq[b * 4096 + n0 + nloc];
    const int mylam = lam[b * 4096 + n0 + nloc];
    const float myrinv = rinv[b * 4096 + n0 + nloc];
    const int msub = wv * 8;

    f32x4 acc[16];
    #pragma unroll
    for (int ct = 0; ct < 16; ct++) acc[ct] = (f32x4){0.f, 0.f, 0.f, 0.f};

    const unsigned short* bhbase = vvT_hi + ((size_t)(b * 256 + lr) * 4096);
    const unsigned short* blbase = vvT_lo + ((size_t)(b * 256 + lr) * 4096);

    for (int mt = 0; mt < 64; mt++) {
        const int mbase = ms * 2048 + mt * 32;
        const int buf = mt & 1;
        // ---- p for m = mbase+msub .. +7 (wave-uniform as2p rows -> broadcast)
        U16x8 hib, lob;
        const float* sp = as2p + ((size_t)b * 4096 + mbase + msub) * 14;
        const int* sidp = sids + b * 4096 + mbase + msub;
        const int* valp = valid + b * 4096 + mbase + msub;
        #pragma unroll
        for (int j = 0; j < 8; j++) {
            float lg = 0.f;
            #pragma unroll
            for (int k2 = 0; k2 < 14; k2++) lg += qv[k2] * sp[j * 14 + k2];
            const int lvl = valp[j] + (aligned_pt(sidp[j], sq) ? 0 : 1);
            const float p = (lvl == mylam) ? expf(lg) * myrinv : 0.f;
            const unsigned short h = f2bf(p);
            hib.us[j] = h;
            lob.us[j] = f2bf(p - bf2f(h));
        }
        *(uint4*)&pAh[buf][nloc * 40 + msub] = hib.u4;
        *(uint4*)&pAl[buf][nloc * 40 + msub] = lob.u4;
        __syncthreads();
        // ---- MFMA over this 32-m chunk
        U16x8 ah, al;
        ah.u4 = *(const uint4*)&pAh[buf][(wv * 16 + lr) * 40 + quad * 8];
        al.u4 = *(const uint4*)&pAl[buf][(wv * 16 + lr) * 40 + quad * 8];
        const size_t goff = (size_t)mbase + quad * 8;
        #pragma unroll
        for (int ct = 0; ct < 16; ct++) {
            U16x8 bh, bl;
            bh.u4 = *(const uint4*)(bhbase + (size_t)ct * 16 * 4096 + goff);
            bl.u4 = *(const uint4*)(blbase + (size_t)ct * 16 * 4096 + goff);
            acc[ct] = __builtin_amdgcn_mfma_f32_16x16x32_bf16(ah.s8, bh.s8, acc[ct], 0, 0, 0);
            acc[ct] = __builtin_amdgcn_mfma_f32_16x16x32_bf16(ah.s8, bl.s8, acc[ct], 0, 0, 0);
            acc[ct] = __builtin_amdgcn_mfma_f32_16x16x32_bf16(al.s8, bh.s8, acc[ct], 0, 0, 0);
        }
    }
    // epilogue: D row=(quad*4+r), col=lr per c-tile
    float* yp = ypart + ((size_t)ms * 4 + b) * 4096 * 256;
    #pragma unroll
    for (int ct = 0; ct < 16; ct++) {
        #pragma unroll
        for (int r = 0; r < 4; r++) {
            const int n = n0 + wv * 16 + quad * 4 + r;
            yp[(size_t)n * 256 + ct * 16 + lr] = acc[ct][r];
        }
    }
}

// ---------------------------------------------------------------- launch
extern "C" void kernel_launch(void* const* d_in, const int* in_sizes, int n_in,
                              void* d_out, int out_size, void* d_ws, size_t ws_size,
                              hipStream_t stream) {
    (void)in_sizes; (void)n_in; (void)out_size; (void)ws_size;
    const float* q    = (const float*)d_in[0];
    const float* k    = (const float*)d_in[1];
    const float* v    = (const float*)d_in[2];
    const float* sv   = (const float*)d_in[3];
    const int*  valid = (const int*)d_in[4];
    const int*  supp  = (const int*)d_in[5];
    const float* Wq   = (const float*)d_in[6];
    const float* Wk   = (const float*)d_in[7];
    const float* Wv   = (const float*)d_in[8];
    const float* Ws   = (const float*)d_in[9];
    const float* Wsq  = (const float*)d_in[10];
    const float* Wsk  = (const float*)d_in[11];
    const float* Wproj= (const float*)d_in[12];
    const float* Wqs  = (const float*)d_in[13];
    const float* Wks  = (const float*)d_in[14];
    const float* Wvs  = (const float*)d_in[15];
    const float* Wfc  = (const float*)d_in[16];
    const float* bfc  = (const float*)d_in[17];
    const float* lng  = (const float*)d_in[18];
    const float* lnb  = (const float*)d_in[19];

    float* ws = (float*)d_ws;
    float* qs   = ws + 0;         float* y0 = qs;   // qs dead before phase2 writes y0
    float* kk   = ws + 4194304;   float* y1 = kk;   // kk dead before phase2 writes y1
    float* vv   = ws + 8388608;
    float* wqk2 = ws + 12582912;
    float* wcomb= ws + 12648448;
    float* seed = ws + 12713984;
    float* qhk  = ws + 12728320;
    float* logA = ws + 12742656;
    float* cpart= ws + 12972032;
    float* pkn  = ws + 13201408;
    float* pqn  = ws + 13215744;
    float* aq2p = ws + 13230080;
    float* attc = ws + 13459456;
    float* as2p = ws + 13688832;
    float* spart= ws + 13918208;
    float* rinvb= ws + 14114816;
    int* lam  = (int*)(ws + 14131200);
    int* sidq = (int*)(ws + 14147584);
    int* sids = (int*)(ws + 14163968);
    unsigned short* vvT_hi = (unsigned short*)(ws + 14180352);  // 4x256x4096 bf16
    unsigned short* vvT_lo = (unsigned short*)(ws + 16277504);  // end: 18374656 floats (73.5 MB)

    gemm_aw<<<dim3(2, 256), 256, 0, stream>>>(q, nullptr, Wq, qs);
    gemm_aw<<<dim3(2, 256), 256, 0, stream>>>(k, nullptr, Wk, kk);
    gemm_aw<<<dim3(2, 256), 256, 0, stream>>>(v, nullptr, Wv, vv);
    k_vvsplit<<<dim3(64, 4, 4), 256, 0, stream>>>(vv, vvT_hi, vvT_lo);
    prep_wqk<<<256, 256, 0, stream>>>(Wqs, Wks, wqk2);
    prep_wcomb<<<256, 256, 0, stream>>>(Wvs, Wfc, wcomb);
    k_seed<<<dim3(14, 4), 256, 0, stream>>>(sv, Ws, wqk2, seed, qhk);
    k_logits1<<<dim3(16, 4), 256, 0, stream>>>(kk, qhk, supp, logA);
    k_softmax1<<<dim3(14, 4), 256, 0, stream>>>(logA);
    k_ctxv<<<dim3(16, 4), 256, 0, stream>>>(logA, vv, cpart);
    k_proto<<<dim3(14, 4), 256, 0, stream>>>(cpart, wcomb, bfc, seed, lng, lnb, Wsk, Wsq, pkn, pqn);
    k_q2p<<<dim3(16, 4), 256, 0, stream>>>(qs, kk, pkn, pqn, aq2p, attc, sidq);
    k_sinkhorn<<<4, 1024, 0, stream>>>(attc, supp, as2p, sids);
    k_phase1<<<dim3(16, 4, 4), 256, 0, stream>>>(aq2p, as2p, sidq, sids, valid, spart);
    k_ph1merge<<<64, 256, 0, stream>>>(spart, lam, rinvb);
    k_phase2_mfma<<<dim3(64, 2, 4), 256, 0, stream>>>(aq2p, as2p, sidq, sids, valid, lam,
                                                      rinvb, vvT_hi, vvT_lo, y0);
    gemm_aw<<<dim3(2, 256), 256, 0, stream>>>(y0, y1, Wproj, (float*)d_out);
}

// Round 3
// 1695.316 us; speedup vs baseline: 1.1660x; 1.0590x over previous
//
#include <hip/hip_runtime.h>
#include <math.h>

#define NB 4
#define NN 4096
#define NC 256
#define NQ 14

typedef __attribute__((ext_vector_type(8))) short short8;
typedef __attribute__((ext_vector_type(4))) float f32x4;
union U16x8 { uint4 u4; short8 s8; unsigned short us[8]; };

// address-space(4) = constant: guarantees s_load for wave-uniform reads
typedef __attribute__((address_space(4))) const float c4float;
typedef __attribute__((address_space(4))) const int c4int;

// ---------------------------------------------------------------- helpers
__device__ __forceinline__ bool aligned_pt(int ss, int sq) {
    // (2s+3)(2q+3) perfect square <=> equal square-free parts
    return (ss == sq) || ((ss == 0) && (sq == 12)) || ((ss == 12) && (sq == 0)) ||
           ((ss == 3) && (sq == 11)) || ((ss == 11) && (sq == 3));
}

__device__ __forceinline__ unsigned short f2bf(float x) {
    unsigned u = __float_as_uint(x);
    u += 0x7fff + ((u >> 16) & 1);   // RNE
    return (unsigned short)(u >> 16);
}
__device__ __forceinline__ float bf2f(unsigned short h) {
    return __uint_as_float(((unsigned)h) << 16);
}

__device__ __forceinline__ float blockReduceSum256(float v, float* sred) {
    #pragma unroll
    for (int off = 32; off; off >>= 1) v += __shfl_xor(v, off, 64);
    const int lane = threadIdx.x & 63, wid = threadIdx.x >> 6;
    if (lane == 0) sred[wid] = v;
    __syncthreads();
    float s = sred[0] + sred[1] + sred[2] + sred[3];
    __syncthreads();
    return s;
}

// ---------------------------------------------------------------- generic GEMM
// out[M,256] = (A (+A2)) @ W[256,256], M = 16384. grid(2,256), block 256.
__global__ __launch_bounds__(256) void gemm_aw(const float* __restrict__ A,
                                               const float* __restrict__ A2,
                                               const float* __restrict__ W,
                                               float* __restrict__ out) {
    const int t = threadIdx.x;
    const int row0 = blockIdx.y * 64;
    const int cb = blockIdx.x * 128;
    __shared__ __align__(16) float Ast[32][68];   // transposed A tile [k][r]
    __shared__ __align__(16) float Wt[32][132];   // W tile [k][c]
    const int r0 = (t & 15) * 4;
    const int c0 = (t >> 4) * 8;
    const int ar = t >> 2;          // 0..63
    const int ak = (t & 3) * 8;     // 0,8,16,24
    const int wr = t >> 3;          // 0..31
    const int wc = (t & 7) * 16;    // 0..112
    float acc[4][8];
    #pragma unroll
    for (int i = 0; i < 4; i++)
        #pragma unroll
        for (int j = 0; j < 8; j++) acc[i][j] = 0.f;

    for (int k0 = 0; k0 < 256; k0 += 32) {
        const float* asrc = A + (size_t)(row0 + ar) * 256 + k0 + ak;
        float4 a0 = *(const float4*)asrc;
        float4 a1 = *(const float4*)(asrc + 4);
        if (A2) {
            const float* a2s = A2 + (size_t)(row0 + ar) * 256 + k0 + ak;
            float4 b0 = *(const float4*)a2s;
            float4 b1 = *(const float4*)(a2s + 4);
            a0.x += b0.x; a0.y += b0.y; a0.z += b0.z; a0.w += b0.w;
            a1.x += b1.x; a1.y += b1.y; a1.z += b1.z; a1.w += b1.w;
        }
        const float* wsrc = W + (size_t)(k0 + wr) * 256 + cb + wc;
        float4 w0 = *(const float4*)wsrc;
        float4 w1 = *(const float4*)(wsrc + 4);
        float4 w2 = *(const float4*)(wsrc + 8);
        float4 w3 = *(const float4*)(wsrc + 12);
        __syncthreads();
        Ast[ak + 0][ar] = a0.x; Ast[ak + 1][ar] = a0.y;
        Ast[ak + 2][ar] = a0.z; Ast[ak + 3][ar] = a0.w;
        Ast[ak + 4][ar] = a1.x; Ast[ak + 5][ar] = a1.y;
        Ast[ak + 6][ar] = a1.z; Ast[ak + 7][ar] = a1.w;
        *(float4*)&Wt[wr][wc + 0] = w0;
        *(float4*)&Wt[wr][wc + 4] = w1;
        *(float4*)&Wt[wr][wc + 8] = w2;
        *(float4*)&Wt[wr][wc + 12] = w3;
        __syncthreads();
        #pragma unroll
        for (int kk = 0; kk < 32; kk++) {
            const float4 a4 = *(const float4*)&Ast[kk][r0];
            const float4 wa = *(const float4*)&Wt[kk][c0];
            const float4 wb = *(const float4*)&Wt[kk][c0 + 4];
            const float av[4] = {a4.x, a4.y, a4.z, a4.w};
            const float wv[8] = {wa.x, wa.y, wa.z, wa.w, wb.x, wb.y, wb.z, wb.w};
            #pragma unroll
            for (int i = 0; i < 4; i++)
                #pragma unroll
                for (int j = 0; j < 8; j++) acc[i][j] += av[i] * wv[j];
        }
    }
    #pragma unroll
    for (int i = 0; i < 4; i++) {
        float* dst = out + (size_t)(row0 + r0 + i) * 256 + cb + c0;
        float4 o0 = make_float4(acc[i][0], acc[i][1], acc[i][2], acc[i][3]);
        float4 o1 = make_float4(acc[i][4], acc[i][5], acc[i][6], acc[i][7]);
        *(float4*)dst = o0;
        *(float4*)(dst + 4) = o1;
    }
}

// ---------------------------------------------------------------- prep kernels
__global__ __launch_bounds__(256) void prep_wqk(const float* __restrict__ Wqs,
                                                const float* __restrict__ Wks,
                                                float* __restrict__ Wqk2) {
    __shared__ __align__(16) float srow[512];
    const int c1 = blockIdx.x, c2 = threadIdx.x;
    srow[c2] = Wqs[c1 * 512 + c2];
    srow[c2 + 256] = Wqs[c1 * 512 + 256 + c2];
    __syncthreads();
    const float* wk = Wks + (size_t)c2 * 512;
    float acc = 0.f;
    for (int d = 0; d < 512; d += 4) {
        float4 a = *(const float4*)&srow[d];
        float4 b = *(const float4*)(wk + d);
        acc += a.x * b.x + a.y * b.y + a.z * b.z + a.w * b.w;
    }
    Wqk2[c1 * 256 + c2] = acc * 0.044194173824159216f;  // 1/sqrt(512)
}

__global__ __launch_bounds__(256) void prep_wcomb(const float* __restrict__ Wvs,
                                                  const float* __restrict__ Wfc,
                                                  float* __restrict__ Wcomb) {
    __shared__ float srow[512];
    const int c1 = blockIdx.x, c2 = threadIdx.x;
    srow[c2] = Wvs[c1 * 512 + c2];
    srow[c2 + 256] = Wvs[c1 * 512 + 256 + c2];
    __syncthreads();
    float acc = 0.f;
    for (int d = 0; d < 512; d++) acc += srow[d] * Wfc[d * 256 + c2];
    Wcomb[c1 * 256 + c2] = acc;
}

__global__ __launch_bounds__(256) void k_seed(const float* __restrict__ sv,
                                              const float* __restrict__ Ws,
                                              const float* __restrict__ Wqk2,
                                              float* __restrict__ seed,
                                              float* __restrict__ qhk) {
    const int q = blockIdx.x, b = blockIdx.y, c = threadIdx.x;
    __shared__ float ssv[256];
    __shared__ float sseed[256];
    ssv[c] = sv[((size_t)b * 256 + c) * 14 + q];
    __syncthreads();
    float acc = 0.f;
    for (int d = 0; d < 256; d++) acc += ssv[d] * Ws[d * 256 + c];
    seed[((size_t)b * 14 + q) * 256 + c] = acc;
    sseed[c] = acc;
    __syncthreads();
    float a2 = 0.f;
    for (int d = 0; d < 256; d++) a2 += sseed[d] * Wqk2[d * 256 + c];
    qhk[((size_t)b * 14 + q) * 256 + c] = a2;
}

// vv [b][m][c] fp32 -> vvT_hi/lo [b][c][m] bf16 split. grid(64,4,4), block 256.
__global__ __launch_bounds__(256) void k_vvsplit(const float* __restrict__ vv,
                                                 unsigned short* __restrict__ vvT_hi,
                                                 unsigned short* __restrict__ vvT_lo) {
    __shared__ float tile[64][65];   // [c][m]
    const int b = blockIdx.z, c0 = blockIdx.y * 64, m0 = blockIdx.x * 64;
    const int t = threadIdx.x;
    #pragma unroll
    for (int i = 0; i < 4; i++) {
        const int m = (t >> 4) + i * 16;
        const float4 v4 = *(const float4*)(vv + ((size_t)b * 4096 + m0 + m) * 256 + c0 + (t & 15) * 4);
        tile[(t & 15) * 4 + 0][m] = v4.x;
        tile[(t & 15) * 4 + 1][m] = v4.y;
        tile[(t & 15) * 4 + 2][m] = v4.z;
        tile[(t & 15) * 4 + 3][m] = v4.w;
    }
    __syncthreads();
    const int c = t >> 2, mo = (t & 3) * 16;
    U16x8 h0, h1, l0, l1;
    #pragma unroll
    for (int j = 0; j < 8; j++) {
        float x = tile[c][mo + j];
        unsigned short h = f2bf(x);
        h0.us[j] = h; l0.us[j] = f2bf(x - bf2f(h));
        float y = tile[c][mo + 8 + j];
        unsigned short h2 = f2bf(y);
        h1.us[j] = h2; l1.us[j] = f2bf(y - bf2f(h2));
    }
    const size_t off = ((size_t)b * 256 + c0 + c) * 4096 + m0 + mo;
    *(uint4*)(vvT_hi + off) = h0.u4;
    *(uint4*)(vvT_hi + off + 8) = h1.u4;
    *(uint4*)(vvT_lo + off) = l0.u4;
    *(uint4*)(vvT_lo + off + 8) = l1.u4;
}

// ---------------------------------------------------------------- stage-2 attention
__global__ __launch_bounds__(256) void k_logits1(const float* __restrict__ kk,
                                                 const float* __restrict__ qhk,
                                                 const int* __restrict__ supp,
                                                 float* __restrict__ logits) {
    const int b = blockIdx.y;
    const int n = blockIdx.x * 256 + threadIdx.x;
    __shared__ __align__(16) float sq[14][256];
    for (int i = threadIdx.x; i < 14 * 256; i += 256) sq[i >> 8][i & 255] = qhk[b * 14 * 256 + i];
    __syncthreads();
    float acc[14];
    #pragma unroll
    for (int q = 0; q < 14; q++) acc[q] = 0.f;
    const float* krow = kk + ((size_t)b * 4096 + n) * 256;
    for (int c = 0; c < 256; c += 4) {
        const float4 k4 = *(const float4*)(krow + c);
        #pragma unroll
        for (int q = 0; q < 14; q++) {
            const float4 a4 = *(const float4*)&sq[q][c];
            acc[q] += k4.x * a4.x + k4.y * a4.y + k4.z * a4.z + k4.w * a4.w;
        }
    }
    const bool msk = (supp[b * 4096 + n] == 0);
    #pragma unroll
    for (int q = 0; q < 14; q++)
        logits[((size_t)b * 14 + q) * 4096 + n] = msk ? -1e9f : acc[q];
}

__global__ __launch_bounds__(256) void k_softmax1(float* __restrict__ logits) {
    const int b = blockIdx.y, qq = blockIdx.x, t = threadIdx.x;
    __shared__ __align__(16) float sl[4096];
    __shared__ float sred[8];
    float* row = logits + ((size_t)b * 14 + qq) * 4096;
    float mx = -3e38f;
    for (int i = t; i < 4096; i += 256) { float v = row[i]; sl[i] = v; mx = fmaxf(mx, v); }
    #pragma unroll
    for (int off = 32; off; off >>= 1) mx = fmaxf(mx, __shfl_xor(mx, off, 64));
    if ((t & 63) == 0) sred[t >> 6] = mx;
    __syncthreads();
    mx = fmaxf(fmaxf(sred[0], sred[1]), fmaxf(sred[2], sred[3]));
    __syncthreads();
    float s = 0.f;
    for (int i = t; i < 4096; i += 256) { float e = expf(sl[i] - mx); sl[i] = e; s += e; }
    #pragma unroll
    for (int off = 32; off; off >>= 1) s += __shfl_xor(s, off, 64);
    if ((t & 63) == 0) sred[t >> 6] = s;
    __syncthreads();
    s = sred[0] + sred[1] + sred[2] + sred[3];
    const float inv = 1.f / s;
    for (int i = t; i < 4096; i += 256) row[i] = sl[i] * inv;
}

__global__ __launch_bounds__(256) void k_ctxv(const float* __restrict__ A,
                                              const float* __restrict__ vv,
                                              float* __restrict__ part) {
    const int b = blockIdx.y, ch = blockIdx.x, c = threadIdx.x;
    const int n0 = ch * 256;
    __shared__ __align__(16) float sA[14][256];
    for (int i = c; i < 14 * 256; i += 256) {
        int qq = i >> 8, j = i & 255;
        sA[qq][j] = A[((size_t)b * 14 + qq) * 4096 + n0 + j];
    }
    __syncthreads();
    float acc[14];
    #pragma unroll
    for (int q = 0; q < 14; q++) acc[q] = 0.f;
    for (int n = 0; n < 256; n += 4) {
        const float v0 = vv[((size_t)b * 4096 + n0 + n + 0) * 256 + c];
        const float v1 = vv[((size_t)b * 4096 + n0 + n + 1) * 256 + c];
        const float v2 = vv[((size_t)b * 4096 + n0 + n + 2) * 256 + c];
        const float v3 = vv[((size_t)b * 4096 + n0 + n + 3) * 256 + c];
        #pragma unroll
        for (int q = 0; q < 14; q++) {
            const float4 a4 = *(const float4*)&sA[q][n];
            acc[q] += a4.x * v0 + a4.y * v1 + a4.z * v2 + a4.w * v3;
        }
    }
    #pragma unroll
    for (int q = 0; q < 14; q++) part[(((size_t)b * 16 + ch) * 14 + q) * 256 + c] = acc[q];
}

__global__ __launch_bounds__(256) void k_proto(const float* __restrict__ part,
                                               const float* __restrict__ Wcomb,
                                               const float* __restrict__ bfc,
                                               const float* __restrict__ seed,
                                               const float* __restrict__ lng,
                                               const float* __restrict__ lnb,
                                               const float* __restrict__ Wsk,
                                               const float* __restrict__ Wsq,
                                               float* __restrict__ pkn,
                                               float* __restrict__ pqn) {
    const int q = blockIdx.x, b = blockIdx.y, c = threadIdx.x;
    __shared__ float sctx[256];
    __shared__ float sproto[256];
    __shared__ float sred[8];
    float cv = 0.f;
    for (int ch = 0; ch < 16; ch++) cv += part[(((size_t)b * 16 + ch) * 14 + q) * 256 + c];
    sctx[c] = cv;
    __syncthreads();
    float pre = 0.f;
    for (int d = 0; d < 256; d++) pre += sctx[d] * Wcomb[d * 256 + c];
    pre += bfc[c] + seed[((size_t)b * 14 + q) * 256 + c];
    const float mu = blockReduceSum256(pre, sred) * (1.f / 256.f);
    const float dv = pre - mu;
    const float var = blockReduceSum256(dv * dv, sred) * (1.f / 256.f);
    const float proto = dv * (1.f / sqrtf(var + 1e-5f)) * lng[c] + lnb[c];
    sproto[c] = proto;
    __syncthreads();
    float pk = 0.f, pq = 0.f;
    for (int d = 0; d < 256; d++) {
        const float sp = sproto[d];
        pk += sp * Wsk[d * 256 + c];
        pq += sp * Wsq[d * 256 + c];
    }
    const float nk = blockReduceSum256(pk * pk, sred);
    const float nq = blockReduceSum256(pq * pq, sred);
    pkn[((size_t)b * 14 + q) * 256 + c] = pk / fmaxf(sqrtf(nk), 1e-12f);
    pqn[((size_t)b * 14 + q) * 256 + c] = pq / fmaxf(sqrtf(nq), 1e-12f);
}

__global__ __launch_bounds__(256) void k_q2p(const float* __restrict__ qs,
                                             const float* __restrict__ kk,
                                             const float* __restrict__ pkn,
                                             const float* __restrict__ pqn,
                                             float* __restrict__ aq2p,
                                             float* __restrict__ attc,
                                             int* __restrict__ sidq) {
    const int b = blockIdx.y;
    const int n = blockIdx.x * 256 + threadIdx.x;
    __shared__ __align__(16) float spk[14][256];
    __shared__ __align__(16) float spq[14][256];
    for (int i = threadIdx.x; i < 14 * 256; i += 256) {
        spk[i >> 8][i & 255] = pkn[b * 14 * 256 + i];
        spq[i >> 8][i & 255] = pqn[b * 14 * 256 + i];
    }
    __syncthreads();
    float aq[14], ak[14];
    #pragma unroll
    for (int q = 0; q < 14; q++) { aq[q] = 0.f; ak[q] = 0.f; }
    float nq = 0.f, nk = 0.f;
    const float* qrow = qs + ((size_t)b * 4096 + n) * 256;
    const float* krow = kk + ((size_t)b * 4096 + n) * 256;
    for (int c = 0; c < 256; c += 4) {
        const float4 q4 = *(const float4*)(qrow + c);
        const float4 k4 = *(const float4*)(krow + c);
        nq += q4.x * q4.x + q4.y * q4.y + q4.z * q4.z + q4.w * q4.w;
        nk += k4.x * k4.x + k4.y * k4.y + k4.z * k4.z + k4.w * k4.w;
        #pragma unroll
        for (int q = 0; q < 14; q++) {
            const float4 p4 = *(const float4*)&spk[q][c];
            const float4 p4b = *(const float4*)&spq[q][c];
            aq[q] += q4.x * p4.x + q4.y * p4.y + q4.z * p4.z + q4.w * p4.w;
            ak[q] += k4.x * p4b.x + k4.y * p4b.y + k4.z * p4b.z + k4.w * p4b.w;
        }
    }
    const float sq_ = 1.f / fmaxf(sqrtf(nq), 1e-12f);
    const float sk_ = 1.f / fmaxf(sqrtf(nk), 1e-12f);
    float* aqrow = aq2p + ((size_t)b * 4096 + n) * 14;
    float* akrow = attc + ((size_t)b * 4096 + n) * 14;
    int best = 0;
    float bv = -3e38f;
    #pragma unroll
    for (int q = 0; q < 14; q++) {
        const float v = aq[q] * sq_;
        aqrow[q] = v;
        if (v > bv) { bv = v; best = q; }
        akrow[q] = ak[q] * sk_;
    }
    sidq[b * 4096 + n] = best;
}

// ---------------------------------------------------------------- Sinkhorn
// as2p written with row stride 16 (padded) for 64B-aligned scalar loads downstream.
__global__ __launch_bounds__(1024) void k_sinkhorn(const float* __restrict__ attc,
                                                   const int* __restrict__ supp,
                                                   float* __restrict__ as2p,
                                                   int* __restrict__ sids) {
    const int b = blockIdx.x;
    const int t = threadIdx.x;
    const int lane = t & 63, wid = t >> 6;
    __shared__ float wred[16][16];
    __shared__ float vsh[16];
    __shared__ float sbg[16];
    float K[4][15], u[4];
    float bgcnt = 0.f;
    #pragma unroll
    for (int j = 0; j < 4; j++) {
        const int n = t + j * 1024;
        const int sm = supp[b * 4096 + n];
        bgcnt += (sm == 0) ? 1.f : 0.f;
        const float* arow = attc + ((size_t)b * 4096 + n) * 14;
        #pragma unroll
        for (int m = 0; m < 14; m++) K[j][m] = expf(-20.f * (1.f - arow[m]));
        K[j][14] = (sm > 0) ? expf(-40.f) : 1.f;
        u[j] = 1.f / 4096.f;
    }
    #pragma unroll
    for (int off = 32; off; off >>= 1) bgcnt += __shfl_xor(bgcnt, off, 64);
    if (lane == 0) sbg[wid] = bgcnt;
    __syncthreads();
    float num_bg = 0.f;
    #pragma unroll
    for (int w = 0; w < 16; w++) num_bg += sbg[w];
    const float num_fg = 4096.f - num_bg;
    const float bm_fg = num_fg / (14.f * 4096.f);
    const float bm_tr = num_bg / 4096.f;
    const float a_n = 1.f / 4096.f;

    for (int it = 0; it < 100; it++) {
        #pragma unroll
        for (int m = 0; m < 15; m++) {
            float p = K[0][m] * u[0] + K[1][m] * u[1] + K[2][m] * u[2] + K[3][m] * u[3];
            #pragma unroll
            for (int off = 32; off; off >>= 1) p += __shfl_xor(p, off, 64);
            if (lane == 0) wred[wid][m] = p;
        }
        __syncthreads();
        if (t < 15) {
            float s = 0.f;
            #pragma unroll
            for (int w = 0; w < 16; w++) s += wred[w][t];
            const float bm = (t < 14) ? bm_fg : bm_tr;
            vsh[t] = bm / (s + 1e-16f);
        }
        __syncthreads();
        #pragma unroll
        for (int j = 0; j < 4; j++) {
            float s = 0.f;
            #pragma unroll
            for (int m = 0; m < 15; m++) s += K[j][m] * vsh[m];
            u[j] = a_n / (s + 1e-16f);
        }
    }
    #pragma unroll
    for (int j = 0; j < 4; j++) {
        const int n = t + j * 1024;
        float* orow = as2p + (((size_t)b * 4096 + n) << 4);
        float bv = -3e38f;
        int bi = 0;
        #pragma unroll
        for (int m = 0; m < 14; m++) {
            float tv = fmaxf(4096.f * u[j] * K[j][m] * vsh[m], 0.f);
            orow[m] = tv;
            if (tv > bv) { bv = tv; bi = m; }
        }
        sids[b * 4096 + n] = bi;
    }
}

// ---------------------------------------------------------------- lam table
// lam for row n depends only on sq[n]: lamtab masks m0 (level-0 exists), m1.
__global__ __launch_bounds__(256) void k_lamtab(const int* __restrict__ sids,
                                                const int* __restrict__ valid,
                                                int* __restrict__ lamtab) {
    const int b = blockIdx.x, t = threadIdx.x;
    __shared__ int sm0[4], sm1[4];
    int m0 = 0, m1 = 0;
    for (int m = t; m < 4096; m += 256) {
        const int s = sids[b * 4096 + m];
        const int v = valid[b * 4096 + m];
        int mask = (1 << s);
        if (s == 0) mask |= (1 << 12);
        else if (s == 12) mask |= 1;
        else if (s == 3) mask |= (1 << 11);
        else if (s == 11) mask |= (1 << 3);
        const int nmask = (~mask) & 0x3fff;
        if (v == 0) { m0 |= mask; m1 |= nmask; }
        else { m1 |= mask; }
    }
    #pragma unroll
    for (int off = 32; off; off >>= 1) {
        m0 |= __shfl_xor(m0, off, 64);
        m1 |= __shfl_xor(m1, off, 64);
    }
    if ((t & 63) == 0) { sm0[t >> 6] = m0; sm1[t >> 6] = m1; }
    __syncthreads();
    if (t == 0) {
        lamtab[b * 2 + 0] = sm0[0] | sm0[1] | sm0[2] | sm0[3];
        lamtab[b * 2 + 1] = sm1[0] | sm1[1] | sm1[2] | sm1[3];
    }
}

// ---------------------------------------------------------------- big attention (fused)
// y[n,c] = (1/rsum_n) * sum_m p'(n,m)*vv[m,c], p' = exp(l)*[lvl==lam].
// grid 256 (b = bid&3 for XCD L2 locality), block 512 (8 waves: 4 n-groups x 2 c-halves).
// p-compute: thread (l, wv): n = n0+l, m-slab = wv*8 within the 64-m chunk;
// as2p/sids/valid read via s_load (AS4 + readfirstlane). Split-bf16 3-product MFMA.
__global__ __launch_bounds__(512) void k_phase2_mfma(
    const float* __restrict__ aq2p, const float* __restrict__ as2p,
    const int* __restrict__ sidq, const int* __restrict__ sids,
    const int* __restrict__ valid, const int* __restrict__ lamtab,
    const unsigned short* __restrict__ vvT_hi,
    const unsigned short* __restrict__ vvT_lo, float* __restrict__ y) {
    const int bid = blockIdx.x;
    const int b = bid & 3, nt = bid >> 2;
    const int t = threadIdx.x;
    const int n0 = nt * 64;
    const int l = t & 63, wv = t >> 6;       // wv 0..7
    const int quad = l >> 4, lr = l & 15;
    const int wn = wv & 3, wc = wv >> 2;     // n-group, c-half

    // kb-swizzled A-operand staging: row stride 64 bf16, block kb' = kb ^ (row&7)
    __shared__ __align__(16) unsigned short pAh[2][64][64];
    __shared__ __align__(16) unsigned short pAl[2][64][64];
    __shared__ float rsums[8][64];

    const int nloc = l;
    float qv[14];
    const float* qrow = aq2p + ((size_t)b * 4096 + n0 + nloc) * 14;
    #pragma unroll
    for (int k2 = 0; k2 < 14; k2++) qv[k2] = qrow[k2];
    const int sq = sidq[b * 4096 + n0 + nloc];
    const int lm0 = lamtab[b * 2 + 0], lm1 = lamtab[b * 2 + 1];
    const int mylam = ((lm0 >> sq) & 1) ? 0 : (((lm1 >> sq) & 1) ? 1 : 2);
    const int msub = wv * 8;
    const int wswz = (wv ^ (nloc & 7)) * 8;
    float rsum = 0.f;

    f32x4 acc[8];
    #pragma unroll
    for (int ct = 0; ct < 8; ct++) acc[ct] = (f32x4){0.f, 0.f, 0.f, 0.f};

    const unsigned short* bhbase = vvT_hi + ((size_t)(b * 256 + wc * 128 + lr) * 4096);
    const unsigned short* blbase = vvT_lo + ((size_t)(b * 256 + wc * 128 + lr) * 4096);

    for (int mt = 0; mt < 64; mt++) {
        const int mbase = mt * 64;
        const int buf = mt & 1;
        // ---- scalar-load uniform slab data (8 m rows)
        const int sofs = __builtin_amdgcn_readfirstlane(b * 4096 + mbase + msub);
        c4float* sp = (c4float*)(uintptr_t)(as2p + ((size_t)sofs << 4));
        c4int* sidp = (c4int*)(uintptr_t)(sids + sofs);
        c4int* valp = (c4int*)(uintptr_t)(valid + sofs);
        U16x8 hib, lob;
        #pragma unroll
        for (int j = 0; j < 8; j++) {
            float lg = 0.f;
            #pragma unroll
            for (int k2 = 0; k2 < 14; k2++) lg += qv[k2] * sp[j * 16 + k2];
            const int lvl = valp[j] + (aligned_pt(sidp[j], sq) ? 0 : 1);
            const float p = (lvl == mylam) ? __expf(lg) : 0.f;
            rsum += p;
            const unsigned u = __float_as_uint(p);
            hib.us[j] = (unsigned short)(u >> 16);                 // trunc hi
            const float lo = p - __uint_as_float(u & 0xffff0000u);
            lob.us[j] = (unsigned short)(__float_as_uint(lo) >> 16);  // trunc lo
        }
        *(uint4*)&pAh[buf][nloc][wswz] = hib.u4;
        *(uint4*)&pAl[buf][nloc][wswz] = lob.u4;
        __syncthreads();
        // ---- MFMA over this 64-m chunk (2 k-subchunks of 32)
        U16x8 ah[2], al[2];
        #pragma unroll
        for (int kc = 0; kc < 2; kc++) {
            const int row = wn * 16 + lr;
            const int kbs = ((kc * 4 + quad) ^ (row & 7)) * 8;
            ah[kc].u4 = *(const uint4*)&pAh[buf][row][kbs];
            al[kc].u4 = *(const uint4*)&pAl[buf][row][kbs];
        }
        const size_t go = (size_t)mbase + quad * 8;
        #pragma unroll
        for (int kc = 0; kc < 2; kc++) {
            #pragma unroll
            for (int ct = 0; ct < 8; ct++) {
                U16x8 bh, bl;
                bh.u4 = *(const uint4*)(bhbase + (size_t)ct * 16 * 4096 + go + kc * 32);
                bl.u4 = *(const uint4*)(blbase + (size_t)ct * 16 * 4096 + go + kc * 32);
                acc[ct] = __builtin_amdgcn_mfma_f32_16x16x32_bf16(ah[kc].s8, bh.s8, acc[ct], 0, 0, 0);
                acc[ct] = __builtin_amdgcn_mfma_f32_16x16x32_bf16(ah[kc].s8, bl.s8, acc[ct], 0, 0, 0);
                acc[ct] = __builtin_amdgcn_mfma_f32_16x16x32_bf16(al[kc].s8, bh.s8, acc[ct], 0, 0, 0);
            }
        }
    }
    rsums[wv][nloc] = rsum;
    __syncthreads();
    // epilogue: row = wn*16 + quad*4 + r, col = wc*128 + ct*16 + lr, scale by 1/rsum
    #pragma unroll
    for (int r = 0; r < 4; r++) {
        const int row = wn * 16 + quad * 4 + r;
        float rs = 0.f;
        #pragma unroll
        for (int w = 0; w < 8; w++) rs += rsums[w][row];
        const float rinv = 1.f / rs;
        float* dst = y + ((size_t)b * 4096 + n0 + row) * 256 + wc * 128 + lr;
        #pragma unroll
        for (int ct = 0; ct < 8; ct++) dst[ct * 16] = acc[ct][r] * rinv;
    }
}

// ---------------------------------------------------------------- launch
extern "C" void kernel_launch(void* const* d_in, const int* in_sizes, int n_in,
                              void* d_out, int out_size, void* d_ws, size_t ws_size,
                              hipStream_t stream) {
    (void)in_sizes; (void)n_in; (void)out_size; (void)ws_size;
    const float* q    = (const float*)d_in[0];
    const float* k    = (const float*)d_in[1];
    const float* v    = (const float*)d_in[2];
    const float* sv   = (const float*)d_in[3];
    const int*  valid = (const int*)d_in[4];
    const int*  supp  = (const int*)d_in[5];
    const float* Wq   = (const float*)d_in[6];
    const float* Wk   = (const float*)d_in[7];
    const float* Wv   = (const float*)d_in[8];
    const float* Ws   = (const float*)d_in[9];
    const float* Wsq  = (const float*)d_in[10];
    const float* Wsk  = (const float*)d_in[11];
    const float* Wproj= (const float*)d_in[12];
    const float* Wqs  = (const float*)d_in[13];
    const float* Wks  = (const float*)d_in[14];
    const float* Wvs  = (const float*)d_in[15];
    const float* Wfc  = (const float*)d_in[16];
    const float* bfc  = (const float*)d_in[17];
    const float* lng  = (const float*)d_in[18];
    const float* lnb  = (const float*)d_in[19];

    float* ws = (float*)d_ws;
    float* qs   = ws + 0;         float* y0 = qs;   // qs dead before phase2 writes y0
    float* kk   = ws + 4194304;
    float* vv   = ws + 8388608;
    float* wqk2 = ws + 12582912;
    float* wcomb= ws + 12648448;
    float* seed = ws + 12713984;
    float* qhk  = ws + 12728320;
    float* logA = ws + 12742656;
    float* cpart= ws + 12972032;
    float* pkn  = ws + 13201408;
    float* pqn  = ws + 13215744;
    float* aq2p = ws + 13230080;
    float* attc = ws + 13459456;
    float* as2p = ws + 13688832;                    // [b][4096][16] padded
    int* sidq = (int*)(ws + 13950976);
    int* sids = (int*)(ws + 13967360);
    int* lamtab = (int*)(ws + 13983744);
    unsigned short* vvT_hi = (unsigned short*)(ws + 14180352);  // 4x256x4096 bf16
    unsigned short* vvT_lo = (unsigned short*)(ws + 16277504);  // end 18374656 floats (73.5 MB)

    gemm_aw<<<dim3(2, 256), 256, 0, stream>>>(q, nullptr, Wq, qs);
    gemm_aw<<<dim3(2, 256), 256, 0, stream>>>(k, nullptr, Wk, kk);
    gemm_aw<<<dim3(2, 256), 256, 0, stream>>>(v, nullptr, Wv, vv);
    k_vvsplit<<<dim3(64, 4, 4), 256, 0, stream>>>(vv, vvT_hi, vvT_lo);
    prep_wqk<<<256, 256, 0, stream>>>(Wqs, Wks, wqk2);
    prep_wcomb<<<256, 256, 0, stream>>>(Wvs, Wfc, wcomb);
    k_seed<<<dim3(14, 4), 256, 0, stream>>>(sv, Ws, wqk2, seed, qhk);
    k_logits1<<<dim3(16, 4), 256, 0, stream>>>(kk, qhk, supp, logA);
    k_softmax1<<<dim3(14, 4), 256, 0, stream>>>(logA);
    k_ctxv<<<dim3(16, 4), 256, 0, stream>>>(logA, vv, cpart);
    k_proto<<<dim3(14, 4), 256, 0, stream>>>(cpart, wcomb, bfc, seed, lng, lnb, Wsk, Wsq, pkn, pqn);
    k_q2p<<<dim3(16, 4), 256, 0, stream>>>(qs, kk, pkn, pqn, aq2p, attc, sidq);
    k_sinkhorn<<<4, 1024, 0, stream>>>(attc, supp, as2p, sids);
    k_lamtab<<<4, 256, 0, stream>>>(sids, valid, lamtab);
    k_phase2_mfma<<<256, 512, 0, stream>>>(aq2p, as2p, sidq, sids, valid, lamtab,
                                           vvT_hi, vvT_lo, y0);
    gemm_aw<<<dim3(2, 256), 256, 0, stream>>>(y0, nullptr, Wproj, (float*)d_out);
}

// Round 4
// 1349.686 us; speedup vs baseline: 1.4646x; 1.2561x over previous
//
#include <hip/hip_runtime.h>
#include <math.h>

#define NB 4
#define NN 4096
#define NC 256
#define NQ 14

typedef __attribute__((ext_vector_type(8))) short short8;
typedef __attribute__((ext_vector_type(4))) float f32x4;
typedef _Float16 f16x8 __attribute__((ext_vector_type(8)));
union UH8 { uint4 u4; f16x8 h8; _Float16 h[8]; };

// ---------------------------------------------------------------- helpers
__device__ __forceinline__ float blockReduceSum256(float v, float* sred) {
    #pragma unroll
    for (int off = 32; off; off >>= 1) v += __shfl_xor(v, off, 64);
    const int lane = threadIdx.x & 63, wid = threadIdx.x >> 6;
    if (lane == 0) sred[wid] = v;
    __syncthreads();
    float s = sred[0] + sred[1] + sred[2] + sred[3];
    __syncthreads();
    return s;
}

// ---------------------------------------------------------------- generic GEMM
// out[M,256] = A @ W[256,256], M = 16384. grid(2,256), block 256.
__global__ __launch_bounds__(256) void gemm_aw(const float* __restrict__ A,
                                               const float* __restrict__ W,
                                               float* __restrict__ out) {
    const int t = threadIdx.x;
    const int row0 = blockIdx.y * 64;
    const int cb = blockIdx.x * 128;
    __shared__ __align__(16) float Ast[32][68];   // transposed A tile [k][r]
    __shared__ __align__(16) float Wt[32][132];   // W tile [k][c]
    const int r0 = (t & 15) * 4;
    const int c0 = (t >> 4) * 8;
    const int ar = t >> 2;          // 0..63
    const int ak = (t & 3) * 8;     // 0,8,16,24
    const int wr = t >> 3;          // 0..31
    const int wc = (t & 7) * 16;    // 0..112
    float acc[4][8];
    #pragma unroll
    for (int i = 0; i < 4; i++)
        #pragma unroll
        for (int j = 0; j < 8; j++) acc[i][j] = 0.f;

    for (int k0 = 0; k0 < 256; k0 += 32) {
        const float* asrc = A + (size_t)(row0 + ar) * 256 + k0 + ak;
        float4 a0 = *(const float4*)asrc;
        float4 a1 = *(const float4*)(asrc + 4);
        const float* wsrc = W + (size_t)(k0 + wr) * 256 + cb + wc;
        float4 w0 = *(const float4*)wsrc;
        float4 w1 = *(const float4*)(wsrc + 4);
        float4 w2 = *(const float4*)(wsrc + 8);
        float4 w3 = *(const float4*)(wsrc + 12);
        __syncthreads();
        Ast[ak + 0][ar] = a0.x; Ast[ak + 1][ar] = a0.y;
        Ast[ak + 2][ar] = a0.z; Ast[ak + 3][ar] = a0.w;
        Ast[ak + 4][ar] = a1.x; Ast[ak + 5][ar] = a1.y;
        Ast[ak + 6][ar] = a1.z; Ast[ak + 7][ar] = a1.w;
        *(float4*)&Wt[wr][wc + 0] = w0;
        *(float4*)&Wt[wr][wc + 4] = w1;
        *(float4*)&Wt[wr][wc + 8] = w2;
        *(float4*)&Wt[wr][wc + 12] = w3;
        __syncthreads();
        #pragma unroll
        for (int kk = 0; kk < 32; kk++) {
            const float4 a4 = *(const float4*)&Ast[kk][r0];
            const float4 wa = *(const float4*)&Wt[kk][c0];
            const float4 wb = *(const float4*)&Wt[kk][c0 + 4];
            const float av[4] = {a4.x, a4.y, a4.z, a4.w};
            const float wv[8] = {wa.x, wa.y, wa.z, wa.w, wb.x, wb.y, wb.z, wb.w};
            #pragma unroll
            for (int i = 0; i < 4; i++)
                #pragma unroll
                for (int j = 0; j < 8; j++) acc[i][j] += av[i] * wv[j];
        }
    }
    #pragma unroll
    for (int i = 0; i < 4; i++) {
        float* dst = out + (size_t)(row0 + r0 + i) * 256 + cb + c0;
        *(float4*)dst = make_float4(acc[i][0], acc[i][1], acc[i][2], acc[i][3]);
        *(float4*)(dst + 4) = make_float4(acc[i][4], acc[i][5], acc[i][6], acc[i][7]);
    }
}

// ---------------------------------------------------------------- prep kernels
__global__ __launch_bounds__(256) void prep_wqk(const float* __restrict__ Wqs,
                                                const float* __restrict__ Wks,
                                                float* __restrict__ Wqk2) {
    __shared__ __align__(16) float srow[512];
    const int c1 = blockIdx.x, c2 = threadIdx.x;
    srow[c2] = Wqs[c1 * 512 + c2];
    srow[c2 + 256] = Wqs[c1 * 512 + 256 + c2];
    __syncthreads();
    const float* wk = Wks + (size_t)c2 * 512;
    float acc = 0.f;
    for (int d = 0; d < 512; d += 4) {
        float4 a = *(const float4*)&srow[d];
        float4 b = *(const float4*)(wk + d);
        acc += a.x * b.x + a.y * b.y + a.z * b.z + a.w * b.w;
    }
    Wqk2[c1 * 256 + c2] = acc * 0.044194173824159216f;  // 1/sqrt(512)
}

__global__ __launch_bounds__(256) void prep_wcomb(const float* __restrict__ Wvs,
                                                  const float* __restrict__ Wfc,
                                                  float* __restrict__ Wcomb) {
    __shared__ float srow[512];
    const int c1 = blockIdx.x, c2 = threadIdx.x;
    srow[c2] = Wvs[c1 * 512 + c2];
    srow[c2 + 256] = Wvs[c1 * 512 + 256 + c2];
    __syncthreads();
    float acc = 0.f;
    for (int d = 0; d < 512; d++) acc += srow[d] * Wfc[d * 256 + c2];
    Wcomb[c1 * 256 + c2] = acc;
}

__global__ __launch_bounds__(256) void k_seed(const float* __restrict__ sv,
                                              const float* __restrict__ Ws,
                                              const float* __restrict__ Wqk2,
                                              float* __restrict__ seed,
                                              float* __restrict__ qhk) {
    const int q = blockIdx.x, b = blockIdx.y, c = threadIdx.x;
    __shared__ float ssv[256];
    __shared__ float sseed[256];
    ssv[c] = sv[((size_t)b * 256 + c) * 14 + q];
    __syncthreads();
    float acc = 0.f;
    for (int d = 0; d < 256; d++) acc += ssv[d] * Ws[d * 256 + c];
    seed[((size_t)b * 14 + q) * 256 + c] = acc;
    sseed[c] = acc;
    __syncthreads();
    float a2 = 0.f;
    for (int d = 0; d < 256; d++) a2 += sseed[d] * Wqk2[d * 256 + c];
    qhk[((size_t)b * 14 + q) * 256 + c] = a2;
}

// vv [b][m][c] fp32 -> vvT_h [b][c][m] fp16. grid(64,4,4), block 256.
__global__ __launch_bounds__(256) void k_vvhalf(const float* __restrict__ vv,
                                                _Float16* __restrict__ vvT_h) {
    __shared__ float tile[64][65];   // [c][m]
    const int b = blockIdx.z, c0 = blockIdx.y * 64, m0 = blockIdx.x * 64;
    const int t = threadIdx.x;
    #pragma unroll
    for (int i = 0; i < 4; i++) {
        const int m = (t >> 4) + i * 16;
        const float4 v4 = *(const float4*)(vv + ((size_t)b * 4096 + m0 + m) * 256 + c0 + (t & 15) * 4);
        tile[(t & 15) * 4 + 0][m] = v4.x;
        tile[(t & 15) * 4 + 1][m] = v4.y;
        tile[(t & 15) * 4 + 2][m] = v4.z;
        tile[(t & 15) * 4 + 3][m] = v4.w;
    }
    __syncthreads();
    const int c = t >> 2, mo = (t & 3) * 16;
    UH8 o0, o1;
    #pragma unroll
    for (int j = 0; j < 8; j++) {
        o0.h[j] = (_Float16)tile[c][mo + j];
        o1.h[j] = (_Float16)tile[c][mo + 8 + j];
    }
    const size_t off = ((size_t)b * 256 + c0 + c) * 4096 + m0 + mo;
    *(uint4*)(vvT_h + off) = o0.u4;
    *(uint4*)(vvT_h + off + 8) = o1.u4;
}

// ---------------------------------------------------------------- stage-2 attention
__global__ __launch_bounds__(256) void k_logits1(const float* __restrict__ kk,
                                                 const float* __restrict__ qhk,
                                                 const int* __restrict__ supp,
                                                 float* __restrict__ logits) {
    const int b = blockIdx.y;
    const int n = blockIdx.x * 256 + threadIdx.x;
    __shared__ __align__(16) float sq[14][256];
    for (int i = threadIdx.x; i < 14 * 256; i += 256) sq[i >> 8][i & 255] = qhk[b * 14 * 256 + i];
    __syncthreads();
    float acc[14];
    #pragma unroll
    for (int q = 0; q < 14; q++) acc[q] = 0.f;
    const float* krow = kk + ((size_t)b * 4096 + n) * 256;
    for (int c = 0; c < 256; c += 4) {
        const float4 k4 = *(const float4*)(krow + c);
        #pragma unroll
        for (int q = 0; q < 14; q++) {
            const float4 a4 = *(const float4*)&sq[q][c];
            acc[q] += k4.x * a4.x + k4.y * a4.y + k4.z * a4.z + k4.w * a4.w;
        }
    }
    const bool msk = (supp[b * 4096 + n] == 0);
    #pragma unroll
    for (int q = 0; q < 14; q++)
        logits[((size_t)b * 14 + q) * 4096 + n] = msk ? -1e9f : acc[q];
}

__global__ __launch_bounds__(256) void k_softmax1(float* __restrict__ logits) {
    const int b = blockIdx.y, qq = blockIdx.x, t = threadIdx.x;
    __shared__ __align__(16) float sl[4096];
    __shared__ float sred[8];
    float* row = logits + ((size_t)b * 14 + qq) * 4096;
    float mx = -3e38f;
    for (int i = t; i < 4096; i += 256) { float v = row[i]; sl[i] = v; mx = fmaxf(mx, v); }
    #pragma unroll
    for (int off = 32; off; off >>= 1) mx = fmaxf(mx, __shfl_xor(mx, off, 64));
    if ((t & 63) == 0) sred[t >> 6] = mx;
    __syncthreads();
    mx = fmaxf(fmaxf(sred[0], sred[1]), fmaxf(sred[2], sred[3]));
    __syncthreads();
    float s = 0.f;
    for (int i = t; i < 4096; i += 256) { float e = expf(sl[i] - mx); sl[i] = e; s += e; }
    #pragma unroll
    for (int off = 32; off; off >>= 1) s += __shfl_xor(s, off, 64);
    if ((t & 63) == 0) sred[t >> 6] = s;
    __syncthreads();
    s = sred[0] + sred[1] + sred[2] + sred[3];
    const float inv = 1.f / s;
    for (int i = t; i < 4096; i += 256) row[i] = sl[i] * inv;
}

__global__ __launch_bounds__(256) void k_ctxv(const float* __restrict__ A,
                                              const float* __restrict__ vv,
                                              float* __restrict__ part) {
    const int b = blockIdx.y, ch = blockIdx.x, c = threadIdx.x;
    const int n0 = ch * 256;
    __shared__ __align__(16) float sA[14][256];
    for (int i = c; i < 14 * 256; i += 256) {
        int qq = i >> 8, j = i & 255;
        sA[qq][j] = A[((size_t)b * 14 + qq) * 4096 + n0 + j];
    }
    __syncthreads();
    float acc[14];
    #pragma unroll
    for (int q = 0; q < 14; q++) acc[q] = 0.f;
    for (int n = 0; n < 256; n += 4) {
        const float v0 = vv[((size_t)b * 4096 + n0 + n + 0) * 256 + c];
        const float v1 = vv[((size_t)b * 4096 + n0 + n + 1) * 256 + c];
        const float v2 = vv[((size_t)b * 4096 + n0 + n + 2) * 256 + c];
        const float v3 = vv[((size_t)b * 4096 + n0 + n + 3) * 256 + c];
        #pragma unroll
        for (int q = 0; q < 14; q++) {
            const float4 a4 = *(const float4*)&sA[q][n];
            acc[q] += a4.x * v0 + a4.y * v1 + a4.z * v2 + a4.w * v3;
        }
    }
    #pragma unroll
    for (int q = 0; q < 14; q++) part[(((size_t)b * 16 + ch) * 14 + q) * 256 + c] = acc[q];
}

__global__ __launch_bounds__(256) void k_proto(const float* __restrict__ part,
                                               const float* __restrict__ Wcomb,
                                               const float* __restrict__ bfc,
                                               const float* __restrict__ seed,
                                               const float* __restrict__ lng,
                                               const float* __restrict__ lnb,
                                               const float* __restrict__ Wsk,
                                               const float* __restrict__ Wsq,
                                               float* __restrict__ pkn,
                                               float* __restrict__ pqn) {
    const int q = blockIdx.x, b = blockIdx.y, c = threadIdx.x;
    __shared__ float sctx[256];
    __shared__ float sproto[256];
    __shared__ float sred[8];
    float cv = 0.f;
    for (int ch = 0; ch < 16; ch++) cv += part[(((size_t)b * 16 + ch) * 14 + q) * 256 + c];
    sctx[c] = cv;
    __syncthreads();
    float pre = 0.f;
    for (int d = 0; d < 256; d++) pre += sctx[d] * Wcomb[d * 256 + c];
    pre += bfc[c] + seed[((size_t)b * 14 + q) * 256 + c];
    const float mu = blockReduceSum256(pre, sred) * (1.f / 256.f);
    const float dv = pre - mu;
    const float var = blockReduceSum256(dv * dv, sred) * (1.f / 256.f);
    const float proto = dv * (1.f / sqrtf(var + 1e-5f)) * lng[c] + lnb[c];
    sproto[c] = proto;
    __syncthreads();
    float pk = 0.f, pq = 0.f;
    for (int d = 0; d < 256; d++) {
        const float sp = sproto[d];
        pk += sp * Wsk[d * 256 + c];
        pq += sp * Wsq[d * 256 + c];
    }
    const float nk = blockReduceSum256(pk * pk, sred);
    const float nq = blockReduceSum256(pq * pq, sred);
    pkn[((size_t)b * 14 + q) * 256 + c] = pk / fmaxf(sqrtf(nk), 1e-12f);
    pqn[((size_t)b * 14 + q) * 256 + c] = pq / fmaxf(sqrtf(nq), 1e-12f);
}

__global__ __launch_bounds__(256) void k_q2p(const float* __restrict__ qs,
                                             const float* __restrict__ kk,
                                             const float* __restrict__ pkn,
                                             const float* __restrict__ pqn,
                                             float* __restrict__ aq2p,
                                             float* __restrict__ attc,
                                             int* __restrict__ sidq) {
    const int b = blockIdx.y;
    const int n = blockIdx.x * 256 + threadIdx.x;
    __shared__ __align__(16) float spk[14][256];
    __shared__ __align__(16) float spq[14][256];
    for (int i = threadIdx.x; i < 14 * 256; i += 256) {
        spk[i >> 8][i & 255] = pkn[b * 14 * 256 + i];
        spq[i >> 8][i & 255] = pqn[b * 14 * 256 + i];
    }
    __syncthreads();
    float aq[14], ak[14];
    #pragma unroll
    for (int q = 0; q < 14; q++) { aq[q] = 0.f; ak[q] = 0.f; }
    float nq = 0.f, nk = 0.f;
    const float* qrow = qs + ((size_t)b * 4096 + n) * 256;
    const float* krow = kk + ((size_t)b * 4096 + n) * 256;
    for (int c = 0; c < 256; c += 4) {
        const float4 q4 = *(const float4*)(qrow + c);
        const float4 k4 = *(const float4*)(krow + c);
        nq += q4.x * q4.x + q4.y * q4.y + q4.z * q4.z + q4.w * q4.w;
        nk += k4.x * k4.x + k4.y * k4.y + k4.z * k4.z + k4.w * k4.w;
        #pragma unroll
        for (int q = 0; q < 14; q++) {
            const float4 p4 = *(const float4*)&spk[q][c];
            const float4 p4b = *(const float4*)&spq[q][c];
            aq[q] += q4.x * p4.x + q4.y * p4.y + q4.z * p4.z + q4.w * p4.w;
            ak[q] += k4.x * p4b.x + k4.y * p4b.y + k4.z * p4b.z + k4.w * p4b.w;
        }
    }
    const float sq_ = 1.f / fmaxf(sqrtf(nq), 1e-12f);
    const float sk_ = 1.f / fmaxf(sqrtf(nk), 1e-12f);
    float* aqrow = aq2p + ((size_t)b * 4096 + n) * 14;
    float* akrow = attc + ((size_t)b * 4096 + n) * 14;
    int best = 0;
    float bv = -3e38f;
    #pragma unroll
    for (int q = 0; q < 14; q++) {
        const float v = aq[q] * sq_;
        aqrow[q] = v;
        if (v > bv) { bv = v; best = q; }
        akrow[q] = ak[q] * sk_;
    }
    sidq[b * 4096 + n] = best;
}

// ---------------------------------------------------------------- Sinkhorn
// outputs: as2pT [b][k=14][m] k-major, and code[m] = alignmask | (valid<<14)
__global__ __launch_bounds__(1024) void k_sinkhorn(const float* __restrict__ attc,
                                                   const int* __restrict__ supp,
                                                   const int* __restrict__ valid,
                                                   float* __restrict__ as2pT,
                                                   int* __restrict__ code) {
    const int b = blockIdx.x;
    const int t = threadIdx.x;
    const int lane = t & 63, wid = t >> 6;
    __shared__ float wred[16][16];
    __shared__ float vsh[16];
    __shared__ float sbg[16];
    float K[4][15], u[4];
    float bgcnt = 0.f;
    #pragma unroll
    for (int j = 0; j < 4; j++) {
        const int n = t + j * 1024;
        const int sm = supp[b * 4096 + n];
        bgcnt += (sm == 0) ? 1.f : 0.f;
        const float* arow = attc + ((size_t)b * 4096 + n) * 14;
        #pragma unroll
        for (int m = 0; m < 14; m++) K[j][m] = expf(-20.f * (1.f - arow[m]));
        K[j][14] = (sm > 0) ? expf(-40.f) : 1.f;
        u[j] = 1.f / 4096.f;
    }
    #pragma unroll
    for (int off = 32; off; off >>= 1) bgcnt += __shfl_xor(bgcnt, off, 64);
    if (lane == 0) sbg[wid] = bgcnt;
    __syncthreads();
    float num_bg = 0.f;
    #pragma unroll
    for (int w = 0; w < 16; w++) num_bg += sbg[w];
    const float num_fg = 4096.f - num_bg;
    const float bm_fg = num_fg / (14.f * 4096.f);
    const float bm_tr = num_bg / 4096.f;
    const float a_n = 1.f / 4096.f;

    for (int it = 0; it < 100; it++) {
        #pragma unroll
        for (int m = 0; m < 15; m++) {
            float p = K[0][m] * u[0] + K[1][m] * u[1] + K[2][m] * u[2] + K[3][m] * u[3];
            #pragma unroll
            for (int off = 32; off; off >>= 1) p += __shfl_xor(p, off, 64);
            if (lane == 0) wred[wid][m] = p;
        }
        __syncthreads();
        if (t < 15) {
            float s = 0.f;
            #pragma unroll
            for (int w = 0; w < 16; w++) s += wred[w][t];
            const float bm = (t < 14) ? bm_fg : bm_tr;
            vsh[t] = bm / (s + 1e-16f);
        }
        __syncthreads();
        #pragma unroll
        for (int j = 0; j < 4; j++) {
            float s = 0.f;
            #pragma unroll
            for (int m = 0; m < 15; m++) s += K[j][m] * vsh[m];
            u[j] = a_n / (s + 1e-16f);
        }
    }
    #pragma unroll
    for (int j = 0; j < 4; j++) {
        const int n = t + j * 1024;
        float bv = -3e38f;
        int bi = 0;
        #pragma unroll
        for (int m = 0; m < 14; m++) {
            float tv = fmaxf(4096.f * u[j] * K[j][m] * vsh[m], 0.f);
            as2pT[((size_t)(b * 14 + m)) * 4096 + n] = tv;
            if (tv > bv) { bv = tv; bi = m; }
        }
        int msk = 1 << bi;
        if (bi == 0) msk |= (1 << 12);
        else if (bi == 12) msk |= 1;
        else if (bi == 3) msk |= (1 << 11);
        else if (bi == 11) msk |= (1 << 3);
        code[b * 4096 + n] = msk | (valid[b * 4096 + n] << 14);
    }
}

// ---------------------------------------------------------------- lam table
__global__ __launch_bounds__(256) void k_lamtab(const int* __restrict__ code,
                                                int* __restrict__ lamtab) {
    const int b = blockIdx.x, t = threadIdx.x;
    __shared__ int sm0[4], sm1[4];
    int m0 = 0, m1 = 0;
    for (int m = t; m < 4096; m += 256) {
        const int c = code[b * 4096 + m];
        const int mask = c & 0x3fff;
        const int v = c >> 14;
        const int nmask = (~mask) & 0x3fff;
        if (v == 0) { m0 |= mask; m1 |= nmask; }
        else { m1 |= mask; }
    }
    #pragma unroll
    for (int off = 32; off; off >>= 1) {
        m0 |= __shfl_xor(m0, off, 64);
        m1 |= __shfl_xor(m1, off, 64);
    }
    if ((t & 63) == 0) { sm0[t >> 6] = m0; sm1[t >> 6] = m1; }
    __syncthreads();
    if (t == 0) {
        lamtab[b * 2 + 0] = sm0[0] | sm0[1] | sm0[2] | sm0[3];
        lamtab[b * 2 + 1] = sm1[0] | sm1[1] | sm1[2] | sm1[3];
    }
}

// ---------------------------------------------------------------- P materialization
// P[b][n][m] (fp16, unnormalized) and rinv[b][n]. grid(512,4), block 256.
// thread (nloc=t>>5, mlane=t&31): n = bx*8+nloc, m = g*128 + mlane*4 (g<32).
__global__ __launch_bounds__(256) void k_pmat(const float* __restrict__ aq2p,
                                              const float* __restrict__ as2pT,
                                              const int* __restrict__ code,
                                              const int* __restrict__ sidq,
                                              const int* __restrict__ lamtab,
                                              _Float16* __restrict__ P,
                                              float* __restrict__ rinv) {
    const int b = blockIdx.y;
    const int t = threadIdx.x;
    const int nloc = t >> 5, mlane = t & 31;
    const int n = blockIdx.x * 8 + nloc;
    float qv[14];
    const float* qrow = aq2p + ((size_t)b * 4096 + n) * 14;
    #pragma unroll
    for (int k = 0; k < 14; k++) qv[k] = qrow[k];
    const int sq = sidq[b * 4096 + n];
    const int lm0 = lamtab[b * 2 + 0], lm1 = lamtab[b * 2 + 1];
    const int mylam = ((lm0 >> sq) & 1) ? 0 : (((lm1 >> sq) & 1) ? 1 : 2);
    float rsum = 0.f;
    _Float16* prow = P + ((size_t)b * 4096 + n) * 4096;
    const float* abase = as2pT + (size_t)b * 14 * 4096;
    const int* cbase = code + b * 4096;

    for (int g = 0; g < 32; g++) {
        const int m = g * 128 + mlane * 4;
        const int4 cd = *(const int4*)(cbase + m);
        f32x4 lv = {0.f, 0.f, 0.f, 0.f};
        #pragma unroll
        for (int k = 0; k < 14; k++) {
            const f32x4 a = *(const f32x4*)(abase + (size_t)k * 4096 + m);
            lv += qv[k] * a;
        }
        const int cj[4] = {cd.x, cd.y, cd.z, cd.w};
        union { uint2 u2; _Float16 h[4]; } o;
        #pragma unroll
        for (int j = 0; j < 4; j++) {
            const int lvl = (cj[j] >> 14) + 1 - ((cj[j] >> sq) & 1);
            const float p = (lvl == mylam) ? __expf(lv[j]) : 0.f;
            rsum += p;
            o.h[j] = (_Float16)p;
        }
        *(uint2*)(prow + m) = o.u2;
    }
    #pragma unroll
    for (int off = 1; off < 32; off <<= 1) rsum += __shfl_xor(rsum, off, 64);
    if (mlane == 0) rinv[b * 4096 + n] = 1.f / rsum;
}

// ---------------------------------------------------------------- PV GEMM (fp16 MFMA)
// y[b][n][c] = rinv[n] * P[n][:] @ vv[:][c]. grid(64,4), block 512 (8 waves:
// wn = wave&3 -> 16-row slab of the 64-n tile, wc = wave>>2 -> c-half).
// No LDS, no barriers: A-frags straight from P rows, B-frags from vvT_h.
__global__ __launch_bounds__(512) void k_pv(const _Float16* __restrict__ P,
                                            const _Float16* __restrict__ vvT_h,
                                            const float* __restrict__ rinv,
                                            float* __restrict__ y) {
    const int b = blockIdx.y, nt = blockIdx.x;
    const int t = threadIdx.x;
    const int l = t & 63, wv = t >> 6;
    const int wn = wv & 3, wc = wv >> 2;
    const int quad = l >> 4, lr = l & 15;
    const int row = nt * 64 + wn * 16 + lr;
    const _Float16* arow = P + (((size_t)b * 4096 + row) * 4096) + quad * 8;
    const _Float16* bbase = vvT_h + ((size_t)(b * 256 + wc * 128 + lr) * 4096) + quad * 8;

    f32x4 acc[8];
    #pragma unroll
    for (int ct = 0; ct < 8; ct++) acc[ct] = (f32x4){0.f, 0.f, 0.f, 0.f};

    uint4 aR = *(const uint4*)(arow);
    uint4 bR[8];
    #pragma unroll
    for (int ct = 0; ct < 8; ct++) bR[ct] = *(const uint4*)(bbase + (size_t)ct * 16 * 4096);

    for (int it = 0; it < 128; it++) {
        const int k1 = (it < 127) ? (it + 1) * 32 : 0;
        uint4 aN = *(const uint4*)(arow + k1);
        uint4 bN[8];
        #pragma unroll
        for (int ct = 0; ct < 8; ct++) bN[ct] = *(const uint4*)(bbase + (size_t)ct * 16 * 4096 + k1);
        #pragma unroll
        for (int ct = 0; ct < 8; ct++) {
            UH8 a, bb;
            a.u4 = aR; bb.u4 = bR[ct];
            acc[ct] = __builtin_amdgcn_mfma_f32_16x16x32_f16(a.h8, bb.h8, acc[ct], 0, 0, 0);
        }
        aR = aN;
        #pragma unroll
        for (int ct = 0; ct < 8; ct++) bR[ct] = bN[ct];
    }
    #pragma unroll
    for (int r = 0; r < 4; r++) {
        const int rowd = nt * 64 + wn * 16 + quad * 4 + r;
        const float ri = rinv[b * 4096 + rowd];
        float* dst = y + ((size_t)b * 4096 + rowd) * 256 + wc * 128 + lr;
        #pragma unroll
        for (int ct = 0; ct < 8; ct++) dst[ct * 16] = acc[ct][r] * ri;
    }
}

// ---------------------------------------------------------------- launch
extern "C" void kernel_launch(void* const* d_in, const int* in_sizes, int n_in,
                              void* d_out, int out_size, void* d_ws, size_t ws_size,
                              hipStream_t stream) {
    (void)in_sizes; (void)n_in; (void)out_size; (void)ws_size;
    const float* q    = (const float*)d_in[0];
    const float* k    = (const float*)d_in[1];
    const float* v    = (const float*)d_in[2];
    const float* sv   = (const float*)d_in[3];
    const int*  valid = (const int*)d_in[4];
    const int*  supp  = (const int*)d_in[5];
    const float* Wq   = (const float*)d_in[6];
    const float* Wk   = (const float*)d_in[7];
    const float* Wv   = (const float*)d_in[8];
    const float* Ws   = (const float*)d_in[9];
    const float* Wsq  = (const float*)d_in[10];
    const float* Wsk  = (const float*)d_in[11];
    const float* Wproj= (const float*)d_in[12];
    const float* Wqs  = (const float*)d_in[13];
    const float* Wks  = (const float*)d_in[14];
    const float* Wvs  = (const float*)d_in[15];
    const float* Wfc  = (const float*)d_in[16];
    const float* bfc  = (const float*)d_in[17];
    const float* lng  = (const float*)d_in[18];
    const float* lnb  = (const float*)d_in[19];

    float* ws = (float*)d_ws;
    // P (fp16 4x4096x4096 = 33,554,432 floats) overlays qs/kk/vv (dead by k_pmat)
    _Float16* P = (_Float16*)ws;
    float* qs   = ws + 0;
    float* kk   = ws + 4194304;
    float* vv   = ws + 8388608;
    float* y0   = ws + 33554432;
    float* wqk2 = ws + 37748736;
    float* wcomb= ws + 37814272;
    float* seed = ws + 37879808;
    float* qhk  = ws + 37894144;
    float* logA = ws + 37908480;
    float* cpart= ws + 38137856;
    float* pkn  = ws + 38367232;
    float* pqn  = ws + 38381568;
    float* aq2p = ws + 38395904;
    float* attc = ws + 38625280;
    float* as2pT= ws + 38854656;
    int* code   = (int*)(ws + 39084032);
    int* sidq   = (int*)(ws + 39100416);
    int* lamtab = (int*)(ws + 39116800);
    float* rinvb= ws + 39116816;
    _Float16* vvT_h = (_Float16*)(ws + 39133216);  // end ~41.2M floats (165 MB)

    gemm_aw<<<dim3(2, 256), 256, 0, stream>>>(q, Wq, qs);
    gemm_aw<<<dim3(2, 256), 256, 0, stream>>>(k, Wk, kk);
    gemm_aw<<<dim3(2, 256), 256, 0, stream>>>(v, Wv, vv);
    k_vvhalf<<<dim3(64, 4, 4), 256, 0, stream>>>(vv, vvT_h);
    prep_wqk<<<256, 256, 0, stream>>>(Wqs, Wks, wqk2);
    prep_wcomb<<<256, 256, 0, stream>>>(Wvs, Wfc, wcomb);
    k_seed<<<dim3(14, 4), 256, 0, stream>>>(sv, Ws, wqk2, seed, qhk);
    k_logits1<<<dim3(16, 4), 256, 0, stream>>>(kk, qhk, supp, logA);
    k_softmax1<<<dim3(14, 4), 256, 0, stream>>>(logA);
    k_ctxv<<<dim3(16, 4), 256, 0, stream>>>(logA, vv, cpart);
    k_proto<<<dim3(14, 4), 256, 0, stream>>>(cpart, wcomb, bfc, seed, lng, lnb, Wsk, Wsq, pkn, pqn);
    k_q2p<<<dim3(16, 4), 256, 0, stream>>>(qs, kk, pkn, pqn, aq2p, attc, sidq);
    k_sinkhorn<<<4, 1024, 0, stream>>>(attc, supp, valid, as2pT, code);
    k_lamtab<<<4, 256, 0, stream>>>(code, lamtab);
    k_pmat<<<dim3(512, 4), 256, 0, stream>>>(aq2p, as2pT, code, sidq, lamtab, P, rinvb);
    k_pv<<<dim3(64, 4), 512, 0, stream>>>(P, vvT_h, rinvb, y0);
    gemm_aw<<<dim3(2, 256), 256, 0, stream>>>(y0, Wproj, (float*)d_out);
}

// Round 5
// 1225.862 us; speedup vs baseline: 1.6126x; 1.1010x over previous
//
#include <hip/hip_runtime.h>
#include <math.h>

#define NB 4
#define NN 4096
#define NC 256
#define NQ 14

typedef __attribute__((ext_vector_type(8))) short short8;
typedef __attribute__((ext_vector_type(4))) float f32x4;
typedef _Float16 f16x8 __attribute__((ext_vector_type(8)));
union UH8 { uint4 u4; f16x8 h8; _Float16 h[8]; };

// ---------------------------------------------------------------- helpers
__device__ __forceinline__ float blockReduceSum256(float v, float* sred) {
    #pragma unroll
    for (int off = 32; off; off >>= 1) v += __shfl_xor(v, off, 64);
    const int lane = threadIdx.x & 63, wid = threadIdx.x >> 6;
    if (lane == 0) sred[wid] = v;
    __syncthreads();
    float s = sred[0] + sred[1] + sred[2] + sred[3];
    __syncthreads();
    return s;
}

// ---------------------------------------------------------------- generic GEMM
// out[M,256] = A @ W[256,256], M = 16384. grid(2,256), block 256.
__global__ __launch_bounds__(256) void gemm_aw(const float* __restrict__ A,
                                               const float* __restrict__ W,
                                               float* __restrict__ out) {
    const int t = threadIdx.x;
    const int row0 = blockIdx.y * 64;
    const int cb = blockIdx.x * 128;
    __shared__ __align__(16) float Ast[32][68];   // transposed A tile [k][r]
    __shared__ __align__(16) float Wt[32][132];   // W tile [k][c]
    const int r0 = (t & 15) * 4;
    const int c0 = (t >> 4) * 8;
    const int ar = t >> 2;          // 0..63
    const int ak = (t & 3) * 8;     // 0,8,16,24
    const int wr = t >> 3;          // 0..31
    const int wc = (t & 7) * 16;    // 0..112
    float acc[4][8];
    #pragma unroll
    for (int i = 0; i < 4; i++)
        #pragma unroll
        for (int j = 0; j < 8; j++) acc[i][j] = 0.f;

    for (int k0 = 0; k0 < 256; k0 += 32) {
        const float* asrc = A + (size_t)(row0 + ar) * 256 + k0 + ak;
        float4 a0 = *(const float4*)asrc;
        float4 a1 = *(const float4*)(asrc + 4);
        const float* wsrc = W + (size_t)(k0 + wr) * 256 + cb + wc;
        float4 w0 = *(const float4*)wsrc;
        float4 w1 = *(const float4*)(wsrc + 4);
        float4 w2 = *(const float4*)(wsrc + 8);
        float4 w3 = *(const float4*)(wsrc + 12);
        __syncthreads();
        Ast[ak + 0][ar] = a0.x; Ast[ak + 1][ar] = a0.y;
        Ast[ak + 2][ar] = a0.z; Ast[ak + 3][ar] = a0.w;
        Ast[ak + 4][ar] = a1.x; Ast[ak + 5][ar] = a1.y;
        Ast[ak + 6][ar] = a1.z; Ast[ak + 7][ar] = a1.w;
        *(float4*)&Wt[wr][wc + 0] = w0;
        *(float4*)&Wt[wr][wc + 4] = w1;
        *(float4*)&Wt[wr][wc + 8] = w2;
        *(float4*)&Wt[wr][wc + 12] = w3;
        __syncthreads();
        #pragma unroll
        for (int kk = 0; kk < 32; kk++) {
            const float4 a4 = *(const float4*)&Ast[kk][r0];
            const float4 wa = *(const float4*)&Wt[kk][c0];
            const float4 wb = *(const float4*)&Wt[kk][c0 + 4];
            const float av[4] = {a4.x, a4.y, a4.z, a4.w};
            const float wv[8] = {wa.x, wa.y, wa.z, wa.w, wb.x, wb.y, wb.z, wb.w};
            #pragma unroll
            for (int i = 0; i < 4; i++)
                #pragma unroll
                for (int j = 0; j < 8; j++) acc[i][j] += av[i] * wv[j];
        }
    }
    #pragma unroll
    for (int i = 0; i < 4; i++) {
        float* dst = out + (size_t)(row0 + r0 + i) * 256 + cb + c0;
        *(float4*)dst = make_float4(acc[i][0], acc[i][1], acc[i][2], acc[i][3]);
        *(float4*)(dst + 4) = make_float4(acc[i][4], acc[i][5], acc[i][6], acc[i][7]);
    }
}

// ---------------------------------------------------------------- prep kernels
__global__ __launch_bounds__(256) void prep_wqk(const float* __restrict__ Wqs,
                                                const float* __restrict__ Wks,
                                                float* __restrict__ Wqk2) {
    __shared__ __align__(16) float srow[512];
    const int c1 = blockIdx.x, c2 = threadIdx.x;
    srow[c2] = Wqs[c1 * 512 + c2];
    srow[c2 + 256] = Wqs[c1 * 512 + 256 + c2];
    __syncthreads();
    const float* wk = Wks + (size_t)c2 * 512;
    float acc = 0.f;
    for (int d = 0; d < 512; d += 4) {
        float4 a = *(const float4*)&srow[d];
        float4 b = *(const float4*)(wk + d);
        acc += a.x * b.x + a.y * b.y + a.z * b.z + a.w * b.w;
    }
    Wqk2[c1 * 256 + c2] = acc * 0.044194173824159216f;  // 1/sqrt(512)
}

__global__ __launch_bounds__(256) void prep_wcomb(const float* __restrict__ Wvs,
                                                  const float* __restrict__ Wfc,
                                                  float* __restrict__ Wcomb) {
    __shared__ float srow[512];
    const int c1 = blockIdx.x, c2 = threadIdx.x;
    srow[c2] = Wvs[c1 * 512 + c2];
    srow[c2 + 256] = Wvs[c1 * 512 + 256 + c2];
    __syncthreads();
    float acc = 0.f;
    for (int d = 0; d < 512; d++) acc += srow[d] * Wfc[d * 256 + c2];
    Wcomb[c1 * 256 + c2] = acc;
}

__global__ __launch_bounds__(256) void k_seed(const float* __restrict__ sv,
                                              const float* __restrict__ Ws,
                                              const float* __restrict__ Wqk2,
                                              float* __restrict__ seed,
                                              float* __restrict__ qhk) {
    const int q = blockIdx.x, b = blockIdx.y, c = threadIdx.x;
    __shared__ float ssv[256];
    __shared__ float sseed[256];
    ssv[c] = sv[((size_t)b * 256 + c) * 14 + q];
    __syncthreads();
    float acc = 0.f;
    for (int d = 0; d < 256; d++) acc += ssv[d] * Ws[d * 256 + c];
    seed[((size_t)b * 14 + q) * 256 + c] = acc;
    sseed[c] = acc;
    __syncthreads();
    float a2 = 0.f;
    for (int d = 0; d < 256; d++) a2 += sseed[d] * Wqk2[d * 256 + c];
    qhk[((size_t)b * 14 + q) * 256 + c] = a2;
}

// vv [b][m][c] fp32 -> vvT_h [b][c][m] fp16. grid(64,4,4), block 256.
__global__ __launch_bounds__(256) void k_vvhalf(const float* __restrict__ vv,
                                                _Float16* __restrict__ vvT_h) {
    __shared__ float tile[64][65];   // [c][m]
    const int b = blockIdx.z, c0 = blockIdx.y * 64, m0 = blockIdx.x * 64;
    const int t = threadIdx.x;
    #pragma unroll
    for (int i = 0; i < 4; i++) {
        const int m = (t >> 4) + i * 16;
        const float4 v4 = *(const float4*)(vv + ((size_t)b * 4096 + m0 + m) * 256 + c0 + (t & 15) * 4);
        tile[(t & 15) * 4 + 0][m] = v4.x;
        tile[(t & 15) * 4 + 1][m] = v4.y;
        tile[(t & 15) * 4 + 2][m] = v4.z;
        tile[(t & 15) * 4 + 3][m] = v4.w;
    }
    __syncthreads();
    const int c = t >> 2, mo = (t & 3) * 16;
    UH8 o0, o1;
    #pragma unroll
    for (int j = 0; j < 8; j++) {
        o0.h[j] = (_Float16)tile[c][mo + j];
        o1.h[j] = (_Float16)tile[c][mo + 8 + j];
    }
    const size_t off = ((size_t)b * 256 + c0 + c) * 4096 + m0 + mo;
    *(uint4*)(vvT_h + off) = o0.u4;
    *(uint4*)(vvT_h + off + 8) = o1.u4;
}

// ---------------------------------------------------------------- stage-2 attention
__global__ __launch_bounds__(256) void k_logits1(const float* __restrict__ kk,
                                                 const float* __restrict__ qhk,
                                                 const int* __restrict__ supp,
                                                 float* __restrict__ logits) {
    const int b = blockIdx.y;
    const int n = blockIdx.x * 256 + threadIdx.x;
    __shared__ __align__(16) float sq[14][256];
    for (int i = threadIdx.x; i < 14 * 256; i += 256) sq[i >> 8][i & 255] = qhk[b * 14 * 256 + i];
    __syncthreads();
    float acc[14];
    #pragma unroll
    for (int q = 0; q < 14; q++) acc[q] = 0.f;
    const float* krow = kk + ((size_t)b * 4096 + n) * 256;
    for (int c = 0; c < 256; c += 4) {
        const float4 k4 = *(const float4*)(krow + c);
        #pragma unroll
        for (int q = 0; q < 14; q++) {
            const float4 a4 = *(const float4*)&sq[q][c];
            acc[q] += k4.x * a4.x + k4.y * a4.y + k4.z * a4.z + k4.w * a4.w;
        }
    }
    const bool msk = (supp[b * 4096 + n] == 0);
    #pragma unroll
    for (int q = 0; q < 14; q++)
        logits[((size_t)b * 14 + q) * 4096 + n] = msk ? -1e9f : acc[q];
}

__global__ __launch_bounds__(256) void k_softmax1(float* __restrict__ logits) {
    const int b = blockIdx.y, qq = blockIdx.x, t = threadIdx.x;
    __shared__ __align__(16) float sl[4096];
    __shared__ float sred[8];
    float* row = logits + ((size_t)b * 14 + qq) * 4096;
    float mx = -3e38f;
    for (int i = t; i < 4096; i += 256) { float v = row[i]; sl[i] = v; mx = fmaxf(mx, v); }
    #pragma unroll
    for (int off = 32; off; off >>= 1) mx = fmaxf(mx, __shfl_xor(mx, off, 64));
    if ((t & 63) == 0) sred[t >> 6] = mx;
    __syncthreads();
    mx = fmaxf(fmaxf(sred[0], sred[1]), fmaxf(sred[2], sred[3]));
    __syncthreads();
    float s = 0.f;
    for (int i = t; i < 4096; i += 256) { float e = expf(sl[i] - mx); sl[i] = e; s += e; }
    #pragma unroll
    for (int off = 32; off; off >>= 1) s += __shfl_xor(s, off, 64);
    if ((t & 63) == 0) sred[t >> 6] = s;
    __syncthreads();
    s = sred[0] + sred[1] + sred[2] + sred[3];
    const float inv = 1.f / s;
    for (int i = t; i < 4096; i += 256) row[i] = sl[i] * inv;
}

__global__ __launch_bounds__(256) void k_ctxv(const float* __restrict__ A,
                                              const float* __restrict__ vv,
                                              float* __restrict__ part) {
    const int b = blockIdx.y, ch = blockIdx.x, c = threadIdx.x;
    const int n0 = ch * 256;
    __shared__ __align__(16) float sA[14][256];
    for (int i = c; i < 14 * 256; i += 256) {
        int qq = i >> 8, j = i & 255;
        sA[qq][j] = A[((size_t)b * 14 + qq) * 4096 + n0 + j];
    }
    __syncthreads();
    float acc[14];
    #pragma unroll
    for (int q = 0; q < 14; q++) acc[q] = 0.f;
    for (int n = 0; n < 256; n += 4) {
        const float v0 = vv[((size_t)b * 4096 + n0 + n + 0) * 256 + c];
        const float v1 = vv[((size_t)b * 4096 + n0 + n + 1) * 256 + c];
        const float v2 = vv[((size_t)b * 4096 + n0 + n + 2) * 256 + c];
        const float v3 = vv[((size_t)b * 4096 + n0 + n + 3) * 256 + c];
        #pragma unroll
        for (int q = 0; q < 14; q++) {
            const float4 a4 = *(const float4*)&sA[q][n];
            acc[q] += a4.x * v0 + a4.y * v1 + a4.z * v2 + a4.w * v3;
        }
    }
    #pragma unroll
    for (int q = 0; q < 14; q++) part[(((size_t)b * 16 + ch) * 14 + q) * 256 + c] = acc[q];
}

__global__ __launch_bounds__(256) void k_proto(const float* __restrict__ part,
                                               const float* __restrict__ Wcomb,
                                               const float* __restrict__ bfc,
                                               const float* __restrict__ seed,
                                               const float* __restrict__ lng,
                                               const float* __restrict__ lnb,
                                               const float* __restrict__ Wsk,
                                               const float* __restrict__ Wsq,
                                               float* __restrict__ pkn,
                                               float* __restrict__ pqn) {
    const int q = blockIdx.x, b = blockIdx.y, c = threadIdx.x;
    __shared__ float sctx[256];
    __shared__ float sproto[256];
    __shared__ float sred[8];
    float cv = 0.f;
    for (int ch = 0; ch < 16; ch++) cv += part[(((size_t)b * 16 + ch) * 14 + q) * 256 + c];
    sctx[c] = cv;
    __syncthreads();
    float pre = 0.f;
    for (int d = 0; d < 256; d++) pre += sctx[d] * Wcomb[d * 256 + c];
    pre += bfc[c] + seed[((size_t)b * 14 + q) * 256 + c];
    const float mu = blockReduceSum256(pre, sred) * (1.f / 256.f);
    const float dv = pre - mu;
    const float var = blockReduceSum256(dv * dv, sred) * (1.f / 256.f);
    const float proto = dv * (1.f / sqrtf(var + 1e-5f)) * lng[c] + lnb[c];
    sproto[c] = proto;
    __syncthreads();
    float pk = 0.f, pq = 0.f;
    for (int d = 0; d < 256; d++) {
        const float sp = sproto[d];
        pk += sp * Wsk[d * 256 + c];
        pq += sp * Wsq[d * 256 + c];
    }
    const float nk = blockReduceSum256(pk * pk, sred);
    const float nq = blockReduceSum256(pq * pq, sred);
    pkn[((size_t)b * 14 + q) * 256 + c] = pk / fmaxf(sqrtf(nk), 1e-12f);
    pqn[((size_t)b * 14 + q) * 256 + c] = pq / fmaxf(sqrtf(nq), 1e-12f);
}

__global__ __launch_bounds__(256) void k_q2p(const float* __restrict__ qs,
                                             const float* __restrict__ kk,
                                             const float* __restrict__ pkn,
                                             const float* __restrict__ pqn,
                                             float* __restrict__ aq2p,
                                             float* __restrict__ attc,
                                             int* __restrict__ sidq) {
    const int b = blockIdx.y;
    const int n = blockIdx.x * 256 + threadIdx.x;
    __shared__ __align__(16) float spk[14][256];
    __shared__ __align__(16) float spq[14][256];
    for (int i = threadIdx.x; i < 14 * 256; i += 256) {
        spk[i >> 8][i & 255] = pkn[b * 14 * 256 + i];
        spq[i >> 8][i & 255] = pqn[b * 14 * 256 + i];
    }
    __syncthreads();
    float aq[14], ak[14];
    #pragma unroll
    for (int q = 0; q < 14; q++) { aq[q] = 0.f; ak[q] = 0.f; }
    float nq = 0.f, nk = 0.f;
    const float* qrow = qs + ((size_t)b * 4096 + n) * 256;
    const float* krow = kk + ((size_t)b * 4096 + n) * 256;
    for (int c = 0; c < 256; c += 4) {
        const float4 q4 = *(const float4*)(qrow + c);
        const float4 k4 = *(const float4*)(krow + c);
        nq += q4.x * q4.x + q4.y * q4.y + q4.z * q4.z + q4.w * q4.w;
        nk += k4.x * k4.x + k4.y * k4.y + k4.z * k4.z + k4.w * k4.w;
        #pragma unroll
        for (int q = 0; q < 14; q++) {
            const float4 p4 = *(const float4*)&spk[q][c];
            const float4 p4b = *(const float4*)&spq[q][c];
            aq[q] += q4.x * p4.x + q4.y * p4.y + q4.z * p4.z + q4.w * p4.w;
            ak[q] += k4.x * p4b.x + k4.y * p4b.y + k4.z * p4b.z + k4.w * p4b.w;
        }
    }
    const float sq_ = 1.f / fmaxf(sqrtf(nq), 1e-12f);
    const float sk_ = 1.f / fmaxf(sqrtf(nk), 1e-12f);
    float* aqrow = aq2p + ((size_t)b * 4096 + n) * 14;
    float* akrow = attc + ((size_t)b * 4096 + n) * 14;
    int best = 0;
    float bv = -3e38f;
    #pragma unroll
    for (int q = 0; q < 14; q++) {
        const float v = aq[q] * sq_;
        aqrow[q] = v;
        if (v > bv) { bv = v; best = q; }
        akrow[q] = ak[q] * sk_;
    }
    sidq[b * 4096 + n] = best;
}

// ---------------------------------------------------------------- Sinkhorn
// 256 threads/block, 16 rows/thread, K[16][15] register-resident
// (__launch_bounds__(256,1) -> VGPR cap 512; K must NOT spill).
// outputs: as2pT [b][k=14][m] k-major, and code[m] = alignmask | (valid<<14)
__global__ __launch_bounds__(256, 1) void k_sinkhorn(const float* __restrict__ attc,
                                                     const int* __restrict__ supp,
                                                     const int* __restrict__ valid,
                                                     float* __restrict__ as2pT,
                                                     int* __restrict__ code) {
    const int b = blockIdx.x;
    const int t = threadIdx.x;
    const int lane = t & 63, wid = t >> 6;   // 4 waves
    __shared__ float wred[4][16];
    __shared__ float vsh[16];
    __shared__ float sbg[4];
    float K[16][15], u[16];
    float bgcnt = 0.f;
    #pragma unroll
    for (int j = 0; j < 16; j++) {
        const int n = t + j * 256;
        const int sm = supp[b * 4096 + n];
        bgcnt += (sm == 0) ? 1.f : 0.f;
        const float* arow = attc + ((size_t)b * 4096 + n) * 14;
        #pragma unroll
        for (int m = 0; m < 14; m++) K[j][m] = expf(-20.f * (1.f - arow[m]));
        K[j][14] = (sm > 0) ? expf(-40.f) : 1.f;
        u[j] = 1.f / 4096.f;
    }
    #pragma unroll
    for (int off = 32; off; off >>= 1) bgcnt += __shfl_xor(bgcnt, off, 64);
    if (lane == 0) sbg[wid] = bgcnt;
    __syncthreads();
    const float num_bg = sbg[0] + sbg[1] + sbg[2] + sbg[3];
    const float num_fg = 4096.f - num_bg;
    const float bm_fg = num_fg / (14.f * 4096.f);
    const float bm_tr = num_bg / 4096.f;
    const float a_n = 1.f / 4096.f;

    for (int it = 0; it < 100; it++) {
        // phase A: p[m] = sum_n K[n][m] * u[n]
        float p[15];
        #pragma unroll
        for (int m = 0; m < 15; m++) {
            float s = 0.f;
            #pragma unroll
            for (int j = 0; j < 16; j++) s += K[j][m] * u[j];
            p[m] = s;
        }
        #pragma unroll
        for (int m = 0; m < 15; m++) {
            #pragma unroll
            for (int off = 32; off; off >>= 1) p[m] += __shfl_xor(p[m], off, 64);
        }
        if (lane < 15) wred[wid][lane] = p[lane];
        __syncthreads();
        if (t < 15) {
            const float s = wred[0][t] + wred[1][t] + wred[2][t] + wred[3][t];
            const float bm = (t < 14) ? bm_fg : bm_tr;
            vsh[t] = bm / (s + 1e-16f);
        }
        __syncthreads();
        // phase B: u[n] = a / sum_m K[n][m] * v[m]
        float vloc[15];
        #pragma unroll
        for (int m = 0; m < 15; m++) vloc[m] = vsh[m];
        #pragma unroll
        for (int j = 0; j < 16; j++) {
            float s = 0.f;
            #pragma unroll
            for (int m = 0; m < 15; m++) s += K[j][m] * vloc[m];
            u[j] = a_n / (s + 1e-16f);
        }
    }
    float vfin[15];
    #pragma unroll
    for (int m = 0; m < 15; m++) vfin[m] = vsh[m];
    #pragma unroll
    for (int j = 0; j < 16; j++) {
        const int n = t + j * 256;
        float bv = -3e38f;
        int bi = 0;
        #pragma unroll
        for (int m = 0; m < 14; m++) {
            float tv = fmaxf(4096.f * u[j] * K[j][m] * vfin[m], 0.f);
            as2pT[((size_t)(b * 14 + m)) * 4096 + n] = tv;
            if (tv > bv) { bv = tv; bi = m; }
        }
        int msk = 1 << bi;
        if (bi == 0) msk |= (1 << 12);
        else if (bi == 12) msk |= 1;
        else if (bi == 3) msk |= (1 << 11);
        else if (bi == 11) msk |= (1 << 3);
        code[b * 4096 + n] = msk | (valid[b * 4096 + n] << 14);
    }
}

// ---------------------------------------------------------------- lam table
__global__ __launch_bounds__(256) void k_lamtab(const int* __restrict__ code,
                                                int* __restrict__ lamtab) {
    const int b = blockIdx.x, t = threadIdx.x;
    __shared__ int sm0[4], sm1[4];
    int m0 = 0, m1 = 0;
    for (int m = t; m < 4096; m += 256) {
        const int c = code[b * 4096 + m];
        const int mask = c & 0x3fff;
        const int v = c >> 14;
        const int nmask = (~mask) & 0x3fff;
        if (v == 0) { m0 |= mask; m1 |= nmask; }
        else { m1 |= mask; }
    }
    #pragma unroll
    for (int off = 32; off; off >>= 1) {
        m0 |= __shfl_xor(m0, off, 64);
        m1 |= __shfl_xor(m1, off, 64);
    }
    if ((t & 63) == 0) { sm0[t >> 6] = m0; sm1[t >> 6] = m1; }
    __syncthreads();
    if (t == 0) {
        lamtab[b * 2 + 0] = sm0[0] | sm0[1] | sm0[2] | sm0[3];
        lamtab[b * 2 + 1] = sm1[0] | sm1[1] | sm1[2] | sm1[3];
    }
}

// ---------------------------------------------------------------- P materialization
// P[b][n][m] (fp16, unnormalized) and rinv[b][n]. grid(512,4), block 256.
__global__ __launch_bounds__(256) void k_pmat(const float* __restrict__ aq2p,
                                              const float* __restrict__ as2pT,
                                              const int* __restrict__ code,
                                              const int* __restrict__ sidq,
                                              const int* __restrict__ lamtab,
                                              _Float16* __restrict__ P,
                                              float* __restrict__ rinv) {
    const int b = blockIdx.y;
    const int t = threadIdx.x;
    const int nloc = t >> 5, mlane = t & 31;
    const int n = blockIdx.x * 8 + nloc;
    float qv[14];
    const float* qrow = aq2p + ((size_t)b * 4096 + n) * 14;
    #pragma unroll
    for (int k = 0; k < 14; k++) qv[k] = qrow[k];
    const int sq = sidq[b * 4096 + n];
    const int lm0 = lamtab[b * 2 + 0], lm1 = lamtab[b * 2 + 1];
    const int mylam = ((lm0 >> sq) & 1) ? 0 : (((lm1 >> sq) & 1) ? 1 : 2);
    float rsum = 0.f;
    _Float16* prow = P + ((size_t)b * 4096 + n) * 4096;
    const float* abase = as2pT + (size_t)b * 14 * 4096;
    const int* cbase = code + b * 4096;

    for (int g = 0; g < 32; g++) {
        const int m = g * 128 + mlane * 4;
        const int4 cd = *(const int4*)(cbase + m);
        f32x4 lv = {0.f, 0.f, 0.f, 0.f};
        #pragma unroll
        for (int k = 0; k < 14; k++) {
            const f32x4 a = *(const f32x4*)(abase + (size_t)k * 4096 + m);
            lv += qv[k] * a;
        }
        const int cj[4] = {cd.x, cd.y, cd.z, cd.w};
        union { uint2 u2; _Float16 h[4]; } o;
        #pragma unroll
        for (int j = 0; j < 4; j++) {
            const int lvl = (cj[j] >> 14) + 1 - ((cj[j] >> sq) & 1);
            const float p = (lvl == mylam) ? __expf(lv[j]) : 0.f;
            rsum += p;
            o.h[j] = (_Float16)p;
        }
        *(uint2*)(prow + m) = o.u2;
    }
    #pragma unroll
    for (int off = 1; off < 32; off <<= 1) rsum += __shfl_xor(rsum, off, 64);
    if (mlane == 0) rinv[b * 4096 + n] = 1.f / rsum;
}

// ---------------------------------------------------------------- PV GEMM (fp16 MFMA)
// y[b][n][c] = rinv[n] * P[n][:] @ vv[:][c]. grid(64,4), block 512 (8 waves).
__global__ __launch_bounds__(512) void k_pv(const _Float16* __restrict__ P,
                                            const _Float16* __restrict__ vvT_h,
                                            const float* __restrict__ rinv,
                                            float* __restrict__ y) {
    const int b = blockIdx.y, nt = blockIdx.x;
    const int t = threadIdx.x;
    const int l = t & 63, wv = t >> 6;
    const int wn = wv & 3, wc = wv >> 2;
    const int quad = l >> 4, lr = l & 15;
    const int row = nt * 64 + wn * 16 + lr;
    const _Float16* arow = P + (((size_t)b * 4096 + row) * 4096) + quad * 8;
    const _Float16* bbase = vvT_h + ((size_t)(b * 256 + wc * 128 + lr) * 4096) + quad * 8;

    f32x4 acc[8];
    #pragma unroll
    for (int ct = 0; ct < 8; ct++) acc[ct] = (f32x4){0.f, 0.f, 0.f, 0.f};

    uint4 aR = *(const uint4*)(arow);
    uint4 bR[8];
    #pragma unroll
    for (int ct = 0; ct < 8; ct++) bR[ct] = *(const uint4*)(bbase + (size_t)ct * 16 * 4096);

    for (int it = 0; it < 128; it++) {
        const int k1 = (it < 127) ? (it + 1) * 32 : 0;
        uint4 aN = *(const uint4*)(arow + k1);
        uint4 bN[8];
        #pragma unroll
        for (int ct = 0; ct < 8; ct++) bN[ct] = *(const uint4*)(bbase + (size_t)ct * 16 * 4096 + k1);
        #pragma unroll
        for (int ct = 0; ct < 8; ct++) {
            UH8 a, bb;
            a.u4 = aR; bb.u4 = bR[ct];
            acc[ct] = __builtin_amdgcn_mfma_f32_16x16x32_f16(a.h8, bb.h8, acc[ct], 0, 0, 0);
        }
        aR = aN;
        #pragma unroll
        for (int ct = 0; ct < 8; ct++) bR[ct] = bN[ct];
    }
    #pragma unroll
    for (int r = 0; r < 4; r++) {
        const int rowd = nt * 64 + wn * 16 + quad * 4 + r;
        const float ri = rinv[b * 4096 + rowd];
        float* dst = y + ((size_t)b * 4096 + rowd) * 256 + wc * 128 + lr;
        #pragma unroll
        for (int ct = 0; ct < 8; ct++) dst[ct * 16] = acc[ct][r] * ri;
    }
}

// ---------------------------------------------------------------- launch
extern "C" void kernel_launch(void* const* d_in, const int* in_sizes, int n_in,
                              void* d_out, int out_size, void* d_ws, size_t ws_size,
                              hipStream_t stream) {
    (void)in_sizes; (void)n_in; (void)out_size; (void)ws_size;
    const float* q    = (const float*)d_in[0];
    const float* k    = (const float*)d_in[1];
    const float* v    = (const float*)d_in[2];
    const float* sv   = (const float*)d_in[3];
    const int*  valid = (const int*)d_in[4];
    const int*  supp  = (const int*)d_in[5];
    const float* Wq   = (const float*)d_in[6];
    const float* Wk   = (const float*)d_in[7];
    const float* Wv   = (const float*)d_in[8];
    const float* Ws   = (const float*)d_in[9];
    const float* Wsq  = (const float*)d_in[10];
    const float* Wsk  = (const float*)d_in[11];
    const float* Wproj= (const float*)d_in[12];
    const float* Wqs  = (const float*)d_in[13];
    const float* Wks  = (const float*)d_in[14];
    const float* Wvs  = (const float*)d_in[15];
    const float* Wfc  = (const float*)d_in[16];
    const float* bfc  = (const float*)d_in[17];
    const float* lng  = (const float*)d_in[18];
    const float* lnb  = (const float*)d_in[19];

    float* ws = (float*)d_ws;
    // P (fp16 4x4096x4096 = 33,554,432 floats) overlays qs/kk/vv (dead by k_pmat)
    _Float16* P = (_Float16*)ws;
    float* qs   = ws + 0;
    float* kk   = ws + 4194304;
    float* vv   = ws + 8388608;
    float* y0   = ws + 33554432;
    float* wqk2 = ws + 37748736;
    float* wcomb= ws + 37814272;
    float* seed = ws + 37879808;
    float* qhk  = ws + 37894144;
    float* logA = ws + 37908480;
    float* cpart= ws + 38137856;
    float* pkn  = ws + 38367232;
    float* pqn  = ws + 38381568;
    float* aq2p = ws + 38395904;
    float* attc = ws + 38625280;
    float* as2pT= ws + 38854656;
    int* code   = (int*)(ws + 39084032);
    int* sidq   = (int*)(ws + 39100416);
    int* lamtab = (int*)(ws + 39116800);
    float* rinvb= ws + 39116816;
    _Float16* vvT_h = (_Float16*)(ws + 39133216);  // end ~41.2M floats (165 MB)

    gemm_aw<<<dim3(2, 256), 256, 0, stream>>>(q, Wq, qs);
    gemm_aw<<<dim3(2, 256), 256, 0, stream>>>(k, Wk, kk);
    gemm_aw<<<dim3(2, 256), 256, 0, stream>>>(v, Wv, vv);
    k_vvhalf<<<dim3(64, 4, 4), 256, 0, stream>>>(vv, vvT_h);
    prep_wqk<<<256, 256, 0, stream>>>(Wqs, Wks, wqk2);
    prep_wcomb<<<256, 256, 0, stream>>>(Wvs, Wfc, wcomb);
    k_seed<<<dim3(14, 4), 256, 0, stream>>>(sv, Ws, wqk2, seed, qhk);
    k_logits1<<<dim3(16, 4), 256, 0, stream>>>(kk, qhk, supp, logA);
    k_softmax1<<<dim3(14, 4), 256, 0, stream>>>(logA);
    k_ctxv<<<dim3(16, 4), 256, 0, stream>>>(logA, vv, cpart);
    k_proto<<<dim3(14, 4), 256, 0, stream>>>(cpart, wcomb, bfc, seed, lng, lnb, Wsk, Wsq, pkn, pqn);
    k_q2p<<<dim3(16, 4), 256, 0, stream>>>(qs, kk, pkn, pqn, aq2p, attc, sidq);
    k_sinkhorn<<<4, 256, 0, stream>>>(attc, supp, valid, as2pT, code);
    k_lamtab<<<4, 256, 0, stream>>>(code, lamtab);
    k_pmat<<<dim3(512, 4), 256, 0, stream>>>(aq2p, as2pT, code, sidq, lamtab, P, rinvb);
    k_pv<<<dim3(64, 4), 512, 0, stream>>>(P, vvT_h, rinvb, y0);
    gemm_aw<<<dim3(2, 256), 256, 0, stream>>>(y0, Wproj, (float*)d_out);
}

// Round 7
// 1149.192 us; speedup vs baseline: 1.7202x; 1.0667x over previous
//
#include <hip/hip_runtime.h>
#include <math.h>

#define NB 4
#define NN 4096
#define NC 256
#define NQ 14

typedef __attribute__((ext_vector_type(8))) short short8;
typedef __attribute__((ext_vector_type(4))) float f32x4;
typedef _Float16 f16x8 __attribute__((ext_vector_type(8)));
union UH8 { uint4 u4; f16x8 h8; _Float16 h[8]; };

// ---------------------------------------------------------------- helpers
__device__ __forceinline__ float blockReduceSum256(float v, float* sred) {
    #pragma unroll
    for (int off = 32; off; off >>= 1) v += __shfl_xor(v, off, 64);
    const int lane = threadIdx.x & 63, wid = threadIdx.x >> 6;
    if (lane == 0) sred[wid] = v;
    __syncthreads();
    float s = sred[0] + sred[1] + sred[2] + sred[3];
    __syncthreads();
    return s;
}

// ---------------------------------------------------------------- generic GEMM
// out[M,256] = A @ W[256,256], M = 16384. grid(2,256), block 256.
__global__ __launch_bounds__(256) void gemm_aw(const float* __restrict__ A,
                                               const float* __restrict__ W,
                                               float* __restrict__ out) {
    const int t = threadIdx.x;
    const int row0 = blockIdx.y * 64;
    const int cb = blockIdx.x * 128;
    __shared__ __align__(16) float Ast[32][68];   // transposed A tile [k][r]
    __shared__ __align__(16) float Wt[32][132];   // W tile [k][c]
    const int r0 = (t & 15) * 4;
    const int c0 = (t >> 4) * 8;
    const int ar = t >> 2;          // 0..63
    const int ak = (t & 3) * 8;     // 0,8,16,24
    const int wr = t >> 3;          // 0..31
    const int wc = (t & 7) * 16;    // 0..112
    float acc[4][8];
    #pragma unroll
    for (int i = 0; i < 4; i++)
        #pragma unroll
        for (int j = 0; j < 8; j++) acc[i][j] = 0.f;

    for (int k0 = 0; k0 < 256; k0 += 32) {
        const float* asrc = A + (size_t)(row0 + ar) * 256 + k0 + ak;
        float4 a0 = *(const float4*)asrc;
        float4 a1 = *(const float4*)(asrc + 4);
        const float* wsrc = W + (size_t)(k0 + wr) * 256 + cb + wc;
        float4 w0 = *(const float4*)wsrc;
        float4 w1 = *(const float4*)(wsrc + 4);
        float4 w2 = *(const float4*)(wsrc + 8);
        float4 w3 = *(const float4*)(wsrc + 12);
        __syncthreads();
        Ast[ak + 0][ar] = a0.x; Ast[ak + 1][ar] = a0.y;
        Ast[ak + 2][ar] = a0.z; Ast[ak + 3][ar] = a0.w;
        Ast[ak + 4][ar] = a1.x; Ast[ak + 5][ar] = a1.y;
        Ast[ak + 6][ar] = a1.z; Ast[ak + 7][ar] = a1.w;
        *(float4*)&Wt[wr][wc + 0] = w0;
        *(float4*)&Wt[wr][wc + 4] = w1;
        *(float4*)&Wt[wr][wc + 8] = w2;
        *(float4*)&Wt[wr][wc + 12] = w3;
        __syncthreads();
        #pragma unroll
        for (int kk = 0; kk < 32; kk++) {
            const float4 a4 = *(const float4*)&Ast[kk][r0];
            const float4 wa = *(const float4*)&Wt[kk][c0];
            const float4 wb = *(const float4*)&Wt[kk][c0 + 4];
            const float av[4] = {a4.x, a4.y, a4.z, a4.w};
            const float wv[8] = {wa.x, wa.y, wa.z, wa.w, wb.x, wb.y, wb.z, wb.w};
            #pragma unroll
            for (int i = 0; i < 4; i++)
                #pragma unroll
                for (int j = 0; j < 8; j++) acc[i][j] += av[i] * wv[j];
        }
    }
    #pragma unroll
    for (int i = 0; i < 4; i++) {
        float* dst = out + (size_t)(row0 + r0 + i) * 256 + cb + c0;
        *(float4*)dst = make_float4(acc[i][0], acc[i][1], acc[i][2], acc[i][3]);
        *(float4*)(dst + 4) = make_float4(acc[i][4], acc[i][5], acc[i][6], acc[i][7]);
    }
}

// ---------------------------------------------------------------- prep kernels
__global__ __launch_bounds__(256) void prep_wqk(const float* __restrict__ Wqs,
                                                const float* __restrict__ Wks,
                                                float* __restrict__ Wqk2) {
    __shared__ __align__(16) float srow[512];
    const int c1 = blockIdx.x, c2 = threadIdx.x;
    srow[c2] = Wqs[c1 * 512 + c2];
    srow[c2 + 256] = Wqs[c1 * 512 + 256 + c2];
    __syncthreads();
    const float* wk = Wks + (size_t)c2 * 512;
    float acc = 0.f;
    for (int d = 0; d < 512; d += 4) {
        float4 a = *(const float4*)&srow[d];
        float4 b = *(const float4*)(wk + d);
        acc += a.x * b.x + a.y * b.y + a.z * b.z + a.w * b.w;
    }
    Wqk2[c1 * 256 + c2] = acc * 0.044194173824159216f;  // 1/sqrt(512)
}

__global__ __launch_bounds__(256) void prep_wcomb(const float* __restrict__ Wvs,
                                                  const float* __restrict__ Wfc,
                                                  float* __restrict__ Wcomb) {
    __shared__ float srow[512];
    const int c1 = blockIdx.x, c2 = threadIdx.x;
    srow[c2] = Wvs[c1 * 512 + c2];
    srow[c2 + 256] = Wvs[c1 * 512 + 256 + c2];
    __syncthreads();
    float acc = 0.f;
    for (int d = 0; d < 512; d++) acc += srow[d] * Wfc[d * 256 + c2];
    Wcomb[c1 * 256 + c2] = acc;
}

__global__ __launch_bounds__(256) void k_seed(const float* __restrict__ sv,
                                              const float* __restrict__ Ws,
                                              const float* __restrict__ Wqk2,
                                              float* __restrict__ seed,
                                              float* __restrict__ qhk) {
    const int q = blockIdx.x, b = blockIdx.y, c = threadIdx.x;
    __shared__ float ssv[256];
    __shared__ float sseed[256];
    ssv[c] = sv[((size_t)b * 256 + c) * 14 + q];
    __syncthreads();
    float acc = 0.f;
    for (int d = 0; d < 256; d++) acc += ssv[d] * Ws[d * 256 + c];
    seed[((size_t)b * 14 + q) * 256 + c] = acc;
    sseed[c] = acc;
    __syncthreads();
    float a2 = 0.f;
    for (int d = 0; d < 256; d++) a2 += sseed[d] * Wqk2[d * 256 + c];
    qhk[((size_t)b * 14 + q) * 256 + c] = a2;
}

// vv [b][m][c] fp32 -> vvT_h [b][c][m] fp16. grid(64,4,4), block 256.
__global__ __launch_bounds__(256) void k_vvhalf(const float* __restrict__ vv,
                                                _Float16* __restrict__ vvT_h) {
    __shared__ float tile[64][65];   // [c][m]
    const int b = blockIdx.z, c0 = blockIdx.y * 64, m0 = blockIdx.x * 64;
    const int t = threadIdx.x;
    #pragma unroll
    for (int i = 0; i < 4; i++) {
        const int m = (t >> 4) + i * 16;
        const float4 v4 = *(const float4*)(vv + ((size_t)b * 4096 + m0 + m) * 256 + c0 + (t & 15) * 4);
        tile[(t & 15) * 4 + 0][m] = v4.x;
        tile[(t & 15) * 4 + 1][m] = v4.y;
        tile[(t & 15) * 4 + 2][m] = v4.z;
        tile[(t & 15) * 4 + 3][m] = v4.w;
    }
    __syncthreads();
    const int c = t >> 2, mo = (t & 3) * 16;
    UH8 o0, o1;
    #pragma unroll
    for (int j = 0; j < 8; j++) {
        o0.h[j] = (_Float16)tile[c][mo + j];
        o1.h[j] = (_Float16)tile[c][mo + 8 + j];
    }
    const size_t off = ((size_t)b * 256 + c0 + c) * 4096 + m0 + mo;
    *(uint4*)(vvT_h + off) = o0.u4;
    *(uint4*)(vvT_h + off + 8) = o1.u4;
}

// ---------------------------------------------------------------- stage-2 attention
__global__ __launch_bounds__(256) void k_logits1(const float* __restrict__ kk,
                                                 const float* __restrict__ qhk,
                                                 const int* __restrict__ supp,
                                                 float* __restrict__ logits) {
    const int b = blockIdx.y;
    const int n = blockIdx.x * 256 + threadIdx.x;
    __shared__ __align__(16) float sq[14][256];
    for (int i = threadIdx.x; i < 14 * 256; i += 256) sq[i >> 8][i & 255] = qhk[b * 14 * 256 + i];
    __syncthreads();
    float acc[14];
    #pragma unroll
    for (int q = 0; q < 14; q++) acc[q] = 0.f;
    const float* krow = kk + ((size_t)b * 4096 + n) * 256;
    for (int c = 0; c < 256; c += 4) {
        const float4 k4 = *(const float4*)(krow + c);
        #pragma unroll
        for (int q = 0; q < 14; q++) {
            const float4 a4 = *(const float4*)&sq[q][c];
            acc[q] += k4.x * a4.x + k4.y * a4.y + k4.z * a4.z + k4.w * a4.w;
        }
    }
    const bool msk = (supp[b * 4096 + n] == 0);
    #pragma unroll
    for (int q = 0; q < 14; q++)
        logits[((size_t)b * 14 + q) * 4096 + n] = msk ? -1e9f : acc[q];
}

__global__ __launch_bounds__(256) void k_softmax1(float* __restrict__ logits) {
    const int b = blockIdx.y, qq = blockIdx.x, t = threadIdx.x;
    __shared__ __align__(16) float sl[4096];
    __shared__ float sred[8];
    float* row = logits + ((size_t)b * 14 + qq) * 4096;
    float mx = -3e38f;
    for (int i = t; i < 4096; i += 256) { float v = row[i]; sl[i] = v; mx = fmaxf(mx, v); }
    #pragma unroll
    for (int off = 32; off; off >>= 1) mx = fmaxf(mx, __shfl_xor(mx, off, 64));
    if ((t & 63) == 0) sred[t >> 6] = mx;
    __syncthreads();
    mx = fmaxf(fmaxf(sred[0], sred[1]), fmaxf(sred[2], sred[3]));
    __syncthreads();
    float s = 0.f;
    for (int i = t; i < 4096; i += 256) { float e = expf(sl[i] - mx); sl[i] = e; s += e; }
    #pragma unroll
    for (int off = 32; off; off >>= 1) s += __shfl_xor(s, off, 64);
    if ((t & 63) == 0) sred[t >> 6] = s;
    __syncthreads();
    s = sred[0] + sred[1] + sred[2] + sred[3];
    const float inv = 1.f / s;
    for (int i = t; i < 4096; i += 256) row[i] = sl[i] * inv;
}

__global__ __launch_bounds__(256) void k_ctxv(const float* __restrict__ A,
                                              const float* __restrict__ vv,
                                              float* __restrict__ part) {
    const int b = blockIdx.y, ch = blockIdx.x, c = threadIdx.x;
    const int n0 = ch * 256;
    __shared__ __align__(16) float sA[14][256];
    for (int i = c; i < 14 * 256; i += 256) {
        int qq = i >> 8, j = i & 255;
        sA[qq][j] = A[((size_t)b * 14 + qq) * 4096 + n0 + j];
    }
    __syncthreads();
    float acc[14];
    #pragma unroll
    for (int q = 0; q < 14; q++) acc[q] = 0.f;
    for (int n = 0; n < 256; n += 4) {
        const float v0 = vv[((size_t)b * 4096 + n0 + n + 0) * 256 + c];
        const float v1 = vv[((size_t)b * 4096 + n0 + n + 1) * 256 + c];
        const float v2 = vv[((size_t)b * 4096 + n0 + n + 2) * 256 + c];
        const float v3 = vv[((size_t)b * 4096 + n0 + n + 3) * 256 + c];
        #pragma unroll
        for (int q = 0; q < 14; q++) {
            const float4 a4 = *(const float4*)&sA[q][n];
            acc[q] += a4.x * v0 + a4.y * v1 + a4.z * v2 + a4.w * v3;
        }
    }
    #pragma unroll
    for (int q = 0; q < 14; q++) part[(((size_t)b * 16 + ch) * 14 + q) * 256 + c] = acc[q];
}

__global__ __launch_bounds__(256) void k_proto(const float* __restrict__ part,
                                               const float* __restrict__ Wcomb,
                                               const float* __restrict__ bfc,
                                               const float* __restrict__ seed,
                                               const float* __restrict__ lng,
                                               const float* __restrict__ lnb,
                                               const float* __restrict__ Wsk,
                                               const float* __restrict__ Wsq,
                                               float* __restrict__ pkn,
                                               float* __restrict__ pqn) {
    const int q = blockIdx.x, b = blockIdx.y, c = threadIdx.x;
    __shared__ float sctx[256];
    __shared__ float sproto[256];
    __shared__ float sred[8];
    float cv = 0.f;
    for (int ch = 0; ch < 16; ch++) cv += part[(((size_t)b * 16 + ch) * 14 + q) * 256 + c];
    sctx[c] = cv;
    __syncthreads();
    float pre = 0.f;
    for (int d = 0; d < 256; d++) pre += sctx[d] * Wcomb[d * 256 + c];
    pre += bfc[c] + seed[((size_t)b * 14 + q) * 256 + c];
    const float mu = blockReduceSum256(pre, sred) * (1.f / 256.f);
    const float dv = pre - mu;
    const float var = blockReduceSum256(dv * dv, sred) * (1.f / 256.f);
    const float proto = dv * (1.f / sqrtf(var + 1e-5f)) * lng[c] + lnb[c];
    sproto[c] = proto;
    __syncthreads();
    float pk = 0.f, pq = 0.f;
    for (int d = 0; d < 256; d++) {
        const float sp = sproto[d];
        pk += sp * Wsk[d * 256 + c];
        pq += sp * Wsq[d * 256 + c];
    }
    const float nk = blockReduceSum256(pk * pk, sred);
    const float nq = blockReduceSum256(pq * pq, sred);
    pkn[((size_t)b * 14 + q) * 256 + c] = pk / fmaxf(sqrtf(nk), 1e-12f);
    pqn[((size_t)b * 14 + q) * 256 + c] = pq / fmaxf(sqrtf(nq), 1e-12f);
}

__global__ __launch_bounds__(256) void k_q2p(const float* __restrict__ qs,
                                             const float* __restrict__ kk,
                                             const float* __restrict__ pkn,
                                             const float* __restrict__ pqn,
                                             float* __restrict__ aq2p,
                                             float* __restrict__ attc,
                                             int* __restrict__ sidq) {
    const int b = blockIdx.y;
    const int n = blockIdx.x * 256 + threadIdx.x;
    __shared__ __align__(16) float spk[14][256];
    __shared__ __align__(16) float spq[14][256];
    for (int i = threadIdx.x; i < 14 * 256; i += 256) {
        spk[i >> 8][i & 255] = pkn[b * 14 * 256 + i];
        spq[i >> 8][i & 255] = pqn[b * 14 * 256 + i];
    }
    __syncthreads();
    float aq[14], ak[14];
    #pragma unroll
    for (int q = 0; q < 14; q++) { aq[q] = 0.f; ak[q] = 0.f; }
    float nq = 0.f, nk = 0.f;
    const float* qrow = qs + ((size_t)b * 4096 + n) * 256;
    const float* krow = kk + ((size_t)b * 4096 + n) * 256;
    for (int c = 0; c < 256; c += 4) {
        const float4 q4 = *(const float4*)(qrow + c);
        const float4 k4 = *(const float4*)(krow + c);
        nq += q4.x * q4.x + q4.y * q4.y + q4.z * q4.z + q4.w * q4.w;
        nk += k4.x * k4.x + k4.y * k4.y + k4.z * k4.z + k4.w * k4.w;
        #pragma unroll
        for (int q = 0; q < 14; q++) {
            const float4 p4 = *(const float4*)&spk[q][c];
            const float4 p4b = *(const float4*)&spq[q][c];
            aq[q] += q4.x * p4.x + q4.y * p4.y + q4.z * p4.z + q4.w * p4.w;
            ak[q] += k4.x * p4b.x + k4.y * p4b.y + k4.z * p4b.z + k4.w * p4b.w;
        }
    }
    const float sq_ = 1.f / fmaxf(sqrtf(nq), 1e-12f);
    const float sk_ = 1.f / fmaxf(sqrtf(nk), 1e-12f);
    float* aqrow = aq2p + ((size_t)b * 4096 + n) * 14;
    float* akrow = attc + ((size_t)b * 4096 + n) * 14;
    int best = 0;
    float bv = -3e38f;
    #pragma unroll
    for (int q = 0; q < 14; q++) {
        const float v = aq[q] * sq_;
        aqrow[q] = v;
        if (v > bv) { bv = v; best = q; }
        akrow[q] = ak[q] * sk_;
    }
    sidq[b * 4096 + n] = best;
}

// ---------------------------------------------------------------- Sinkhorn
// 512 threads/block (8 waves), 8 rows/thread: K[8][15] = 120 VGPR.
// __launch_bounds__(512, 2): 2 waves/EU min -> hard VGPR cap 256 (8-wave
// block NEEDS <=256 VGPR/thread to be schedulable; (512,1) made the launch
// fail with out-of-resources in R6).
__global__ __launch_bounds__(512, 2) void k_sinkhorn(const float* __restrict__ attc,
                                                     const int* __restrict__ supp,
                                                     const int* __restrict__ valid,
                                                     float* __restrict__ as2pT,
                                                     int* __restrict__ code) {
    const int b = blockIdx.x;
    const int t = threadIdx.x;
    const int lane = t & 63, wid = t >> 6;   // 8 waves
    __shared__ float wred[8][16];
    __shared__ float vsh[16];
    __shared__ float sbg[8];
    float K[8][15], u[8];
    float bgcnt = 0.f;
    #pragma unroll
    for (int j = 0; j < 8; j++) {
        const int n = t + j * 512;
        const int sm = supp[b * 4096 + n];
        bgcnt += (sm == 0) ? 1.f : 0.f;
        const float* arow = attc + ((size_t)b * 4096 + n) * 14;
        #pragma unroll
        for (int m = 0; m < 14; m++) K[j][m] = expf(-20.f * (1.f - arow[m]));
        K[j][14] = (sm > 0) ? expf(-40.f) : 1.f;
        u[j] = 1.f / 4096.f;
    }
    #pragma unroll
    for (int off = 32; off; off >>= 1) bgcnt += __shfl_xor(bgcnt, off, 64);
    if (lane == 0) sbg[wid] = bgcnt;
    __syncthreads();
    float num_bg = 0.f;
    #pragma unroll
    for (int w = 0; w < 8; w++) num_bg += sbg[w];
    const float num_fg = 4096.f - num_bg;
    const float bm_fg = num_fg / (14.f * 4096.f);
    const float bm_tr = num_bg / 4096.f;
    const float a_n = 1.f / 4096.f;

    for (int it = 0; it < 100; it++) {
        // phase A: p[m] = sum_n K[n][m] * u[n]
        float p[15];
        #pragma unroll
        for (int m = 0; m < 15; m++) {
            float s = 0.f;
            #pragma unroll
            for (int j = 0; j < 8; j++) s += K[j][m] * u[j];
            p[m] = s;
        }
        #pragma unroll
        for (int m = 0; m < 15; m++) {
            #pragma unroll
            for (int off = 32; off; off >>= 1) p[m] += __shfl_xor(p[m], off, 64);
        }
        if (lane < 15) wred[wid][lane] = p[lane];
        __syncthreads();
        if (t < 15) {
            float s = 0.f;
            #pragma unroll
            for (int w = 0; w < 8; w++) s += wred[w][t];
            const float bm = (t < 14) ? bm_fg : bm_tr;
            vsh[t] = bm / (s + 1e-16f);
        }
        __syncthreads();
        // phase B: u[n] = a / sum_m K[n][m] * v[m]
        float vloc[15];
        #pragma unroll
        for (int m = 0; m < 15; m++) vloc[m] = vsh[m];
        #pragma unroll
        for (int j = 0; j < 8; j++) {
            float s = 0.f;
            #pragma unroll
            for (int m = 0; m < 15; m++) s += K[j][m] * vloc[m];
            u[j] = a_n / (s + 1e-16f);
        }
    }
    float vfin[15];
    #pragma unroll
    for (int m = 0; m < 15; m++) vfin[m] = vsh[m];
    #pragma unroll
    for (int j = 0; j < 8; j++) {
        const int n = t + j * 512;
        float bv = -3e38f;
        int bi = 0;
        #pragma unroll
        for (int m = 0; m < 14; m++) {
            float tv = fmaxf(4096.f * u[j] * K[j][m] * vfin[m], 0.f);
            as2pT[((size_t)(b * 14 + m)) * 4096 + n] = tv;
            if (tv > bv) { bv = tv; bi = m; }
        }
        int msk = 1 << bi;
        if (bi == 0) msk |= (1 << 12);
        else if (bi == 12) msk |= 1;
        else if (bi == 3) msk |= (1 << 11);
        else if (bi == 11) msk |= (1 << 3);
        code[b * 4096 + n] = msk | (valid[b * 4096 + n] << 14);
    }
}

// ---------------------------------------------------------------- lam table
__global__ __launch_bounds__(256) void k_lamtab(const int* __restrict__ code,
                                                int* __restrict__ lamtab) {
    const int b = blockIdx.x, t = threadIdx.x;
    __shared__ int sm0[4], sm1[4];
    int m0 = 0, m1 = 0;
    for (int m = t; m < 4096; m += 256) {
        const int c = code[b * 4096 + m];
        const int mask = c & 0x3fff;
        const int v = c >> 14;
        const int nmask = (~mask) & 0x3fff;
        if (v == 0) { m0 |= mask; m1 |= nmask; }
        else { m1 |= mask; }
    }
    #pragma unroll
    for (int off = 32; off; off >>= 1) {
        m0 |= __shfl_xor(m0, off, 64);
        m1 |= __shfl_xor(m1, off, 64);
    }
    if ((t & 63) == 0) { sm0[t >> 6] = m0; sm1[t >> 6] = m1; }
    __syncthreads();
    if (t == 0) {
        lamtab[b * 2 + 0] = sm0[0] | sm0[1] | sm0[2] | sm0[3];
        lamtab[b * 2 + 1] = sm1[0] | sm1[1] | sm1[2] | sm1[3];
    }
}

// ---------------------------------------------------------------- P materialization
// P[b][n][m] (fp16, unnormalized) and rinv[b][n]. grid(512,4), block 256.
__global__ __launch_bounds__(256) void k_pmat(const float* __restrict__ aq2p,
                                              const float* __restrict__ as2pT,
                                              const int* __restrict__ code,
                                              const int* __restrict__ sidq,
                                              const int* __restrict__ lamtab,
                                              _Float16* __restrict__ P,
                                              float* __restrict__ rinv) {
    const int b = blockIdx.y;
    const int t = threadIdx.x;
    const int nloc = t >> 5, mlane = t & 31;
    const int n = blockIdx.x * 8 + nloc;
    float qv[14];
    const float* qrow = aq2p + ((size_t)b * 4096 + n) * 14;
    #pragma unroll
    for (int k = 0; k < 14; k++) qv[k] = qrow[k];
    const int sq = sidq[b * 4096 + n];
    const int lm0 = lamtab[b * 2 + 0], lm1 = lamtab[b * 2 + 1];
    const int mylam = ((lm0 >> sq) & 1) ? 0 : (((lm1 >> sq) & 1) ? 1 : 2);
    float rsum = 0.f;
    _Float16* prow = P + ((size_t)b * 4096 + n) * 4096;
    const float* abase = as2pT + (size_t)b * 14 * 4096;
    const int* cbase = code + b * 4096;

    for (int g = 0; g < 32; g++) {
        const int m = g * 128 + mlane * 4;
        const int4 cd = *(const int4*)(cbase + m);
        f32x4 lv = {0.f, 0.f, 0.f, 0.f};
        #pragma unroll
        for (int k = 0; k < 14; k++) {
            const f32x4 a = *(const f32x4*)(abase + (size_t)k * 4096 + m);
            lv += qv[k] * a;
        }
        const int cj[4] = {cd.x, cd.y, cd.z, cd.w};
        union { uint2 u2; _Float16 h[4]; } o;
        #pragma unroll
        for (int j = 0; j < 4; j++) {
            const int lvl = (cj[j] >> 14) + 1 - ((cj[j] >> sq) & 1);
            const float p = (lvl == mylam) ? __expf(lv[j]) : 0.f;
            rsum += p;
            o.h[j] = (_Float16)p;
        }
        *(uint2*)(prow + m) = o.u2;
    }
    #pragma unroll
    for (int off = 1; off < 32; off <<= 1) rsum += __shfl_xor(rsum, off, 64);
    if (mlane == 0) rinv[b * 4096 + n] = 1.f / rsum;
}

// ---------------------------------------------------------------- PV GEMM (fp16 MFMA)
// y[b][n][c] = rinv[n] * P[n][:] @ vv[:][c]. grid(64,4), block 512 (8 waves).
__global__ __launch_bounds__(512) void k_pv(const _Float16* __restrict__ P,
                                            const _Float16* __restrict__ vvT_h,
                                            const float* __restrict__ rinv,
                                            float* __restrict__ y) {
    const int b = blockIdx.y, nt = blockIdx.x;
    const int t = threadIdx.x;
    const int l = t & 63, wv = t >> 6;
    const int wn = wv & 3, wc = wv >> 2;
    const int quad = l >> 4, lr = l & 15;
    const int row = nt * 64 + wn * 16 + lr;
    const _Float16* arow = P + (((size_t)b * 4096 + row) * 4096) + quad * 8;
    const _Float16* bbase = vvT_h + ((size_t)(b * 256 + wc * 128 + lr) * 4096) + quad * 8;

    f32x4 acc[8];
    #pragma unroll
    for (int ct = 0; ct < 8; ct++) acc[ct] = (f32x4){0.f, 0.f, 0.f, 0.f};

    uint4 aR = *(const uint4*)(arow);
    uint4 bR[8];
    #pragma unroll
    for (int ct = 0; ct < 8; ct++) bR[ct] = *(const uint4*)(bbase + (size_t)ct * 16 * 4096);

    for (int it = 0; it < 128; it++) {
        const int k1 = (it < 127) ? (it + 1) * 32 : 0;
        uint4 aN = *(const uint4*)(arow + k1);
        uint4 bN[8];
        #pragma unroll
        for (int ct = 0; ct < 8; ct++) bN[ct] = *(const uint4*)(bbase + (size_t)ct * 16 * 4096 + k1);
        #pragma unroll
        for (int ct = 0; ct < 8; ct++) {
            UH8 a, bb;
            a.u4 = aR; bb.u4 = bR[ct];
            acc[ct] = __builtin_amdgcn_mfma_f32_16x16x32_f16(a.h8, bb.h8, acc[ct], 0, 0, 0);
        }
        aR = aN;
        #pragma unroll
        for (int ct = 0; ct < 8; ct++) bR[ct] = bN[ct];
    }
    #pragma unroll
    for (int r = 0; r < 4; r++) {
        const int rowd = nt * 64 + wn * 16 + quad * 4 + r;
        const float ri = rinv[b * 4096 + rowd];
        float* dst = y + ((size_t)b * 4096 + rowd) * 256 + wc * 128 + lr;
        #pragma unroll
        for (int ct = 0; ct < 8; ct++) dst[ct * 16] = acc[ct][r] * ri;
    }
}

// ---------------------------------------------------------------- launch
extern "C" void kernel_launch(void* const* d_in, const int* in_sizes, int n_in,
                              void* d_out, int out_size, void* d_ws, size_t ws_size,
                              hipStream_t stream) {
    (void)in_sizes; (void)n_in; (void)out_size; (void)ws_size;
    const float* q    = (const float*)d_in[0];
    const float* k    = (const float*)d_in[1];
    const float* v    = (const float*)d_in[2];
    const float* sv   = (const float*)d_in[3];
    const int*  valid = (const int*)d_in[4];
    const int*  supp  = (const int*)d_in[5];
    const float* Wq   = (const float*)d_in[6];
    const float* Wk   = (const float*)d_in[7];
    const float* Wv   = (const float*)d_in[8];
    const float* Ws   = (const float*)d_in[9];
    const float* Wsq  = (const float*)d_in[10];
    const float* Wsk  = (const float*)d_in[11];
    const float* Wproj= (const float*)d_in[12];
    const float* Wqs  = (const float*)d_in[13];
    const float* Wks  = (const float*)d_in[14];
    const float* Wvs  = (const float*)d_in[15];
    const float* Wfc  = (const float*)d_in[16];
    const float* bfc  = (const float*)d_in[17];
    const float* lng  = (const float*)d_in[18];
    const float* lnb  = (const float*)d_in[19];

    float* ws = (float*)d_ws;
    // P (fp16 4x4096x4096 = 33,554,432 floats) overlays qs/kk/vv (dead by k_pmat)
    _Float16* P = (_Float16*)ws;
    float* qs   = ws + 0;
    float* kk   = ws + 4194304;
    float* vv   = ws + 8388608;
    float* y0   = ws + 33554432;
    float* wqk2 = ws + 37748736;
    float* wcomb= ws + 37814272;
    float* seed = ws + 37879808;
    float* qhk  = ws + 37894144;
    float* logA = ws + 37908480;
    float* cpart= ws + 38137856;
    float* pkn  = ws + 38367232;
    float* pqn  = ws + 38381568;
    float* aq2p = ws + 38395904;
    float* attc = ws + 38625280;
    float* as2pT= ws + 38854656;
    int* code   = (int*)(ws + 39084032);
    int* sidq   = (int*)(ws + 39100416);
    int* lamtab = (int*)(ws + 39116800);
    float* rinvb= ws + 39116816;
    _Float16* vvT_h = (_Float16*)(ws + 39133216);  // end ~41.2M floats (165 MB)

    gemm_aw<<<dim3(2, 256), 256, 0, stream>>>(q, Wq, qs);
    gemm_aw<<<dim3(2, 256), 256, 0, stream>>>(k, Wk, kk);
    gemm_aw<<<dim3(2, 256), 256, 0, stream>>>(v, Wv, vv);
    k_vvhalf<<<dim3(64, 4, 4), 256, 0, stream>>>(vv, vvT_h);
    prep_wqk<<<256, 256, 0, stream>>>(Wqs, Wks, wqk2);
    prep_wcomb<<<256, 256, 0, stream>>>(Wvs, Wfc, wcomb);
    k_seed<<<dim3(14, 4), 256, 0, stream>>>(sv, Ws, wqk2, seed, qhk);
    k_logits1<<<dim3(16, 4), 256, 0, stream>>>(kk, qhk, supp, logA);
    k_softmax1<<<dim3(14, 4), 256, 0, stream>>>(logA);
    k_ctxv<<<dim3(16, 4), 256, 0, stream>>>(logA, vv, cpart);
    k_proto<<<dim3(14, 4), 256, 0, stream>>>(cpart, wcomb, bfc, seed, lng, lnb, Wsk, Wsq, pkn, pqn);
    k_q2p<<<dim3(16, 4), 256, 0, stream>>>(qs, kk, pkn, pqn, aq2p, attc, sidq);
    k_sinkhorn<<<4, 512, 0, stream>>>(attc, supp, valid, as2pT, code);
    k_lamtab<<<4, 256, 0, stream>>>(code, lamtab);
    k_pmat<<<dim3(512, 4), 256, 0, stream>>>(aq2p, as2pT, code, sidq, lamtab, P, rinvb);
    k_pv<<<dim3(64, 4), 512, 0, stream>>>(P, vvT_h, rinvb, y0);
    gemm_aw<<<dim3(2, 256), 256, 0, stream>>>(y0, Wproj, (float*)d_out);
}

// Round 8
// 1058.283 us; speedup vs baseline: 1.8679x; 1.0859x over previous
//
#include <hip/hip_runtime.h>
#include <math.h>

#define NB 4
#define NN 4096
#define NC 256
#define NQ 14

typedef __attribute__((ext_vector_type(8))) short short8;
typedef __attribute__((ext_vector_type(4))) float f32x4;
typedef _Float16 f16x8 __attribute__((ext_vector_type(8)));
union UH8 { uint4 u4; f16x8 h8; _Float16 h[8]; };

// ---------------------------------------------------------------- helpers
__device__ __forceinline__ float blockReduceSum256(float v, float* sred) {
    #pragma unroll
    for (int off = 32; off; off >>= 1) v += __shfl_xor(v, off, 64);
    const int lane = threadIdx.x & 63, wid = threadIdx.x >> 6;
    if (lane == 0) sred[wid] = v;
    __syncthreads();
    float s = sred[0] + sred[1] + sred[2] + sred[3];
    __syncthreads();
    return s;
}

// DPP wave64 sum: result lands in lane 63 (VALU-only, no LDS pipe).
// row_shr:1/2/4/8 then row_bcast:15 / row_bcast:31, bound_ctrl=1 (OOB -> 0).
__device__ __forceinline__ float dpp_wave_sum63(float x) {
    x += __int_as_float(__builtin_amdgcn_update_dpp(0, __float_as_int(x), 0x111, 0xf, 0xf, true));
    x += __int_as_float(__builtin_amdgcn_update_dpp(0, __float_as_int(x), 0x112, 0xf, 0xf, true));
    x += __int_as_float(__builtin_amdgcn_update_dpp(0, __float_as_int(x), 0x114, 0xf, 0xf, true));
    x += __int_as_float(__builtin_amdgcn_update_dpp(0, __float_as_int(x), 0x118, 0xf, 0xf, true));
    x += __int_as_float(__builtin_amdgcn_update_dpp(0, __float_as_int(x), 0x142, 0xf, 0xf, true));
    x += __int_as_float(__builtin_amdgcn_update_dpp(0, __float_as_int(x), 0x143, 0xf, 0xf, true));
    return x;
}
__device__ __forceinline__ float rdlane(float x, int l) {
    return __int_as_float(__builtin_amdgcn_readlane(__float_as_int(x), l));
}

// ---------------------------------------------------------------- generic GEMM
// out[M,256] = A @ W[256,256], M = 16384. grid(2,256), block 256.
__global__ __launch_bounds__(256) void gemm_aw(const float* __restrict__ A,
                                               const float* __restrict__ W,
                                               float* __restrict__ out) {
    const int t = threadIdx.x;
    const int row0 = blockIdx.y * 64;
    const int cb = blockIdx.x * 128;
    __shared__ __align__(16) float Ast[32][68];   // transposed A tile [k][r]
    __shared__ __align__(16) float Wt[32][132];   // W tile [k][c]
    const int r0 = (t & 15) * 4;
    const int c0 = (t >> 4) * 8;
    const int ar = t >> 2;          // 0..63
    const int ak = (t & 3) * 8;     // 0,8,16,24
    const int wr = t >> 3;          // 0..31
    const int wc = (t & 7) * 16;    // 0..112
    float acc[4][8];
    #pragma unroll
    for (int i = 0; i < 4; i++)
        #pragma unroll
        for (int j = 0; j < 8; j++) acc[i][j] = 0.f;

    for (int k0 = 0; k0 < 256; k0 += 32) {
        const float* asrc = A + (size_t)(row0 + ar) * 256 + k0 + ak;
        float4 a0 = *(const float4*)asrc;
        float4 a1 = *(const float4*)(asrc + 4);
        const float* wsrc = W + (size_t)(k0 + wr) * 256 + cb + wc;
        float4 w0 = *(const float4*)wsrc;
        float4 w1 = *(const float4*)(wsrc + 4);
        float4 w2 = *(const float4*)(wsrc + 8);
        float4 w3 = *(const float4*)(wsrc + 12);
        __syncthreads();
        Ast[ak + 0][ar] = a0.x; Ast[ak + 1][ar] = a0.y;
        Ast[ak + 2][ar] = a0.z; Ast[ak + 3][ar] = a0.w;
        Ast[ak + 4][ar] = a1.x; Ast[ak + 5][ar] = a1.y;
        Ast[ak + 6][ar] = a1.z; Ast[ak + 7][ar] = a1.w;
        *(float4*)&Wt[wr][wc + 0] = w0;
        *(float4*)&Wt[wr][wc + 4] = w1;
        *(float4*)&Wt[wr][wc + 8] = w2;
        *(float4*)&Wt[wr][wc + 12] = w3;
        __syncthreads();
        #pragma unroll
        for (int kk = 0; kk < 32; kk++) {
            const float4 a4 = *(const float4*)&Ast[kk][r0];
            const float4 wa = *(const float4*)&Wt[kk][c0];
            const float4 wb = *(const float4*)&Wt[kk][c0 + 4];
            const float av[4] = {a4.x, a4.y, a4.z, a4.w};
            const float wv[8] = {wa.x, wa.y, wa.z, wa.w, wb.x, wb.y, wb.z, wb.w};
            #pragma unroll
            for (int i = 0; i < 4; i++)
                #pragma unroll
                for (int j = 0; j < 8; j++) acc[i][j] += av[i] * wv[j];
        }
    }
    #pragma unroll
    for (int i = 0; i < 4; i++) {
        float* dst = out + (size_t)(row0 + r0 + i) * 256 + cb + c0;
        *(float4*)dst = make_float4(acc[i][0], acc[i][1], acc[i][2], acc[i][3]);
        *(float4*)(dst + 4) = make_float4(acc[i][4], acc[i][5], acc[i][6], acc[i][7]);
    }
}

// ---------------------------------------------------------------- prep kernels
__global__ __launch_bounds__(256) void prep_wqk(const float* __restrict__ Wqs,
                                                const float* __restrict__ Wks,
                                                float* __restrict__ Wqk2) {
    __shared__ __align__(16) float srow[512];
    const int c1 = blockIdx.x, c2 = threadIdx.x;
    srow[c2] = Wqs[c1 * 512 + c2];
    srow[c2 + 256] = Wqs[c1 * 512 + 256 + c2];
    __syncthreads();
    const float* wk = Wks + (size_t)c2 * 512;
    float acc = 0.f;
    for (int d = 0; d < 512; d += 4) {
        float4 a = *(const float4*)&srow[d];
        float4 b = *(const float4*)(wk + d);
        acc += a.x * b.x + a.y * b.y + a.z * b.z + a.w * b.w;
    }
    Wqk2[c1 * 256 + c2] = acc * 0.044194173824159216f;  // 1/sqrt(512)
}

__global__ __launch_bounds__(256) void prep_wcomb(const float* __restrict__ Wvs,
                                                  const float* __restrict__ Wfc,
                                                  float* __restrict__ Wcomb) {
    __shared__ float srow[512];
    const int c1 = blockIdx.x, c2 = threadIdx.x;
    srow[c2] = Wvs[c1 * 512 + c2];
    srow[c2 + 256] = Wvs[c1 * 512 + 256 + c2];
    __syncthreads();
    float acc = 0.f;
    for (int d = 0; d < 512; d++) acc += srow[d] * Wfc[d * 256 + c2];
    Wcomb[c1 * 256 + c2] = acc;
}

__global__ __launch_bounds__(256) void k_seed(const float* __restrict__ sv,
                                              const float* __restrict__ Ws,
                                              const float* __restrict__ Wqk2,
                                              float* __restrict__ seed,
                                              float* __restrict__ qhk) {
    const int q = blockIdx.x, b = blockIdx.y, c = threadIdx.x;
    __shared__ float ssv[256];
    __shared__ float sseed[256];
    ssv[c] = sv[((size_t)b * 256 + c) * 14 + q];
    __syncthreads();
    float acc = 0.f;
    for (int d = 0; d < 256; d++) acc += ssv[d] * Ws[d * 256 + c];
    seed[((size_t)b * 14 + q) * 256 + c] = acc;
    sseed[c] = acc;
    __syncthreads();
    float a2 = 0.f;
    for (int d = 0; d < 256; d++) a2 += sseed[d] * Wqk2[d * 256 + c];
    qhk[((size_t)b * 14 + q) * 256 + c] = a2;
}

// vv [b][m][c] fp32 -> vvT_h [b][c][m] fp16. grid(64,4,4), block 256.
__global__ __launch_bounds__(256) void k_vvhalf(const float* __restrict__ vv,
                                                _Float16* __restrict__ vvT_h) {
    __shared__ float tile[64][65];   // [c][m]
    const int b = blockIdx.z, c0 = blockIdx.y * 64, m0 = blockIdx.x * 64;
    const int t = threadIdx.x;
    #pragma unroll
    for (int i = 0; i < 4; i++) {
        const int m = (t >> 4) + i * 16;
        const float4 v4 = *(const float4*)(vv + ((size_t)b * 4096 + m0 + m) * 256 + c0 + (t & 15) * 4);
        tile[(t & 15) * 4 + 0][m] = v4.x;
        tile[(t & 15) * 4 + 1][m] = v4.y;
        tile[(t & 15) * 4 + 2][m] = v4.z;
        tile[(t & 15) * 4 + 3][m] = v4.w;
    }
    __syncthreads();
    const int c = t >> 2, mo = (t & 3) * 16;
    UH8 o0, o1;
    #pragma unroll
    for (int j = 0; j < 8; j++) {
        o0.h[j] = (_Float16)tile[c][mo + j];
        o1.h[j] = (_Float16)tile[c][mo + 8 + j];
    }
    const size_t off = ((size_t)b * 256 + c0 + c) * 4096 + m0 + mo;
    *(uint4*)(vvT_h + off) = o0.u4;
    *(uint4*)(vvT_h + off + 8) = o1.u4;
}

// ---------------------------------------------------------------- stage-2 attention
__global__ __launch_bounds__(256) void k_logits1(const float* __restrict__ kk,
                                                 const float* __restrict__ qhk,
                                                 const int* __restrict__ supp,
                                                 float* __restrict__ logits) {
    const int b = blockIdx.y;
    const int n = blockIdx.x * 256 + threadIdx.x;
    __shared__ __align__(16) float sq[14][256];
    for (int i = threadIdx.x; i < 14 * 256; i += 256) sq[i >> 8][i & 255] = qhk[b * 14 * 256 + i];
    __syncthreads();
    float acc[14];
    #pragma unroll
    for (int q = 0; q < 14; q++) acc[q] = 0.f;
    const float* krow = kk + ((size_t)b * 4096 + n) * 256;
    for (int c = 0; c < 256; c += 4) {
        const float4 k4 = *(const float4*)(krow + c);
        #pragma unroll
        for (int q = 0; q < 14; q++) {
            const float4 a4 = *(const float4*)&sq[q][c];
            acc[q] += k4.x * a4.x + k4.y * a4.y + k4.z * a4.z + k4.w * a4.w;
        }
    }
    const bool msk = (supp[b * 4096 + n] == 0);
    #pragma unroll
    for (int q = 0; q < 14; q++)
        logits[((size_t)b * 14 + q) * 4096 + n] = msk ? -1e9f : acc[q];
}

__global__ __launch_bounds__(256) void k_softmax1(float* __restrict__ logits) {
    const int b = blockIdx.y, qq = blockIdx.x, t = threadIdx.x;
    __shared__ __align__(16) float sl[4096];
    __shared__ float sred[8];
    float* row = logits + ((size_t)b * 14 + qq) * 4096;
    float mx = -3e38f;
    for (int i = t; i < 4096; i += 256) { float v = row[i]; sl[i] = v; mx = fmaxf(mx, v); }
    #pragma unroll
    for (int off = 32; off; off >>= 1) mx = fmaxf(mx, __shfl_xor(mx, off, 64));
    if ((t & 63) == 0) sred[t >> 6] = mx;
    __syncthreads();
    mx = fmaxf(fmaxf(sred[0], sred[1]), fmaxf(sred[2], sred[3]));
    __syncthreads();
    float s = 0.f;
    for (int i = t; i < 4096; i += 256) { float e = expf(sl[i] - mx); sl[i] = e; s += e; }
    #pragma unroll
    for (int off = 32; off; off >>= 1) s += __shfl_xor(s, off, 64);
    if ((t & 63) == 0) sred[t >> 6] = s;
    __syncthreads();
    s = sred[0] + sred[1] + sred[2] + sred[3];
    const float inv = 1.f / s;
    for (int i = t; i < 4096; i += 256) row[i] = sl[i] * inv;
}

__global__ __launch_bounds__(256) void k_ctxv(const float* __restrict__ A,
                                              const float* __restrict__ vv,
                                              float* __restrict__ part) {
    const int b = blockIdx.y, ch = blockIdx.x, c = threadIdx.x;
    const int n0 = ch * 256;
    __shared__ __align__(16) float sA[14][256];
    for (int i = c; i < 14 * 256; i += 256) {
        int qq = i >> 8, j = i & 255;
        sA[qq][j] = A[((size_t)b * 14 + qq) * 4096 + n0 + j];
    }
    __syncthreads();
    float acc[14];
    #pragma unroll
    for (int q = 0; q < 14; q++) acc[q] = 0.f;
    for (int n = 0; n < 256; n += 4) {
        const float v0 = vv[((size_t)b * 4096 + n0 + n + 0) * 256 + c];
        const float v1 = vv[((size_t)b * 4096 + n0 + n + 1) * 256 + c];
        const float v2 = vv[((size_t)b * 4096 + n0 + n + 2) * 256 + c];
        const float v3 = vv[((size_t)b * 4096 + n0 + n + 3) * 256 + c];
        #pragma unroll
        for (int q = 0; q < 14; q++) {
            const float4 a4 = *(const float4*)&sA[q][n];
            acc[q] += a4.x * v0 + a4.y * v1 + a4.z * v2 + a4.w * v3;
        }
    }
    #pragma unroll
    for (int q = 0; q < 14; q++) part[(((size_t)b * 16 + ch) * 14 + q) * 256 + c] = acc[q];
}

__global__ __launch_bounds__(256) void k_proto(const float* __restrict__ part,
                                               const float* __restrict__ Wcomb,
                                               const float* __restrict__ bfc,
                                               const float* __restrict__ seed,
                                               const float* __restrict__ lng,
                                               const float* __restrict__ lnb,
                                               const float* __restrict__ Wsk,
                                               const float* __restrict__ Wsq,
                                               float* __restrict__ pkn,
                                               float* __restrict__ pqn) {
    const int q = blockIdx.x, b = blockIdx.y, c = threadIdx.x;
    __shared__ float sctx[256];
    __shared__ float sproto[256];
    __shared__ float sred[8];
    float cv = 0.f;
    for (int ch = 0; ch < 16; ch++) cv += part[(((size_t)b * 16 + ch) * 14 + q) * 256 + c];
    sctx[c] = cv;
    __syncthreads();
    float pre = 0.f;
    for (int d = 0; d < 256; d++) pre += sctx[d] * Wcomb[d * 256 + c];
    pre += bfc[c] + seed[((size_t)b * 14 + q) * 256 + c];
    const float mu = blockReduceSum256(pre, sred) * (1.f / 256.f);
    const float dv = pre - mu;
    const float var = blockReduceSum256(dv * dv, sred) * (1.f / 256.f);
    const float proto = dv * (1.f / sqrtf(var + 1e-5f)) * lng[c] + lnb[c];
    sproto[c] = proto;
    __syncthreads();
    float pk = 0.f, pq = 0.f;
    for (int d = 0; d < 256; d++) {
        const float sp = sproto[d];
        pk += sp * Wsk[d * 256 + c];
        pq += sp * Wsq[d * 256 + c];
    }
    const float nk = blockReduceSum256(pk * pk, sred);
    const float nq = blockReduceSum256(pq * pq, sred);
    pkn[((size_t)b * 14 + q) * 256 + c] = pk / fmaxf(sqrtf(nk), 1e-12f);
    pqn[((size_t)b * 14 + q) * 256 + c] = pq / fmaxf(sqrtf(nq), 1e-12f);
}

__global__ __launch_bounds__(256) void k_q2p(const float* __restrict__ qs,
                                             const float* __restrict__ kk,
                                             const float* __restrict__ pkn,
                                             const float* __restrict__ pqn,
                                             float* __restrict__ aq2p,
                                             float* __restrict__ attc,
                                             int* __restrict__ sidq) {
    const int b = blockIdx.y;
    const int n = blockIdx.x * 256 + threadIdx.x;
    __shared__ __align__(16) float spk[14][256];
    __shared__ __align__(16) float spq[14][256];
    for (int i = threadIdx.x; i < 14 * 256; i += 256) {
        spk[i >> 8][i & 255] = pkn[b * 14 * 256 + i];
        spq[i >> 8][i & 255] = pqn[b * 14 * 256 + i];
    }
    __syncthreads();
    float aq[14], ak[14];
    #pragma unroll
    for (int q = 0; q < 14; q++) { aq[q] = 0.f; ak[q] = 0.f; }
    float nq = 0.f, nk = 0.f;
    const float* qrow = qs + ((size_t)b * 4096 + n) * 256;
    const float* krow = kk + ((size_t)b * 4096 + n) * 256;
    for (int c = 0; c < 256; c += 4) {
        const float4 q4 = *(const float4*)(qrow + c);
        const float4 k4 = *(const float4*)(krow + c);
        nq += q4.x * q4.x + q4.y * q4.y + q4.z * q4.z + q4.w * q4.w;
        nk += k4.x * k4.x + k4.y * k4.y + k4.z * k4.z + k4.w * k4.w;
        #pragma unroll
        for (int q = 0; q < 14; q++) {
            const float4 p4 = *(const float4*)&spk[q][c];
            const float4 p4b = *(const float4*)&spq[q][c];
            aq[q] += q4.x * p4.x + q4.y * p4.y + q4.z * p4.z + q4.w * p4.w;
            ak[q] += k4.x * p4b.x + k4.y * p4b.y + k4.z * p4b.z + k4.w * p4b.w;
        }
    }
    const float sq_ = 1.f / fmaxf(sqrtf(nq), 1e-12f);
    const float sk_ = 1.f / fmaxf(sqrtf(nk), 1e-12f);
    float* aqrow = aq2p + ((size_t)b * 4096 + n) * 14;
    float* akrow = attc + ((size_t)b * 4096 + n) * 14;
    int best = 0;
    float bv = -3e38f;
    #pragma unroll
    for (int q = 0; q < 14; q++) {
        const float v = aq[q] * sq_;
        aqrow[q] = v;
        if (v > bv) { bv = v; best = q; }
        akrow[q] = ak[q] * sk_;
    }
    sidq[b * 4096 + n] = best;
}

// ---------------------------------------------------------------- Sinkhorn
// 512 threads (8 waves), 8 rows/thread, K[8][15] register-resident.
// Column reduction via DPP VALU tree (no LDS-pipe shuffles — R7's 90
// serialized ds_swizzle/iter were the 2.8 us/iter cost), one barrier/iter
// with double-buffered wred, v recomputed redundantly per wave and
// broadcast through v_readlane (SGPRs).
__global__ __launch_bounds__(512, 2) void k_sinkhorn(const float* __restrict__ attc,
                                                     const int* __restrict__ supp,
                                                     const int* __restrict__ valid,
                                                     float* __restrict__ as2pT,
                                                     int* __restrict__ code) {
    const int b = blockIdx.x;
    const int t = threadIdx.x;
    const int lane = t & 63, wid = t >> 6;   // 8 waves
    __shared__ __align__(16) float wred[2][15][8];
    __shared__ float sbg[8];
    float K[8][15], u[8];
    float bgcnt = 0.f;
    #pragma unroll
    for (int j = 0; j < 8; j++) {
        const int n = t + j * 512;
        const int sm = supp[b * 4096 + n];
        bgcnt += (sm == 0) ? 1.f : 0.f;
        const float* arow = attc + ((size_t)b * 4096 + n) * 14;
        #pragma unroll
        for (int m = 0; m < 14; m++) K[j][m] = expf(-20.f * (1.f - arow[m]));
        K[j][14] = (sm > 0) ? expf(-40.f) : 1.f;
        u[j] = 1.f / 4096.f;
    }
    const float bgw = dpp_wave_sum63(bgcnt);
    if (lane == 63) sbg[wid] = bgw;
    __syncthreads();
    float num_bg = 0.f;
    #pragma unroll
    for (int w = 0; w < 8; w++) num_bg += sbg[w];
    const float num_fg = 4096.f - num_bg;
    const float bm_fg = num_fg / (14.f * 4096.f);
    const float bm_tr = num_bg / 4096.f;
    const float a_n = 1.f / 4096.f;
    const float mybm = (lane < 14) ? bm_fg : bm_tr;

    float vloc[15];
    for (int it = 0; it < 100; it++) {
        const int buf = it & 1;
        // phase A: per-thread local column sums, DPP wave reduce -> SGPR totals
        float tot[15];
        #pragma unroll
        for (int m = 0; m < 15; m++) {
            float s = 0.f;
            #pragma unroll
            for (int j = 0; j < 8; j++) s += K[j][m] * u[j];
            tot[m] = rdlane(dpp_wave_sum63(s), 63);   // uniform per wave
        }
        // lane<15 writes its m's wave-total (single ds_write per wave)
        float wv = 0.f;
        #pragma unroll
        for (int m = 0; m < 15; m++) wv = (lane == m) ? tot[m] : wv;
        if (lane < 15) wred[buf][lane][wid] = wv;
        __syncthreads();
        // every wave: lanes 0..14 sum the 8 wave-partials and compute v
        float vtmp = 0.f;
        {
            const float4 r0 = *(const float4*)&wred[buf][lane < 15 ? lane : 0][0];
            const float4 r1 = *(const float4*)&wred[buf][lane < 15 ? lane : 0][4];
            const float s = r0.x + r0.y + r0.z + r0.w + r1.x + r1.y + r1.z + r1.w;
            vtmp = mybm / (s + 1e-16f);
        }
        #pragma unroll
        for (int m = 0; m < 15; m++) vloc[m] = rdlane(vtmp, m);
        // phase B: u[n] = a / sum_m K[n][m] * v[m]
        #pragma unroll
        for (int j = 0; j < 8; j++) {
            float s = 0.f;
            #pragma unroll
            for (int m = 0; m < 15; m++) s += K[j][m] * vloc[m];
            u[j] = a_n / (s + 1e-16f);
        }
    }
    #pragma unroll
    for (int j = 0; j < 8; j++) {
        const int n = t + j * 512;
        float bv = -3e38f;
        int bi = 0;
        #pragma unroll
        for (int m = 0; m < 14; m++) {
            float tv = fmaxf(4096.f * u[j] * K[j][m] * vloc[m], 0.f);
            as2pT[((size_t)(b * 14 + m)) * 4096 + n] = tv;
            if (tv > bv) { bv = tv; bi = m; }
        }
        int msk = 1 << bi;
        if (bi == 0) msk |= (1 << 12);
        else if (bi == 12) msk |= 1;
        else if (bi == 3) msk |= (1 << 11);
        else if (bi == 11) msk |= (1 << 3);
        code[b * 4096 + n] = msk | (valid[b * 4096 + n] << 14);
    }
}

// ---------------------------------------------------------------- lam table
__global__ __launch_bounds__(256) void k_lamtab(const int* __restrict__ code,
                                                int* __restrict__ lamtab) {
    const int b = blockIdx.x, t = threadIdx.x;
    __shared__ int sm0[4], sm1[4];
    int m0 = 0, m1 = 0;
    for (int m = t; m < 4096; m += 256) {
        const int c = code[b * 4096 + m];
        const int mask = c & 0x3fff;
        const int v = c >> 14;
        const int nmask = (~mask) & 0x3fff;
        if (v == 0) { m0 |= mask; m1 |= nmask; }
        else { m1 |= mask; }
    }
    #pragma unroll
    for (int off = 32; off; off >>= 1) {
        m0 |= __shfl_xor(m0, off, 64);
        m1 |= __shfl_xor(m1, off, 64);
    }
    if ((t & 63) == 0) { sm0[t >> 6] = m0; sm1[t >> 6] = m1; }
    __syncthreads();
    if (t == 0) {
        lamtab[b * 2 + 0] = sm0[0] | sm0[1] | sm0[2] | sm0[3];
        lamtab[b * 2 + 1] = sm1[0] | sm1[1] | sm1[2] | sm1[3];
    }
}

// ---------------------------------------------------------------- P materialization
// P[b][n][m] (fp16, unnormalized) and rinv[b][n]. grid(512,4), block 256.
__global__ __launch_bounds__(256) void k_pmat(const float* __restrict__ aq2p,
                                              const float* __restrict__ as2pT,
                                              const int* __restrict__ code,
                                              const int* __restrict__ sidq,
                                              const int* __restrict__ lamtab,
                                              _Float16* __restrict__ P,
                                              float* __restrict__ rinv) {
    const int b = blockIdx.y;
    const int t = threadIdx.x;
    const int nloc = t >> 5, mlane = t & 31;
    const int n = blockIdx.x * 8 + nloc;
    float qv[14];
    const float* qrow = aq2p + ((size_t)b * 4096 + n) * 14;
    #pragma unroll
    for (int k = 0; k < 14; k++) qv[k] = qrow[k];
    const int sq = sidq[b * 4096 + n];
    const int lm0 = lamtab[b * 2 + 0], lm1 = lamtab[b * 2 + 1];
    const int mylam = ((lm0 >> sq) & 1) ? 0 : (((lm1 >> sq) & 1) ? 1 : 2);
    float rsum = 0.f;
    _Float16* prow = P + ((size_t)b * 4096 + n) * 4096;
    const float* abase = as2pT + (size_t)b * 14 * 4096;
    const int* cbase = code + b * 4096;

    for (int g = 0; g < 32; g++) {
        const int m = g * 128 + mlane * 4;
        const int4 cd = *(const int4*)(cbase + m);
        f32x4 lv = {0.f, 0.f, 0.f, 0.f};
        #pragma unroll
        for (int k = 0; k < 14; k++) {
            const f32x4 a = *(const f32x4*)(abase + (size_t)k * 4096 + m);
            lv += qv[k] * a;
        }
        const int cj[4] = {cd.x, cd.y, cd.z, cd.w};
        union { uint2 u2; _Float16 h[4]; } o;
        #pragma unroll
        for (int j = 0; j < 4; j++) {
            const int lvl = (cj[j] >> 14) + 1 - ((cj[j] >> sq) & 1);
            const float p = (lvl == mylam) ? __expf(lv[j]) : 0.f;
            rsum += p;
            o.h[j] = (_Float16)p;
        }
        *(uint2*)(prow + m) = o.u2;
    }
    #pragma unroll
    for (int off = 1; off < 32; off <<= 1) rsum += __shfl_xor(rsum, off, 64);
    if (mlane == 0) rinv[b * 4096 + n] = 1.f / rsum;
}

// ---------------------------------------------------------------- PV GEMM (fp16 MFMA)
// y[b][n][c] = rinv[n] * P[n][:] @ vv[:][c]. grid(64,4), block 512 (8 waves).
__global__ __launch_bounds__(512) void k_pv(const _Float16* __restrict__ P,
                                            const _Float16* __restrict__ vvT_h,
                                            const float* __restrict__ rinv,
                                            float* __restrict__ y) {
    const int b = blockIdx.y, nt = blockIdx.x;
    const int t = threadIdx.x;
    const int l = t & 63, wv = t >> 6;
    const int wn = wv & 3, wc = wv >> 2;
    const int quad = l >> 4, lr = l & 15;
    const int row = nt * 64 + wn * 16 + lr;
    const _Float16* arow = P + (((size_t)b * 4096 + row) * 4096) + quad * 8;
    const _Float16* bbase = vvT_h + ((size_t)(b * 256 + wc * 128 + lr) * 4096) + quad * 8;

    f32x4 acc[8];
    #pragma unroll
    for (int ct = 0; ct < 8; ct++) acc[ct] = (f32x4){0.f, 0.f, 0.f, 0.f};

    uint4 aR = *(const uint4*)(arow);
    uint4 bR[8];
    #pragma unroll
    for (int ct = 0; ct < 8; ct++) bR[ct] = *(const uint4*)(bbase + (size_t)ct * 16 * 4096);

    for (int it = 0; it < 128; it++) {
        const int k1 = (it < 127) ? (it + 1) * 32 : 0;
        uint4 aN = *(const uint4*)(arow + k1);
        uint4 bN[8];
        #pragma unroll
        for (int ct = 0; ct < 8; ct++) bN[ct] = *(const uint4*)(bbase + (size_t)ct * 16 * 4096 + k1);
        #pragma unroll
        for (int ct = 0; ct < 8; ct++) {
            UH8 a, bb;
            a.u4 = aR; bb.u4 = bR[ct];
            acc[ct] = __builtin_amdgcn_mfma_f32_16x16x32_f16(a.h8, bb.h8, acc[ct], 0, 0, 0);
        }
        aR = aN;
        #pragma unroll
        for (int ct = 0; ct < 8; ct++) bR[ct] = bN[ct];
    }
    #pragma unroll
    for (int r = 0; r < 4; r++) {
        const int rowd = nt * 64 + wn * 16 + quad * 4 + r;
        const float ri = rinv[b * 4096 + rowd];
        float* dst = y + ((size_t)b * 4096 + rowd) * 256 + wc * 128 + lr;
        #pragma unroll
        for (int ct = 0; ct < 8; ct++) dst[ct * 16] = acc[ct][r] * ri;
    }
}

// ---------------------------------------------------------------- launch
extern "C" void kernel_launch(void* const* d_in, const int* in_sizes, int n_in,
                              void* d_out, int out_size, void* d_ws, size_t ws_size,
                              hipStream_t stream) {
    (void)in_sizes; (void)n_in; (void)out_size; (void)ws_size;
    const float* q    = (const float*)d_in[0];
    const float* k    = (const float*)d_in[1];
    const float* v    = (const float*)d_in[2];
    const float* sv   = (const float*)d_in[3];
    const int*  valid = (const int*)d_in[4];
    const int*  supp  = (const int*)d_in[5];
    const float* Wq   = (const float*)d_in[6];
    const float* Wk   = (const float*)d_in[7];
    const float* Wv   = (const float*)d_in[8];
    const float* Ws   = (const float*)d_in[9];
    const float* Wsq  = (const float*)d_in[10];
    const float* Wsk  = (const float*)d_in[11];
    const float* Wproj= (const float*)d_in[12];
    const float* Wqs  = (const float*)d_in[13];
    const float* Wks  = (const float*)d_in[14];
    const float* Wvs  = (const float*)d_in[15];
    const float* Wfc  = (const float*)d_in[16];
    const float* bfc  = (const float*)d_in[17];
    const float* lng  = (const float*)d_in[18];
    const float* lnb  = (const float*)d_in[19];

    float* ws = (float*)d_ws;
    // P (fp16 4x4096x4096 = 33,554,432 floats) overlays qs/kk/vv (dead by k_pmat)
    _Float16* P = (_Float16*)ws;
    float* qs   = ws + 0;
    float* kk   = ws + 4194304;
    float* vv   = ws + 8388608;
    float* y0   = ws + 33554432;
    float* wqk2 = ws + 37748736;
    float* wcomb= ws + 37814272;
    float* seed = ws + 37879808;
    float* qhk  = ws + 37894144;
    float* logA = ws + 37908480;
    float* cpart= ws + 38137856;
    float* pkn  = ws + 38367232;
    float* pqn  = ws + 38381568;
    float* aq2p = ws + 38395904;
    float* attc = ws + 38625280;
    float* as2pT= ws + 38854656;
    int* code   = (int*)(ws + 39084032);
    int* sidq   = (int*)(ws + 39100416);
    int* lamtab = (int*)(ws + 39116800);
    float* rinvb= ws + 39116816;
    _Float16* vvT_h = (_Float16*)(ws + 39133216);  // end ~41.2M floats (165 MB)

    gemm_aw<<<dim3(2, 256), 256, 0, stream>>>(q, Wq, qs);
    gemm_aw<<<dim3(2, 256), 256, 0, stream>>>(k, Wk, kk);
    gemm_aw<<<dim3(2, 256), 256, 0, stream>>>(v, Wv, vv);
    k_vvhalf<<<dim3(64, 4, 4), 256, 0, stream>>>(vv, vvT_h);
    prep_wqk<<<256, 256, 0, stream>>>(Wqs, Wks, wqk2);
    prep_wcomb<<<256, 256, 0, stream>>>(Wvs, Wfc, wcomb);
    k_seed<<<dim3(14, 4), 256, 0, stream>>>(sv, Ws, wqk2, seed, qhk);
    k_logits1<<<dim3(16, 4), 256, 0, stream>>>(kk, qhk, supp, logA);
    k_softmax1<<<dim3(14, 4), 256, 0, stream>>>(logA);
    k_ctxv<<<dim3(16, 4), 256, 0, stream>>>(logA, vv, cpart);
    k_proto<<<dim3(14, 4), 256, 0, stream>>>(cpart, wcomb, bfc, seed, lng, lnb, Wsk, Wsq, pkn, pqn);
    k_q2p<<<dim3(16, 4), 256, 0, stream>>>(qs, kk, pkn, pqn, aq2p, attc, sidq);
    k_sinkhorn<<<4, 512, 0, stream>>>(attc, supp, valid, as2pT, code);
    k_lamtab<<<4, 256, 0, stream>>>(code, lamtab);
    k_pmat<<<dim3(512, 4), 256, 0, stream>>>(aq2p, as2pT, code, sidq, lamtab, P, rinvb);
    k_pv<<<dim3(64, 4), 512, 0, stream>>>(P, vvT_h, rinvb, y0);
    gemm_aw<<<dim3(2, 256), 256, 0, stream>>>(y0, Wproj, (float*)d_out);
}